// Round 1
// baseline (2648.266 us; speedup 1.0000x reference)
//
#include <hip/hip_runtime.h>
#include <cfloat>
#include <math.h>

#define B_   8
#define V_   4096
#define E_   256
#define K_   6
#define H_   8
#define HD_  32
#define NPTS (B_*V_)

#define BR 64
#define BC 64
#define KB 32
#define LDP (BR+4)

// ---------------- k0: squared norms (fp32) ----------------
__global__ __launch_bounds__(256) void sq_kernel(const float* __restrict__ x,
                                                 float* __restrict__ sq) {
    int p = blockIdx.x * 64 + (threadIdx.x >> 2);
    int q = threadIdx.x & 3;
    const float4* xp = reinterpret_cast<const float4*>(x + (size_t)p * E_) + q * 16;
    float s = 0.f;
#pragma unroll
    for (int i = 0; i < 16; ++i) {
        float4 v = xp[i];
        s += v.x * v.x + v.y * v.y + v.z * v.z + v.w * v.w;
    }
    s += __shfl_xor(s, 1);
    s += __shfl_xor(s, 2);
    if (q == 0) sq[p] = s;
}

// ---------------- k1: fused Gram + coarse top-16 ----------------
// rank by dr = sq[c] - 2*dot  (sq[r] constant per row -> irrelevant for ranking)
__global__ __launch_bounds__(256) void knn_kernel(const float* __restrict__ x,
                                                  const float* __restrict__ sq,
                                                  int* __restrict__ cand) {
    __shared__ __align__(16) char smem[49152];
    float (*As)[LDP] = reinterpret_cast<float (*)[LDP]>(smem);
    float (*Bs)[LDP] = reinterpret_cast<float (*)[LDP]>(smem + KB * LDP * 4);

    const int b    = blockIdx.y;
    const int row0 = blockIdx.x * BR;
    const float* Xb  = x  + (size_t)b * V_ * E_;
    const float* sqb = sq + (size_t)b * V_;
    const int tid = threadIdx.x;
    const int tr = tid >> 4, tc = tid & 15;

    float bd[4][6];
    int   bi6[4][6];
#pragma unroll
    for (int i = 0; i < 4; ++i)
#pragma unroll
        for (int s = 0; s < 6; ++s) { bd[i][s] = FLT_MAX; bi6[i][s] = 0x7fffffff; }

    for (int c0 = 0; c0 < V_; c0 += BC) {
        float acc[4][4] = {};
        for (int kc = 0; kc < E_; kc += KB) {
            __syncthreads();
#pragma unroll
            for (int it = 0; it < 8; ++it) {
                int l = it * 256 + tid;
                int r = l >> 5, k = l & 31;
                As[k][r] = Xb[(size_t)(row0 + r) * E_ + kc + k];
                Bs[k][r] = Xb[(size_t)(c0 + r) * E_ + kc + k];
            }
            __syncthreads();
#pragma unroll
            for (int k = 0; k < KB; ++k) {
                float4 a  = *reinterpret_cast<const float4*>(&As[k][tr * 4]);
                float4 bb = *reinterpret_cast<const float4*>(&Bs[k][tc * 4]);
                float av[4] = {a.x, a.y, a.z, a.w};
                float bv[4] = {bb.x, bb.y, bb.z, bb.w};
#pragma unroll
                for (int i = 0; i < 4; ++i)
#pragma unroll
                    for (int j = 0; j < 4; ++j) acc[i][j] += av[i] * bv[j];
            }
        }
        // top-6 insertion per owned row over this thread's 4 columns
#pragma unroll
        for (int j = 0; j < 4; ++j) {
            int c = c0 + tc * 4 + j;
            float sc = sqb[c];
#pragma unroll
            for (int i = 0; i < 4; ++i) {
                float d = sc - 2.f * acc[i][j];
                if (d < bd[i][5]) {
                    bd[i][5] = d; bi6[i][5] = c;
#pragma unroll
                    for (int s = 5; s > 0; --s) {
                        if (bd[i][s] < bd[i][s - 1]) {
                            float td = bd[i][s]; bd[i][s] = bd[i][s - 1]; bd[i][s - 1] = td;
                            int   ti = bi6[i][s]; bi6[i][s] = bi6[i][s - 1]; bi6[i][s - 1] = ti;
                        } else break;
                    }
                }
            }
        }
    }

    __syncthreads();
    // merge: 16 column-threads x 6 slots = 96 candidates per row -> coarse top-16
    float* Md = reinterpret_cast<float*>(smem);
    int*   Mi = reinterpret_cast<int*>(smem + 24576);
#pragma unroll
    for (int i = 0; i < 4; ++i) {
        int row = tr * 4 + i;
#pragma unroll
        for (int s = 0; s < 6; ++s) {
            Md[(row * 16 + tc) * 6 + s] = bd[i][s];
            Mi[(row * 16 + tc) * 6 + s] = bi6[i][s];
        }
    }
    __syncthreads();
    if (tid < BR) {
        int row = tid;
        float* md = Md + row * 96;
        int*   mi = Mi + row * 96;
        int* op = cand + ((size_t)b * V_ + row0 + row) * 16;
        for (int s = 0; s < 16; ++s) {
            float best = FLT_MAX; int bc = 0x7fffffff; int bs = 0;
            for (int t = 0; t < 96; ++t) {
                float d = md[t]; int c = mi[t];
                if (d < best || (d == best && c < bc)) { best = d; bc = c; bs = t; }
            }
            md[bs] = FLT_MAX;
            op[s] = bc;
        }
    }
}

// ---------------- k1b: fp64 exact re-rank of 16 candidates -> top-6 ----------------
__global__ __launch_bounds__(256) void refine_kernel(const float* __restrict__ x,
                                                     const int* __restrict__ cand,
                                                     int* __restrict__ idxout) {
    int wv = threadIdx.x >> 6;
    int lane = threadIdx.x & 63;
    int p = blockIdx.x * 4 + wv;
    int b = p >> 12;
    int vi = p & 4095;
    const float* Xb = x + (size_t)b * V_ * E_;

    double xi[4];
#pragma unroll
    for (int t = 0; t < 4; ++t) xi[t] = (double)Xb[(size_t)vi * E_ + lane + t * 64];

    double bdist[6]; int bidx[6];
#pragma unroll
    for (int s = 0; s < 6; ++s) { bdist[s] = DBL_MAX; bidx[s] = 0x7fffffff; }

    for (int c = 0; c < 16; ++c) {
        int j = cand[(size_t)p * 16 + c];
        double s = 0.0;
#pragma unroll
        for (int t = 0; t < 4; ++t) {
            double d = xi[t] - (double)Xb[(size_t)j * E_ + lane + t * 64];
            s += d * d;
        }
#pragma unroll
        for (int off = 32; off; off >>= 1) s += __shfl_xor(s, off);
        // replicated insertion, tie-break by smaller index (matches top_k stability)
        if (s < bdist[5] || (s == bdist[5] && j < bidx[5])) {
            bdist[5] = s; bidx[5] = j;
#pragma unroll
            for (int t = 5; t > 0; --t) {
                if (bdist[t] < bdist[t - 1] || (bdist[t] == bdist[t - 1] && bidx[t] < bidx[t - 1])) {
                    double td = bdist[t]; bdist[t] = bdist[t - 1]; bdist[t - 1] = td;
                    int    ti = bidx[t];  bidx[t]  = bidx[t - 1];  bidx[t - 1]  = ti;
                } else break;
            }
        }
    }
    if (lane == 0) {
        int* op = idxout + (size_t)p * K_;
#pragma unroll
        for (int s = 0; s < 6; ++s) op[s] = bidx[s];
    }
}

// ---------------- k2: QKV projection GEMM  Y[32768][768] ----------------
__global__ __launch_bounds__(256) void proj_kernel(const float* __restrict__ x,
                                                   const float* __restrict__ Wq,
                                                   const float* __restrict__ Wk,
                                                   const float* __restrict__ Wv,
                                                   float* __restrict__ Y) {
    __shared__ __align__(16) float Xs[KB][LDP];
    __shared__ __align__(16) float Ws[KB][LDP];
    const int row0 = blockIdx.x * 64;
    const int cb = blockIdx.y;              // 0..11
    const int w = cb >> 2;
    const int wc0 = (cb & 3) * 64;
    const float* W = (w == 0) ? Wq : ((w == 1) ? Wk : Wv);
    const int tid = threadIdx.x;
    const int tr = tid >> 4, tc = tid & 15;
    float acc[4][4] = {};
    for (int kc = 0; kc < E_; kc += KB) {
        __syncthreads();
#pragma unroll
        for (int it = 0; it < 8; ++it) {
            int l = it * 256 + tid;
            int r = l >> 5, k = l & 31;
            Xs[k][r] = x[(size_t)(row0 + r) * E_ + kc + k];
            Ws[k][r] = W[(size_t)(wc0 + r) * E_ + kc + k];
        }
        __syncthreads();
#pragma unroll
        for (int k = 0; k < KB; ++k) {
            float4 a  = *reinterpret_cast<const float4*>(&Xs[k][tr * 4]);
            float4 bb = *reinterpret_cast<const float4*>(&Ws[k][tc * 4]);
            float av[4] = {a.x, a.y, a.z, a.w};
            float bv[4] = {bb.x, bb.y, bb.z, bb.w};
#pragma unroll
            for (int i = 0; i < 4; ++i)
#pragma unroll
                for (int j = 0; j < 4; ++j) acc[i][j] += av[i] * bv[j];
        }
    }
#pragma unroll
    for (int i = 0; i < 4; ++i) {
        size_t row = row0 + tr * 4 + i;
        float4 v = make_float4(acc[i][0], acc[i][1], acc[i][2], acc[i][3]);
        *reinterpret_cast<float4*>(&Y[row * 768 + w * 256 + wc0 + tc * 4]) = v;
    }
}

// ---------------- k3: per-point attention ----------------
// thread = h*32+d ; writes pre-Wo output back into the Q slice of Y
__global__ __launch_bounds__(256) void attn_kernel(float* __restrict__ Y,
                                                   const int* __restrict__ idx,
                                                   float* __restrict__ xw) {
    const int p = blockIdx.x;
    const int b = p >> 12;
    const int tid = threadIdx.x;
    const int d = tid & 31;
    __shared__ float aw[K_];
    __shared__ int   nbs[K_];
    if (tid < K_) { aw[tid] = 0.f; nbs[tid] = idx[(size_t)p * K_ + tid]; }
    __syncthreads();
    int nb[K_];
#pragma unroll
    for (int k = 0; k < K_; ++k) nb[k] = nbs[k];

    float* Yp = Y + (size_t)p * 768;
    float q = Yp[tid];
    float vself = Yp[512 + tid];
    const size_t bbase = (size_t)(b << 12) * 768;

    float sc[K_];
#pragma unroll
    for (int k = 0; k < K_; ++k) {
        const float* Kr = Y + bbase + (size_t)nb[k] * 768 + 256;
        float s = q * Kr[tid];
        s += __shfl_xor(s, 16);
        s += __shfl_xor(s, 8);
        s += __shfl_xor(s, 4);
        s += __shfl_xor(s, 2);
        s += __shfl_xor(s, 1);
        sc[k] = s * 0.17677669529663687f;   // 1/sqrt(32)
    }
    float m = sc[0];
#pragma unroll
    for (int k = 1; k < K_; ++k) m = fmaxf(m, sc[k]);
    float e[K_], sum = 0.f;
#pragma unroll
    for (int k = 0; k < K_; ++k) { e[k] = __expf(sc[k] - m); sum += e[k]; }
    float inv = 1.f / sum;

    float o = 0.f;
#pragma unroll
    for (int k = 0; k < K_; ++k) {
        const float* Vr = Y + bbase + (size_t)nb[k] * 768 + 512;
        o += (e[k] * inv) * (Vr[tid] - vself);
    }
    if (d == 0) {
#pragma unroll
        for (int k = 0; k < K_; ++k) atomicAdd(&aw[k], e[k] * inv);
    }
    __syncthreads();
    Yp[tid] = o;   // own Q row only ever read by this block -> safe overwrite
    if (tid < K_) atomicAdd(&xw[(b << 12) + nb[tid]], aw[tid] * 0.125f);
}

// ---------------- k4: out = P @ Wo^T + x ----------------
__global__ __launch_bounds__(256) void out_kernel(const float* __restrict__ Y,
                                                  const float* __restrict__ Wo,
                                                  const float* __restrict__ x,
                                                  float* __restrict__ out) {
    __shared__ __align__(16) float Ps[KB][LDP];
    __shared__ __align__(16) float Ws[KB][LDP];
    const int row0 = blockIdx.x * 64;
    const int c0 = blockIdx.y * 64;
    const int tid = threadIdx.x;
    const int tr = tid >> 4, tc = tid & 15;
    float acc[4][4] = {};
    for (int kc = 0; kc < E_; kc += KB) {
        __syncthreads();
#pragma unroll
        for (int it = 0; it < 8; ++it) {
            int l = it * 256 + tid;
            int r = l >> 5, k = l & 31;
            Ps[k][r] = Y[(size_t)(row0 + r) * 768 + kc + k];
            Ws[k][r] = Wo[(size_t)(c0 + r) * E_ + kc + k];
        }
        __syncthreads();
#pragma unroll
        for (int k = 0; k < KB; ++k) {
            float4 a  = *reinterpret_cast<const float4*>(&Ps[k][tr * 4]);
            float4 bb = *reinterpret_cast<const float4*>(&Ws[k][tc * 4]);
            float av[4] = {a.x, a.y, a.z, a.w};
            float bv[4] = {bb.x, bb.y, bb.z, bb.w};
#pragma unroll
            for (int i = 0; i < 4; ++i)
#pragma unroll
                for (int j = 0; j < 4; ++j) acc[i][j] += av[i] * bv[j];
        }
    }
#pragma unroll
    for (int i = 0; i < 4; ++i) {
        size_t row = row0 + tr * 4 + i;
        float4 xr = *reinterpret_cast<const float4*>(&x[row * E_ + c0 + tc * 4]);
        float4 v = make_float4(acc[i][0] + xr.x, acc[i][1] + xr.y,
                               acc[i][2] + xr.z, acc[i][3] + xr.w);
        *reinterpret_cast<float4*>(&out[row * E_ + c0 + tc * 4]) = v;
    }
}

extern "C" void kernel_launch(void* const* d_in, const int* in_sizes, int n_in,
                              void* d_out, int out_size, void* d_ws, size_t ws_size,
                              hipStream_t stream) {
    const float* x  = (const float*)d_in[0];
    const float* Wq = (const float*)d_in[1];
    const float* Wk = (const float*)d_in[2];
    const float* Wv = (const float*)d_in[3];
    const float* Wo = (const float*)d_in[4];

    float* out = (float*)d_out;
    float* xw  = out + (size_t)NPTS * E_;   // second output [B,V]

    // workspace layout
    char* ws = (char*)d_ws;
    float* sqw  = (float*)ws;                                   // 131072 B
    int*   candw = (int*)(ws + 131072);                         // 2 MiB
    int*   idxw  = (int*)(ws + 131072 + 2097152);               // 786432 B
    float* Y     = (float*)(ws + 131072 + 2097152 + 786432);    // 100663296 B

    hipMemsetAsync(xw, 0, (size_t)NPTS * sizeof(float), stream);

    sq_kernel<<<NPTS / 64, 256, 0, stream>>>(x, sqw);
    knn_kernel<<<dim3(V_ / BR, B_), 256, 0, stream>>>(x, sqw, candw);
    refine_kernel<<<NPTS / 4, 256, 0, stream>>>(x, candw, idxw);
    proj_kernel<<<dim3(NPTS / 64, 12), 256, 0, stream>>>(x, Wq, Wk, Wv, Y);
    attn_kernel<<<NPTS, 256, 0, stream>>>(Y, idxw, xw);
    out_kernel<<<dim3(NPTS / 64, 4), 256, 0, stream>>>(Y, Wo, x, out);
}

// Round 2
// 905.432 us; speedup vs baseline: 2.9249x; 2.9249x over previous
//
#include <hip/hip_runtime.h>
#include <cfloat>
#include <math.h>

#define B_   8
#define V_   4096
#define E_   256
#define K_   6
#define H_   8
#define HD_  32
#define NPTS (B_*V_)

#define KB 32
#define LDP 68

typedef __bf16 bf16x8 __attribute__((ext_vector_type(8)));
typedef float  f32x4  __attribute__((ext_vector_type(4)));

// ---------------- k0: squared norms (fp32, exact from fp32 x) ----------------
__global__ __launch_bounds__(256) void sq_kernel(const float* __restrict__ x,
                                                 float* __restrict__ sq) {
    int p = blockIdx.x * 64 + (threadIdx.x >> 2);
    int q = threadIdx.x & 3;
    const float4* xp = reinterpret_cast<const float4*>(x + (size_t)p * E_) + q * 16;
    float s = 0.f;
#pragma unroll
    for (int i = 0; i < 16; ++i) {
        float4 v = xp[i];
        s += v.x * v.x + v.y * v.y + v.z * v.z + v.w * v.w;
    }
    s += __shfl_xor(s, 1);
    s += __shfl_xor(s, 2);
    if (q == 0) sq[p] = s;
}

// ---------------- k0b: fp32 -> bf16 (RNE) conversion of x ----------------
__device__ inline unsigned short f2bf(float f) {
    unsigned int u = __float_as_uint(f);
    return (unsigned short)((u + 0x7fffu + ((u >> 16) & 1u)) >> 16);
}
__global__ __launch_bounds__(256) void cvt_kernel(const float* __restrict__ x,
                                                  unsigned short* __restrict__ xh) {
    size_t i = ((size_t)blockIdx.x * 256 + threadIdx.x) * 8;
    float4 a = *reinterpret_cast<const float4*>(x + i);
    float4 b = *reinterpret_cast<const float4*>(x + i + 4);
    ushort out[8] = { f2bf(a.x), f2bf(a.y), f2bf(a.z), f2bf(a.w),
                      f2bf(b.x), f2bf(b.y), f2bf(b.z), f2bf(b.w) };
    *reinterpret_cast<uint4*>(xh + i) = *reinterpret_cast<uint4*>(out);
}

// ---------------- k1: MFMA Gram + coarse top-16 ----------------
// rank by d = sq[c] - 2*dot  (sq[r] constant per row -> irrelevant for ranking)
// block: 256 thr = 4 waves; 64 rows/block (16 rows/wave); full K=256 in regs.
__global__ __launch_bounds__(256) void knn2_kernel(const unsigned short* __restrict__ xh,
                                                   const float* __restrict__ sq,
                                                   int* __restrict__ cand) {
    __shared__ __align__(16) char smem[49152];

    const int b    = blockIdx.y;
    const int row0 = blockIdx.x * 64;
    const int tid  = threadIdx.x;
    const int w    = tid >> 6;
    const int l    = tid & 63;
    const int cl   = l & 15;       // fragment lane-col
    const int g    = l >> 4;       // fragment k-group
    const float* sqb = sq + (size_t)b * V_;
    const unsigned short* Xb = xh + ((size_t)b << 12) * E_;

    // A fragments: wave w owns rows row0 + w*16 .. +15; lane holds row (cl), k-group g
    const int ar = row0 + (w << 4) + cl;
    bf16x8 a[8];
#pragma unroll
    for (int ks = 0; ks < 8; ++ks)
        a[ks] = *reinterpret_cast<const bf16x8*>(Xb + ((size_t)ar << 8) + ks * 32 + g * 8);

    float bd[4][6];
    int   bi[4][6];
#pragma unroll
    for (int r = 0; r < 4; ++r)
#pragma unroll
        for (int s = 0; s < 6; ++s) { bd[r][s] = FLT_MAX; bi[r][s] = 0x7fffffff; }

    float* sqs = reinterpret_cast<float*>(smem + 32768);

    for (int c0 = 0; c0 < V_; c0 += 64) {
        __syncthreads();
        // stage B tile: 64 rows x 256 bf16, XOR-swizzled 16B slots
#pragma unroll
        for (int it = 0; it < 8; ++it) {
            int li   = it * 256 + tid;
            int row  = li >> 5;
            int slot = li & 31;
            uint4 v = *reinterpret_cast<const uint4*>(Xb + ((size_t)(c0 + row) << 8) + slot * 8);
            *reinterpret_cast<uint4*>(smem + row * 512 + ((slot << 4) ^ ((row & 7) << 4))) = v;
        }
        if (tid < 64) sqs[tid] = sqb[c0 + tid];
        __syncthreads();

#pragma unroll
        for (int ct = 0; ct < 4; ++ct) {
            const int brow = (ct << 4) + cl;
            const int bbase = brow * 512;
            const int swz  = (brow & 7) << 4;
            const int kb16 = g << 4;
            f32x4 acc = {0.f, 0.f, 0.f, 0.f};
#pragma unroll
            for (int ks = 0; ks < 8; ++ks) {
                bf16x8 bf = *reinterpret_cast<const bf16x8*>(
                    smem + bbase + ((ks * 64 + kb16) ^ swz));
                acc = __builtin_amdgcn_mfma_f32_16x16x32_bf16(a[ks], bf, acc, 0, 0, 0);
            }
            const int c = c0 + (ct << 4) + cl;
            const float scq = sqs[(ct << 4) + cl];
#pragma unroll
            for (int r = 0; r < 4; ++r) {
                float d = fmaf(-2.f, acc[r], scq);
                if (d < bd[r][5]) {
                    bd[r][5] = d; bi[r][5] = c;
#pragma unroll
                    for (int s = 5; s > 0; --s) {
                        if (bd[r][s] < bd[r][s - 1]) {
                            float td = bd[r][s]; bd[r][s] = bd[r][s - 1]; bd[r][s - 1] = td;
                            int   ti = bi[r][s]; bi[r][s] = bi[r][s - 1]; bi[r][s - 1] = ti;
                        } else break;
                    }
                }
            }
        }
    }

    __syncthreads();
    // merge: per row, 16 lane-partitions x 6 slots = 96 cands -> coarse top-16
    float* Md = reinterpret_cast<float*>(smem);
    int*   Mi = reinterpret_cast<int*>(smem + 24576);
#pragma unroll
    for (int r = 0; r < 4; ++r) {
        int row_local = (w << 4) + (g << 2) + r;   // C-row = (l>>4)*4 + reg
        int base = (row_local * 16 + cl) * 6;
#pragma unroll
        for (int s = 0; s < 6; ++s) { Md[base + s] = bd[r][s]; Mi[base + s] = bi[r][s]; }
    }
    __syncthreads();
    if (tid < 64) {
        float* md = Md + tid * 96;
        int*   mi = Mi + tid * 96;
        int* op = cand + (((size_t)b << 12) + row0 + tid) * 16;
        for (int s = 0; s < 16; ++s) {
            float best = FLT_MAX; int bc = 0x7fffffff; int bs = 0;
            for (int t = 0; t < 96; ++t) {
                float d = md[t]; int c = mi[t];
                if (d < best || (d == best && c < bc)) { best = d; bc = c; bs = t; }
            }
            md[bs] = FLT_MAX;
            op[s] = bc;
        }
    }
}

// ---------------- k1b: fp64 exact re-rank of 16 candidates -> top-6 ----------------
__global__ __launch_bounds__(256) void refine_kernel(const float* __restrict__ x,
                                                     const int* __restrict__ cand,
                                                     int* __restrict__ idxout) {
    int wv = threadIdx.x >> 6;
    int lane = threadIdx.x & 63;
    int p = blockIdx.x * 4 + wv;
    int b = p >> 12;
    int vi = p & 4095;
    const float* Xb = x + (size_t)b * V_ * E_;

    double xi[4];
#pragma unroll
    for (int t = 0; t < 4; ++t) xi[t] = (double)Xb[(size_t)vi * E_ + lane + t * 64];

    double bdist[6]; int bidx[6];
#pragma unroll
    for (int s = 0; s < 6; ++s) { bdist[s] = DBL_MAX; bidx[s] = 0x7fffffff; }

    for (int c = 0; c < 16; ++c) {
        int j = cand[(size_t)p * 16 + c];
        double s = 0.0;
#pragma unroll
        for (int t = 0; t < 4; ++t) {
            double d = xi[t] - (double)Xb[(size_t)j * E_ + lane + t * 64];
            s += d * d;
        }
#pragma unroll
        for (int off = 32; off; off >>= 1) s += __shfl_xor(s, off);
        if (s < bdist[5] || (s == bdist[5] && j < bidx[5])) {
            bdist[5] = s; bidx[5] = j;
#pragma unroll
            for (int t = 5; t > 0; --t) {
                if (bdist[t] < bdist[t - 1] || (bdist[t] == bdist[t - 1] && bidx[t] < bidx[t - 1])) {
                    double td = bdist[t]; bdist[t] = bdist[t - 1]; bdist[t - 1] = td;
                    int    ti = bidx[t];  bidx[t]  = bidx[t - 1];  bidx[t - 1]  = ti;
                } else break;
            }
        }
    }
    if (lane == 0) {
        int* op = idxout + (size_t)p * K_;
#pragma unroll
        for (int s = 0; s < 6; ++s) op[s] = bidx[s];
    }
}

// ---------------- k2: QKV projection GEMM  Y[32768][768] ----------------
__global__ __launch_bounds__(256) void proj_kernel(const float* __restrict__ x,
                                                   const float* __restrict__ Wq,
                                                   const float* __restrict__ Wk,
                                                   const float* __restrict__ Wv,
                                                   float* __restrict__ Y) {
    __shared__ __align__(16) float Xs[KB][LDP];
    __shared__ __align__(16) float Ws[KB][LDP];
    const int row0 = blockIdx.x * 64;
    const int cb = blockIdx.y;              // 0..11
    const int w = cb >> 2;
    const int wc0 = (cb & 3) * 64;
    const float* W = (w == 0) ? Wq : ((w == 1) ? Wk : Wv);
    const int tid = threadIdx.x;
    const int tr = tid >> 4, tc = tid & 15;
    float acc[4][4] = {};
    for (int kc = 0; kc < E_; kc += KB) {
        __syncthreads();
#pragma unroll
        for (int it = 0; it < 8; ++it) {
            int li = it * 256 + tid;
            int r = li >> 5, k = li & 31;
            Xs[k][r] = x[(size_t)(row0 + r) * E_ + kc + k];
            Ws[k][r] = W[(size_t)(wc0 + r) * E_ + kc + k];
        }
        __syncthreads();
#pragma unroll
        for (int k = 0; k < KB; ++k) {
            float4 a  = *reinterpret_cast<const float4*>(&Xs[k][tr * 4]);
            float4 bb = *reinterpret_cast<const float4*>(&Ws[k][tc * 4]);
            float av[4] = {a.x, a.y, a.z, a.w};
            float bv[4] = {bb.x, bb.y, bb.z, bb.w};
#pragma unroll
            for (int i = 0; i < 4; ++i)
#pragma unroll
                for (int j = 0; j < 4; ++j) acc[i][j] += av[i] * bv[j];
        }
    }
#pragma unroll
    for (int i = 0; i < 4; ++i) {
        size_t row = row0 + tr * 4 + i;
        float4 v = make_float4(acc[i][0], acc[i][1], acc[i][2], acc[i][3]);
        *reinterpret_cast<float4*>(&Y[row * 768 + w * 256 + wc0 + tc * 4]) = v;
    }
}

// ---------------- k3: per-point attention ----------------
__global__ __launch_bounds__(256) void attn_kernel(float* __restrict__ Y,
                                                   const int* __restrict__ idx,
                                                   float* __restrict__ xw) {
    const int p = blockIdx.x;
    const int b = p >> 12;
    const int tid = threadIdx.x;
    const int d = tid & 31;
    __shared__ float aw[K_];
    __shared__ int   nbs[K_];
    if (tid < K_) { aw[tid] = 0.f; nbs[tid] = idx[(size_t)p * K_ + tid]; }
    __syncthreads();
    int nb[K_];
#pragma unroll
    for (int k = 0; k < K_; ++k) nb[k] = nbs[k];

    float* Yp = Y + (size_t)p * 768;
    float q = Yp[tid];
    float vself = Yp[512 + tid];
    const size_t bbase = (size_t)(b << 12) * 768;

    float sc[K_];
#pragma unroll
    for (int k = 0; k < K_; ++k) {
        const float* Kr = Y + bbase + (size_t)nb[k] * 768 + 256;
        float s = q * Kr[tid];
        s += __shfl_xor(s, 16);
        s += __shfl_xor(s, 8);
        s += __shfl_xor(s, 4);
        s += __shfl_xor(s, 2);
        s += __shfl_xor(s, 1);
        sc[k] = s * 0.17677669529663687f;   // 1/sqrt(32)
    }
    float m = sc[0];
#pragma unroll
    for (int k = 1; k < K_; ++k) m = fmaxf(m, sc[k]);
    float e[K_], sum = 0.f;
#pragma unroll
    for (int k = 0; k < K_; ++k) { e[k] = __expf(sc[k] - m); sum += e[k]; }
    float inv = 1.f / sum;

    float o = 0.f;
#pragma unroll
    for (int k = 0; k < K_; ++k) {
        const float* Vr = Y + bbase + (size_t)nb[k] * 768 + 512;
        o += (e[k] * inv) * (Vr[tid] - vself);
    }
    if (d == 0) {
#pragma unroll
        for (int k = 0; k < K_; ++k) atomicAdd(&aw[k], e[k] * inv);
    }
    __syncthreads();
    Yp[tid] = o;
    if (tid < K_) atomicAdd(&xw[(b << 12) + nb[tid]], aw[tid] * 0.125f);
}

// ---------------- k4: out = P @ Wo^T + x ----------------
__global__ __launch_bounds__(256) void out_kernel(const float* __restrict__ Y,
                                                  const float* __restrict__ Wo,
                                                  const float* __restrict__ x,
                                                  float* __restrict__ out) {
    __shared__ __align__(16) float Ps[KB][LDP];
    __shared__ __align__(16) float Ws[KB][LDP];
    const int row0 = blockIdx.x * 64;
    const int c0 = blockIdx.y * 64;
    const int tid = threadIdx.x;
    const int tr = tid >> 4, tc = tid & 15;
    float acc[4][4] = {};
    for (int kc = 0; kc < E_; kc += KB) {
        __syncthreads();
#pragma unroll
        for (int it = 0; it < 8; ++it) {
            int li = it * 256 + tid;
            int r = li >> 5, k = li & 31;
            Ps[k][r] = Y[(size_t)(row0 + r) * 768 + kc + k];
            Ws[k][r] = Wo[(size_t)(c0 + r) * E_ + kc + k];
        }
        __syncthreads();
#pragma unroll
        for (int k = 0; k < KB; ++k) {
            float4 a  = *reinterpret_cast<const float4*>(&Ps[k][tr * 4]);
            float4 bb = *reinterpret_cast<const float4*>(&Ws[k][tc * 4]);
            float av[4] = {a.x, a.y, a.z, a.w};
            float bv[4] = {bb.x, bb.y, bb.z, bb.w};
#pragma unroll
            for (int i = 0; i < 4; ++i)
#pragma unroll
                for (int j = 0; j < 4; ++j) acc[i][j] += av[i] * bv[j];
        }
    }
#pragma unroll
    for (int i = 0; i < 4; ++i) {
        size_t row = row0 + tr * 4 + i;
        float4 xr = *reinterpret_cast<const float4*>(&x[row * E_ + c0 + tc * 4]);
        float4 v = make_float4(acc[i][0] + xr.x, acc[i][1] + xr.y,
                               acc[i][2] + xr.z, acc[i][3] + xr.w);
        *reinterpret_cast<float4*>(&out[row * E_ + c0 + tc * 4]) = v;
    }
}

extern "C" void kernel_launch(void* const* d_in, const int* in_sizes, int n_in,
                              void* d_out, int out_size, void* d_ws, size_t ws_size,
                              hipStream_t stream) {
    const float* x  = (const float*)d_in[0];
    const float* Wq = (const float*)d_in[1];
    const float* Wk = (const float*)d_in[2];
    const float* Wv = (const float*)d_in[3];
    const float* Wo = (const float*)d_in[4];

    float* out = (float*)d_out;
    float* xw  = out + (size_t)NPTS * E_;   // second output [B,V]

    // workspace layout
    char* ws = (char*)d_ws;
    float* sqw   = (float*)ws;                                   // 131072 B
    int*   candw = (int*)(ws + 131072);                          // 2 MiB
    int*   idxw  = (int*)(ws + 131072 + 2097152);                // 786432 B
    float* Y     = (float*)(ws + 131072 + 2097152 + 786432);     // 100663296 B
    // Xh (bf16 copy of x, 16 MiB) aliases Y: dead before proj_kernel writes Y
    unsigned short* Xh = (unsigned short*)Y;

    hipMemsetAsync(xw, 0, (size_t)NPTS * sizeof(float), stream);

    sq_kernel<<<NPTS / 64, 256, 0, stream>>>(x, sqw);
    cvt_kernel<<<NPTS * E_ / (256 * 8), 256, 0, stream>>>(x, Xh);
    knn2_kernel<<<dim3(V_ / 64, B_), 256, 0, stream>>>(Xh, sqw, candw);
    refine_kernel<<<NPTS / 4, 256, 0, stream>>>(x, candw, idxw);
    proj_kernel<<<dim3(NPTS / 64, 12), 256, 0, stream>>>(x, Wq, Wk, Wv, Y);
    attn_kernel<<<NPTS, 256, 0, stream>>>(Y, idxw, xw);
    out_kernel<<<dim3(NPTS / 64, 4), 256, 0, stream>>>(Y, Wo, x, out);
}

// Round 3
// 784.406 us; speedup vs baseline: 3.3761x; 1.1543x over previous
//
#include <hip/hip_runtime.h>
#include <cfloat>
#include <math.h>

#define B_   8
#define V_   4096
#define E_   256
#define K_   6
#define H_   8
#define HD_  32
#define NPTS (B_*V_)

#define KB 32
#define LDP 68

typedef __bf16 bf16x8 __attribute__((ext_vector_type(8)));
typedef float  f32x4  __attribute__((ext_vector_type(4)));

// ---------------- k0: squared norms (fp32, exact from fp32 x) ----------------
__global__ __launch_bounds__(256) void sq_kernel(const float* __restrict__ x,
                                                 float* __restrict__ sq) {
    int p = blockIdx.x * 64 + (threadIdx.x >> 2);
    int q = threadIdx.x & 3;
    const float4* xp = reinterpret_cast<const float4*>(x + (size_t)p * E_) + q * 16;
    float s = 0.f;
#pragma unroll
    for (int i = 0; i < 16; ++i) {
        float4 v = xp[i];
        s += v.x * v.x + v.y * v.y + v.z * v.z + v.w * v.w;
    }
    s += __shfl_xor(s, 1);
    s += __shfl_xor(s, 2);
    if (q == 0) sq[p] = s;
}

// ---------------- k0b: fp32 -> bf16 (RNE) conversion of x ----------------
__device__ inline unsigned short f2bf(float f) {
    unsigned int u = __float_as_uint(f);
    return (unsigned short)((u + 0x7fffu + ((u >> 16) & 1u)) >> 16);
}
__global__ __launch_bounds__(256) void cvt_kernel(const float* __restrict__ x,
                                                  unsigned short* __restrict__ xh) {
    size_t i = ((size_t)blockIdx.x * 256 + threadIdx.x) * 8;
    float4 a = *reinterpret_cast<const float4*>(x + i);
    float4 b = *reinterpret_cast<const float4*>(x + i + 4);
    ushort out[8] = { f2bf(a.x), f2bf(a.y), f2bf(a.z), f2bf(a.w),
                      f2bf(b.x), f2bf(b.y), f2bf(b.z), f2bf(b.w) };
    *reinterpret_cast<uint4*>(xh + i) = *reinterpret_cast<uint4*>(out);
}

// ---------------- k1: MFMA Gram + per-partition top-6 (24 cands/row) ----------------
// rank by d = sq[c] - 2*dot  (sq[r] constant per row -> irrelevant for ranking)
// 256 thr = 4 waves; 64 rows/block (16/wave); K=256 A-fragments in registers.
// T14 pipeline: issue next tile's global loads before computing current tile.
__global__ __launch_bounds__(256) void knn3_kernel(const unsigned short* __restrict__ xh,
                                                   const float* __restrict__ sq,
                                                   unsigned short* __restrict__ cand) {
    __shared__ __align__(16) char smem[49664];

    const int b    = blockIdx.y;
    const int row0 = blockIdx.x * 64;
    const int tid  = threadIdx.x;
    const int w    = tid >> 6;
    const int l    = tid & 63;
    const int cl   = l & 15;       // fragment lane-col
    const int g    = l >> 4;       // fragment k-group
    const float* sqb = sq + (size_t)b * V_;
    const unsigned short* Xb = xh + ((size_t)b << 12) * E_;

    // A fragments: wave w owns rows row0 + w*16 .. +15
    const int ar = row0 + (w << 4) + cl;
    bf16x8 a[8];
#pragma unroll
    for (int ks = 0; ks < 8; ++ks)
        a[ks] = *reinterpret_cast<const bf16x8*>(Xb + ((size_t)ar << 8) + ks * 32 + g * 8);

    float bd[4][6];
    int   bi[4][6];
#pragma unroll
    for (int r = 0; r < 4; ++r)
#pragma unroll
        for (int s = 0; s < 6; ++s) { bd[r][s] = FLT_MAX; bi[r][s] = 0x7fffffff; }

    // prologue: stage tile 0
    uint4 st[8];
#pragma unroll
    for (int it = 0; it < 8; ++it) {
        int li = it * 256 + tid, row = li >> 5, sl = li & 31;
        st[it] = *reinterpret_cast<const uint4*>(Xb + ((size_t)row << 8) + sl * 8);
    }
#pragma unroll
    for (int it = 0; it < 8; ++it) {
        int li = it * 256 + tid, row = li >> 5, sl = li & 31;
        *reinterpret_cast<uint4*>(smem + row * 512 + ((sl << 4) ^ ((row & 7) << 4))) = st[it];
    }
    __syncthreads();

    for (int c0 = 0; c0 < V_; c0 += 64) {
        const int c0n = (c0 + 64) & (V_ - 1);   // wrapped; last-iter loads harmless
        // issue next-tile global loads early (latency hides under compute)
#pragma unroll
        for (int it = 0; it < 8; ++it) {
            int li = it * 256 + tid, row = li >> 5, sl = li & 31;
            st[it] = *reinterpret_cast<const uint4*>(Xb + ((size_t)(c0n + row) << 8) + sl * 8);
        }
        float sqv[4];
#pragma unroll
        for (int ct = 0; ct < 4; ++ct) sqv[ct] = sqb[c0 + (ct << 4) + cl];

#pragma unroll
        for (int ct = 0; ct < 4; ++ct) {
            const int brow = (ct << 4) + cl;
            const int bbase = brow * 512;
            const int swz  = (brow & 7) << 4;
            const int kb16 = g << 4;
            f32x4 acc = {0.f, 0.f, 0.f, 0.f};
#pragma unroll
            for (int ks = 0; ks < 8; ++ks) {
                bf16x8 bf = *reinterpret_cast<const bf16x8*>(
                    smem + bbase + ((ks * 64 + kb16) ^ swz));
                acc = __builtin_amdgcn_mfma_f32_16x16x32_bf16(a[ks], bf, acc, 0, 0, 0);
            }
            const int c = c0 + (ct << 4) + cl;
#pragma unroll
            for (int r = 0; r < 4; ++r) {
                float d = fmaf(-2.f, acc[r], sqv[ct]);
                if (d < bd[r][5]) {
                    bd[r][5] = d; bi[r][5] = c;
#pragma unroll
                    for (int s = 5; s > 0; --s) {
                        if (bd[r][s] < bd[r][s - 1]) {
                            float td = bd[r][s]; bd[r][s] = bd[r][s - 1]; bd[r][s - 1] = td;
                            int   ti = bi[r][s]; bi[r][s] = bi[r][s - 1]; bi[r][s - 1] = ti;
                        } else break;
                    }
                }
            }
        }
        __syncthreads();
        // write next tile into LDS (swizzled)
#pragma unroll
        for (int it = 0; it < 8; ++it) {
            int li = it * 256 + tid, row = li >> 5, sl = li & 31;
            *reinterpret_cast<uint4*>(smem + row * 512 + ((sl << 4) ^ ((row & 7) << 4))) = st[it];
        }
        __syncthreads();
    }

    // ---- dump per-lane lists to LDS (stride 97 -> conflict-free scans) ----
    float* D = reinterpret_cast<float*>(smem);            // [64][97]
    int*   C = reinterpret_cast<int*>(smem + 24832);      // [64][97]
#pragma unroll
    for (int r = 0; r < 4; ++r) {
        int rl = (w << 4) + (g << 2) + r;    // C-row = (l>>4)*4 + reg
        int base = rl * 97 + cl * 6;
#pragma unroll
        for (int s = 0; s < 6; ++s) { D[base + s] = bd[r][s]; C[base + s] = bi[r][s]; }
    }
    __syncthreads();

    // ---- 4 threads/row, each keeps top-6 of its 24 -> 24 cands/row to global ----
    {
        const int row = tid >> 2, part = tid & 3;
        const float* dr = D + row * 97 + part * 24;
        const int*   cr = C + row * 97 + part * 24;
        float td[6]; int ti[6];
#pragma unroll
        for (int s = 0; s < 6; ++s) { td[s] = FLT_MAX; ti[s] = 0x7fffffff; }
        for (int j = 0; j < 24; ++j) {
            float d = dr[j]; int c = cr[j];
            if (d < td[5] || (d == td[5] && c < ti[5])) {
                td[5] = d; ti[5] = c;
#pragma unroll
                for (int s = 5; s > 0; --s) {
                    if (td[s] < td[s - 1] || (td[s] == td[s - 1] && ti[s] < ti[s - 1])) {
                        float x0 = td[s]; td[s] = td[s - 1]; td[s - 1] = x0;
                        int   i0 = ti[s]; ti[s] = ti[s - 1]; ti[s - 1] = i0;
                    } else break;
                }
            }
        }
        unsigned short* op = cand + (((size_t)b << 12) + row0 + row) * 24 + part * 6;
#pragma unroll
        for (int s = 0; s < 6; ++s) op[s] = (unsigned short)ti[s];
    }
}

// ---------------- k1b: fp64 exact re-rank of 24 candidates -> top-6 ----------------
__global__ __launch_bounds__(256) void refine_kernel(const float* __restrict__ x,
                                                     const unsigned short* __restrict__ cand,
                                                     int* __restrict__ idxout) {
    int wv = threadIdx.x >> 6;
    int lane = threadIdx.x & 63;
    int p = blockIdx.x * 4 + wv;
    int b = p >> 12;
    int vi = p & 4095;
    const float* Xb = x + (size_t)b * V_ * E_;

    double xi[4];
#pragma unroll
    for (int t = 0; t < 4; ++t) xi[t] = (double)Xb[(size_t)vi * E_ + lane + t * 64];

    double bdist[6]; int bidx[6];
#pragma unroll
    for (int s = 0; s < 6; ++s) { bdist[s] = DBL_MAX; bidx[s] = 0x7fffffff; }

    for (int c = 0; c < 24; ++c) {
        int j = cand[(size_t)p * 24 + c];
        double s = 0.0;
#pragma unroll
        for (int t = 0; t < 4; ++t) {
            double d = xi[t] - (double)Xb[(size_t)j * E_ + lane + t * 64];
            s += d * d;
        }
#pragma unroll
        for (int off = 32; off; off >>= 1) s += __shfl_xor(s, off);
        if (s < bdist[5] || (s == bdist[5] && j < bidx[5])) {
            bdist[5] = s; bidx[5] = j;
#pragma unroll
            for (int t = 5; t > 0; --t) {
                if (bdist[t] < bdist[t - 1] || (bdist[t] == bdist[t - 1] && bidx[t] < bidx[t - 1])) {
                    double td = bdist[t]; bdist[t] = bdist[t - 1]; bdist[t - 1] = td;
                    int    ti = bidx[t];  bidx[t]  = bidx[t - 1];  bidx[t - 1]  = ti;
                } else break;
            }
        }
    }
    if (lane == 0) {
        int* op = idxout + (size_t)p * K_;
#pragma unroll
        for (int s = 0; s < 6; ++s) op[s] = bidx[s];
    }
}

// ---------------- k2: QKV projection GEMM  Y[32768][768] ----------------
__global__ __launch_bounds__(256) void proj_kernel(const float* __restrict__ x,
                                                   const float* __restrict__ Wq,
                                                   const float* __restrict__ Wk,
                                                   const float* __restrict__ Wv,
                                                   float* __restrict__ Y) {
    __shared__ __align__(16) float Xs[KB][LDP];
    __shared__ __align__(16) float Ws[KB][LDP];
    const int row0 = blockIdx.x * 64;
    const int cb = blockIdx.y;              // 0..11
    const int w = cb >> 2;
    const int wc0 = (cb & 3) * 64;
    const float* W = (w == 0) ? Wq : ((w == 1) ? Wk : Wv);
    const int tid = threadIdx.x;
    const int tr = tid >> 4, tc = tid & 15;
    float acc[4][4] = {};
    for (int kc = 0; kc < E_; kc += KB) {
        __syncthreads();
#pragma unroll
        for (int it = 0; it < 8; ++it) {
            int li = it * 256 + tid;
            int r = li >> 5, k = li & 31;
            Xs[k][r] = x[(size_t)(row0 + r) * E_ + kc + k];
            Ws[k][r] = W[(size_t)(wc0 + r) * E_ + kc + k];
        }
        __syncthreads();
#pragma unroll
        for (int k = 0; k < KB; ++k) {
            float4 a  = *reinterpret_cast<const float4*>(&Xs[k][tr * 4]);
            float4 bb = *reinterpret_cast<const float4*>(&Ws[k][tc * 4]);
            float av[4] = {a.x, a.y, a.z, a.w};
            float bv[4] = {bb.x, bb.y, bb.z, bb.w};
#pragma unroll
            for (int i = 0; i < 4; ++i)
#pragma unroll
                for (int j = 0; j < 4; ++j) acc[i][j] += av[i] * bv[j];
        }
    }
#pragma unroll
    for (int i = 0; i < 4; ++i) {
        size_t row = row0 + tr * 4 + i;
        float4 v = make_float4(acc[i][0], acc[i][1], acc[i][2], acc[i][3]);
        *reinterpret_cast<float4*>(&Y[row * 768 + w * 256 + wc0 + tc * 4]) = v;
    }
}

// ---------------- k3: per-point attention ----------------
__global__ __launch_bounds__(256) void attn_kernel(float* __restrict__ Y,
                                                   const int* __restrict__ idx,
                                                   float* __restrict__ xw) {
    const int p = blockIdx.x;
    const int b = p >> 12;
    const int tid = threadIdx.x;
    const int d = tid & 31;
    __shared__ float aw[K_];
    __shared__ int   nbs[K_];
    if (tid < K_) { aw[tid] = 0.f; nbs[tid] = idx[(size_t)p * K_ + tid]; }
    __syncthreads();
    int nb[K_];
#pragma unroll
    for (int k = 0; k < K_; ++k) nb[k] = nbs[k];

    float* Yp = Y + (size_t)p * 768;
    float q = Yp[tid];
    float vself = Yp[512 + tid];
    const size_t bbase = (size_t)(b << 12) * 768;

    float sc[K_];
#pragma unroll
    for (int k = 0; k < K_; ++k) {
        const float* Kr = Y + bbase + (size_t)nb[k] * 768 + 256;
        float s = q * Kr[tid];
        s += __shfl_xor(s, 16);
        s += __shfl_xor(s, 8);
        s += __shfl_xor(s, 4);
        s += __shfl_xor(s, 2);
        s += __shfl_xor(s, 1);
        sc[k] = s * 0.17677669529663687f;   // 1/sqrt(32)
    }
    float m = sc[0];
#pragma unroll
    for (int k = 1; k < K_; ++k) m = fmaxf(m, sc[k]);
    float e[K_], sum = 0.f;
#pragma unroll
    for (int k = 0; k < K_; ++k) { e[k] = __expf(sc[k] - m); sum += e[k]; }
    float inv = 1.f / sum;

    float o = 0.f;
#pragma unroll
    for (int k = 0; k < K_; ++k) {
        const float* Vr = Y + bbase + (size_t)nb[k] * 768 + 512;
        o += (e[k] * inv) * (Vr[tid] - vself);
    }
    if (d == 0) {
#pragma unroll
        for (int k = 0; k < K_; ++k) atomicAdd(&aw[k], e[k] * inv);
    }
    __syncthreads();
    Yp[tid] = o;
    if (tid < K_) atomicAdd(&xw[(b << 12) + nb[tid]], aw[tid] * 0.125f);
}

// ---------------- k4: out = P @ Wo^T + x ----------------
__global__ __launch_bounds__(256) void out_kernel(const float* __restrict__ Y,
                                                  const float* __restrict__ Wo,
                                                  const float* __restrict__ x,
                                                  float* __restrict__ out) {
    __shared__ __align__(16) float Ps[KB][LDP];
    __shared__ __align__(16) float Ws[KB][LDP];
    const int row0 = blockIdx.x * 64;
    const int c0 = blockIdx.y * 64;
    const int tid = threadIdx.x;
    const int tr = tid >> 4, tc = tid & 15;
    float acc[4][4] = {};
    for (int kc = 0; kc < E_; kc += KB) {
        __syncthreads();
#pragma unroll
        for (int it = 0; it < 8; ++it) {
            int li = it * 256 + tid;
            int r = li >> 5, k = li & 31;
            Ps[k][r] = Y[(size_t)(row0 + r) * 768 + kc + k];
            Ws[k][r] = Wo[(size_t)(c0 + r) * E_ + kc + k];
        }
        __syncthreads();
#pragma unroll
        for (int k = 0; k < KB; ++k) {
            float4 a  = *reinterpret_cast<const float4*>(&Ps[k][tr * 4]);
            float4 bb = *reinterpret_cast<const float4*>(&Ws[k][tc * 4]);
            float av[4] = {a.x, a.y, a.z, a.w};
            float bv[4] = {bb.x, bb.y, bb.z, bb.w};
#pragma unroll
            for (int i = 0; i < 4; ++i)
#pragma unroll
                for (int j = 0; j < 4; ++j) acc[i][j] += av[i] * bv[j];
        }
    }
#pragma unroll
    for (int i = 0; i < 4; ++i) {
        size_t row = row0 + tr * 4 + i;
        float4 xr = *reinterpret_cast<const float4*>(&x[row * E_ + c0 + tc * 4]);
        float4 v = make_float4(acc[i][0] + xr.x, acc[i][1] + xr.y,
                               acc[i][2] + xr.z, acc[i][3] + xr.w);
        *reinterpret_cast<float4*>(&out[row * E_ + c0 + tc * 4]) = v;
    }
}

extern "C" void kernel_launch(void* const* d_in, const int* in_sizes, int n_in,
                              void* d_out, int out_size, void* d_ws, size_t ws_size,
                              hipStream_t stream) {
    const float* x  = (const float*)d_in[0];
    const float* Wq = (const float*)d_in[1];
    const float* Wk = (const float*)d_in[2];
    const float* Wv = (const float*)d_in[3];
    const float* Wo = (const float*)d_in[4];

    float* out = (float*)d_out;
    float* xw  = out + (size_t)NPTS * E_;   // second output [B,V]

    // workspace layout
    char* ws = (char*)d_ws;
    float* sqw = (float*)ws;                                     // 131072 B
    unsigned short* candw = (unsigned short*)(ws + 131072);      // 1.5 MiB used (2 MiB slot)
    int*   idxw  = (int*)(ws + 131072 + 2097152);                // 786432 B
    float* Y     = (float*)(ws + 131072 + 2097152 + 786432);     // 100663296 B
    // Xh (bf16 copy of x, 16 MiB) aliases Y: dead before proj_kernel writes Y
    unsigned short* Xh = (unsigned short*)Y;

    hipMemsetAsync(xw, 0, (size_t)NPTS * sizeof(float), stream);

    sq_kernel<<<NPTS / 64, 256, 0, stream>>>(x, sqw);
    cvt_kernel<<<NPTS * E_ / (256 * 8), 256, 0, stream>>>(x, Xh);
    knn3_kernel<<<dim3(V_ / 64, B_), 256, 0, stream>>>(Xh, sqw, candw);
    refine_kernel<<<NPTS / 4, 256, 0, stream>>>(x, candw, idxw);
    proj_kernel<<<dim3(NPTS / 64, 12), 256, 0, stream>>>(x, Wq, Wk, Wv, Y);
    attn_kernel<<<NPTS, 256, 0, stream>>>(Y, idxw, xw);
    out_kernel<<<dim3(NPTS / 64, 4), 256, 0, stream>>>(Y, Wo, x, out);
}

// Round 4
// 551.574 us; speedup vs baseline: 4.8013x; 1.4221x over previous
//
#include <hip/hip_runtime.h>
#include <cfloat>
#include <math.h>

#define B_   8
#define V_   4096
#define E_   256
#define K_   6
#define H_   8
#define HD_  32
#define NPTS (B_*V_)

typedef __bf16 bf16x8 __attribute__((ext_vector_type(8)));
typedef float  f32x4  __attribute__((ext_vector_type(4)));

__device__ __forceinline__ float bf2f(unsigned short u) {
    return __uint_as_float(((unsigned int)u) << 16);
}
__device__ __forceinline__ unsigned short f2bf(float f) {
    unsigned int u = __float_as_uint(f);
    return (unsigned short)((u + 0x7fffu + ((u >> 16) & 1u)) >> 16);
}

// ---------------- k0: squared norms (fp32, exact from fp32 x) ----------------
__global__ __launch_bounds__(256) void sq_kernel(const float* __restrict__ x,
                                                 float* __restrict__ sq) {
    int p = blockIdx.x * 64 + (threadIdx.x >> 2);
    int q = threadIdx.x & 3;
    const float4* xp = reinterpret_cast<const float4*>(x + (size_t)p * E_) + q * 16;
    float s = 0.f;
#pragma unroll
    for (int i = 0; i < 16; ++i) {
        float4 v = xp[i];
        s += v.x * v.x + v.y * v.y + v.z * v.z + v.w * v.w;
    }
    s += __shfl_xor(s, 1);
    s += __shfl_xor(s, 2);
    if (q == 0) sq[p] = s;
}

// ---------------- k0b: fp32 -> bf16 (RNE) of x ----------------
__global__ __launch_bounds__(256) void cvt_kernel(const float* __restrict__ x,
                                                  unsigned short* __restrict__ xh) {
    size_t i = ((size_t)blockIdx.x * 256 + threadIdx.x) * 8;
    float4 a = *reinterpret_cast<const float4*>(x + i);
    float4 b = *reinterpret_cast<const float4*>(x + i + 4);
    ushort out[8] = { f2bf(a.x), f2bf(a.y), f2bf(a.z), f2bf(a.w),
                      f2bf(b.x), f2bf(b.y), f2bf(b.z), f2bf(b.w) };
    *reinterpret_cast<uint4*>(xh + i) = *reinterpret_cast<uint4*>(out);
}

// ---------------- k0c: weights fp32 -> bf16; grid.y selects matrix ----------------
__global__ __launch_bounds__(256) void cvtw_kernel(const float* __restrict__ Wq,
                                                   const float* __restrict__ Wk,
                                                   const float* __restrict__ Wv,
                                                   const float* __restrict__ Wo,
                                                   unsigned short* __restrict__ Wh) {
    const float* src = (blockIdx.y == 0) ? Wq : (blockIdx.y == 1) ? Wk
                     : (blockIdx.y == 2) ? Wv : Wo;
    unsigned short* dst = Wh + (size_t)blockIdx.y * 65536;
    size_t i = ((size_t)blockIdx.x * 256 + threadIdx.x) * 8;
    float4 a = *reinterpret_cast<const float4*>(src + i);
    float4 b = *reinterpret_cast<const float4*>(src + i + 4);
    ushort out[8] = { f2bf(a.x), f2bf(a.y), f2bf(a.z), f2bf(a.w),
                      f2bf(b.x), f2bf(b.y), f2bf(b.z), f2bf(b.w) };
    *reinterpret_cast<uint4*>(dst + i) = *reinterpret_cast<uint4*>(out);
}

// ---------------- k1: MFMA Gram + per-partition top-6 (24 cands/row) ----------------
// global_load_lds double-buffered staging; swizzle applied on SOURCE address
// (linear LDS dest) and re-applied on read: sl ^ (row&7) is an involution.
__global__ __launch_bounds__(256) void knn4_kernel(const unsigned short* __restrict__ xh,
                                                   const float* __restrict__ sq,
                                                   unsigned short* __restrict__ cand) {
    __shared__ __align__(16) char smem[65536];   // 2 x 32KB tile buffers

    const int b    = blockIdx.y;
    const int row0 = blockIdx.x * 64;
    const int tid  = threadIdx.x;
    const int w    = tid >> 6;
    const int l    = tid & 63;
    const int cl   = l & 15;
    const int g    = l >> 4;
    const float* sqb = sq + (size_t)b * V_;
    const unsigned short* Xb = xh + ((size_t)b << 12) * E_;

    // A fragments: wave w owns rows row0 + w*16 .. +15 ; full K=256 in regs
    const int ar = row0 + (w << 4) + cl;
    bf16x8 a[8];
#pragma unroll
    for (int ks = 0; ks < 8; ++ks)
        a[ks] = *reinterpret_cast<const bf16x8*>(Xb + ((size_t)ar << 8) + ks * 32 + g * 8);

    float bd[4][6];
    int   bi[4][6];
#pragma unroll
    for (int r = 0; r < 4; ++r)
#pragma unroll
        for (int s = 0; s < 6; ++s) { bd[r][s] = FLT_MAX; bi[r][s] = 0x7fffffff; }

    // prologue: stage tile 0 into buf0
#pragma unroll
    for (int it = 0; it < 8; ++it) {
        int li = it * 256 + tid, row = li >> 5, sl = li & 31;
        const unsigned short* gp = Xb + ((size_t)row << 8) + ((sl ^ (row & 7)) << 3);
        __builtin_amdgcn_global_load_lds(
            (const __attribute__((address_space(1))) void*)gp,
            (__attribute__((address_space(3))) void*)(smem + li * 16), 16, 0, 0);
    }
    __syncthreads();

    for (int t = 0; t < 64; ++t) {
        const int c0  = t * 64;
        const int cur = (t & 1) * 32768;
        if (t < 63) {
            const int c0n = c0 + 64;
            char* nb = smem + (cur ^ 32768);
#pragma unroll
            for (int it = 0; it < 8; ++it) {
                int li = it * 256 + tid, row = li >> 5, sl = li & 31;
                const unsigned short* gp =
                    Xb + ((size_t)(c0n + row) << 8) + ((sl ^ (row & 7)) << 3);
                __builtin_amdgcn_global_load_lds(
                    (const __attribute__((address_space(1))) void*)gp,
                    (__attribute__((address_space(3))) void*)(nb + li * 16), 16, 0, 0);
            }
        }
        float sqv[4];
#pragma unroll
        for (int ct = 0; ct < 4; ++ct) sqv[ct] = sqb[c0 + (ct << 4) + cl];

#pragma unroll
        for (int ct = 0; ct < 4; ++ct) {
            const int brow = (ct << 4) + cl;
            const char* bbase = smem + cur + brow * 512;
            const int swz  = (brow & 7) << 4;
            const int kb16 = g << 4;
            f32x4 acc = {0.f, 0.f, 0.f, 0.f};
#pragma unroll
            for (int ks = 0; ks < 8; ++ks) {
                bf16x8 bf = *reinterpret_cast<const bf16x8*>(
                    bbase + ((ks * 64 + kb16) ^ swz));
                acc = __builtin_amdgcn_mfma_f32_16x16x32_bf16(a[ks], bf, acc, 0, 0, 0);
            }
            const int c = c0 + (ct << 4) + cl;
#pragma unroll
            for (int r = 0; r < 4; ++r) {
                float d = fmaf(-2.f, acc[r], sqv[ct]);
                if (d < bd[r][5]) {
                    bd[r][5] = d; bi[r][5] = c;
#pragma unroll
                    for (int s = 5; s > 0; --s) {
                        if (bd[r][s] < bd[r][s - 1]) {
                            float td = bd[r][s]; bd[r][s] = bd[r][s - 1]; bd[r][s - 1] = td;
                            int   ti = bi[r][s]; bi[r][s] = bi[r][s - 1]; bi[r][s - 1] = ti;
                        } else break;
                    }
                }
            }
        }
        __syncthreads();   // prefetch landed (vmcnt drain) + all reads of cur done
    }

    // ---- dump per-lane lists to LDS (stride 97 -> conflict-free scans) ----
    float* D = reinterpret_cast<float*>(smem);            // [64][97]
    int*   C = reinterpret_cast<int*>(smem + 24832);      // [64][97]
#pragma unroll
    for (int r = 0; r < 4; ++r) {
        int rl = (w << 4) + (g << 2) + r;    // C-row = (l>>4)*4 + reg
        int base = rl * 97 + cl * 6;
#pragma unroll
        for (int s = 0; s < 6; ++s) { D[base + s] = bd[r][s]; C[base + s] = bi[r][s]; }
    }
    __syncthreads();

    // ---- 4 threads/row, each keeps top-6 of its 24 -> 24 cands/row ----
    {
        const int row = tid >> 2, part = tid & 3;
        const float* dr = D + row * 97 + part * 24;
        const int*   cr = C + row * 97 + part * 24;
        float td[6]; int ti[6];
#pragma unroll
        for (int s = 0; s < 6; ++s) { td[s] = FLT_MAX; ti[s] = 0x7fffffff; }
        for (int j = 0; j < 24; ++j) {
            float d = dr[j]; int c = cr[j];
            if (d < td[5] || (d == td[5] && c < ti[5])) {
                td[5] = d; ti[5] = c;
#pragma unroll
                for (int s = 5; s > 0; --s) {
                    if (td[s] < td[s - 1] || (td[s] == td[s - 1] && ti[s] < ti[s - 1])) {
                        float x0 = td[s]; td[s] = td[s - 1]; td[s - 1] = x0;
                        int   i0 = ti[s]; ti[s] = ti[s - 1]; ti[s - 1] = i0;
                    } else break;
                }
            }
        }
        unsigned short* op = cand + (((size_t)b << 12) + row0 + row) * 24 + part * 6;
#pragma unroll
        for (int s = 0; s < 6; ++s) op[s] = (unsigned short)ti[s];
    }
}

// ---------------- k1b: fp64 exact re-rank of 24 candidates -> top-6 ----------------
__global__ __launch_bounds__(256) void refine_kernel(const float* __restrict__ x,
                                                     const unsigned short* __restrict__ cand,
                                                     int* __restrict__ idxout) {
    int wv = threadIdx.x >> 6;
    int lane = threadIdx.x & 63;
    int p = blockIdx.x * 4 + wv;
    int b = p >> 12;
    int vi = p & 4095;
    const float* Xb = x + (size_t)b * V_ * E_;

    double xi[4];
#pragma unroll
    for (int t = 0; t < 4; ++t) xi[t] = (double)Xb[(size_t)vi * E_ + lane + t * 64];

    double bdist[6]; int bidx[6];
#pragma unroll
    for (int s = 0; s < 6; ++s) { bdist[s] = DBL_MAX; bidx[s] = 0x7fffffff; }

    for (int c = 0; c < 24; ++c) {
        int j = cand[(size_t)p * 24 + c];
        double s = 0.0;
#pragma unroll
        for (int t = 0; t < 4; ++t) {
            double d = xi[t] - (double)Xb[(size_t)j * E_ + lane + t * 64];
            s += d * d;
        }
#pragma unroll
        for (int off = 32; off; off >>= 1) s += __shfl_xor(s, off);
        if (s < bdist[5] || (s == bdist[5] && j < bidx[5])) {
            bdist[5] = s; bidx[5] = j;
#pragma unroll
            for (int t = 5; t > 0; --t) {
                if (bdist[t] < bdist[t - 1] || (bdist[t] == bdist[t - 1] && bidx[t] < bidx[t - 1])) {
                    double td = bdist[t]; bdist[t] = bdist[t - 1]; bdist[t - 1] = td;
                    int    ti = bidx[t];  bidx[t]  = bidx[t - 1];  bidx[t - 1]  = ti;
                } else break;
            }
        }
    }
    if (lane == 0) {
        int* op = idxout + (size_t)p * K_;
#pragma unroll
        for (int s = 0; s < 6; ++s) op[s] = bidx[s];
    }
}

// ---------------- k2: QKV projection, bf16 MFMA, Y[32768][768] bf16 ----------------
// C[row][col] = sum_k Xh[row][k] * W[col][k]  (W rows are B^T rows)
__global__ __launch_bounds__(256, 2) void proj_mfma(const unsigned short* __restrict__ xh,
                                                    const unsigned short* __restrict__ Wh,
                                                    unsigned short* __restrict__ Y) {
    const int tid = threadIdx.x;
    const int w = tid >> 6, l = tid & 63, cl = l & 15, g = l >> 4;
    const int row0 = blockIdx.x * 64;
    const int wsel = blockIdx.y;                    // 0=Q,1=K,2=V
    const unsigned short* W = Wh + (size_t)wsel * 65536;

    const int ar = row0 + (w << 4) + cl;
    bf16x8 a[8];
#pragma unroll
    for (int ks = 0; ks < 8; ++ks)
        a[ks] = *reinterpret_cast<const bf16x8*>(xh + ((size_t)ar << 8) + ks * 32 + g * 8);

#pragma unroll
    for (int ct = 0; ct < 16; ++ct) {
        f32x4 acc = {0.f, 0.f, 0.f, 0.f};
        const unsigned short* Wr = W + (size_t)(ct * 16 + cl) * 256 + g * 8;
#pragma unroll
        for (int ks = 0; ks < 8; ++ks) {
            bf16x8 bf = *reinterpret_cast<const bf16x8*>(Wr + ks * 32);
            acc = __builtin_amdgcn_mfma_f32_16x16x32_bf16(a[ks], bf, acc, 0, 0, 0);
        }
#pragma unroll
        for (int r = 0; r < 4; ++r) {
            size_t row = row0 + (w << 4) + (g << 2) + r;
            Y[row * 768 + wsel * 256 + ct * 16 + cl] = f2bf(acc[r]);
        }
    }
}

// ---------------- k3: per-point attention (bf16 Y) ----------------
__global__ __launch_bounds__(256) void attn_kernel(unsigned short* __restrict__ Y,
                                                   const int* __restrict__ idx,
                                                   float* __restrict__ xw) {
    const int p = blockIdx.x;
    const int b = p >> 12;
    const int tid = threadIdx.x;
    const int d = tid & 31;
    __shared__ float aw[K_];
    __shared__ int   nbs[K_];
    if (tid < K_) { aw[tid] = 0.f; nbs[tid] = idx[(size_t)p * K_ + tid]; }
    __syncthreads();
    int nb[K_];
#pragma unroll
    for (int k = 0; k < K_; ++k) nb[k] = nbs[k];

    unsigned short* Yp = Y + (size_t)p * 768;
    float q = bf2f(Yp[tid]);
    float vself = bf2f(Yp[512 + tid]);
    const size_t bbase = (size_t)(b << 12) * 768;

    float sc[K_];
#pragma unroll
    for (int k = 0; k < K_; ++k) {
        const unsigned short* Kr = Y + bbase + (size_t)nb[k] * 768 + 256;
        float s = q * bf2f(Kr[tid]);
        s += __shfl_xor(s, 16);
        s += __shfl_xor(s, 8);
        s += __shfl_xor(s, 4);
        s += __shfl_xor(s, 2);
        s += __shfl_xor(s, 1);
        sc[k] = s * 0.17677669529663687f;   // 1/sqrt(32)
    }
    float m = sc[0];
#pragma unroll
    for (int k = 1; k < K_; ++k) m = fmaxf(m, sc[k]);
    float e[K_], sum = 0.f;
#pragma unroll
    for (int k = 0; k < K_; ++k) { e[k] = __expf(sc[k] - m); sum += e[k]; }
    float inv = 1.f / sum;

    float o = 0.f;
#pragma unroll
    for (int k = 0; k < K_; ++k) {
        const unsigned short* Vr = Y + bbase + (size_t)nb[k] * 768 + 512;
        o += (e[k] * inv) * (bf2f(Vr[tid]) - vself);
    }
    if (d == 0) {
#pragma unroll
        for (int k = 0; k < K_; ++k) atomicAdd(&aw[k], e[k] * inv);
    }
    __syncthreads();
    Yp[tid] = f2bf(o);          // own Q row only read by this block -> safe
    if (tid < K_) atomicAdd(&xw[(b << 12) + nb[tid]], aw[tid] * 0.125f);
}

// ---------------- k4: out = P @ Wo^T + x (bf16 MFMA, fp32 out) ----------------
__global__ __launch_bounds__(256, 2) void out_mfma(const unsigned short* __restrict__ Y,
                                                   const unsigned short* __restrict__ WoH,
                                                   const float* __restrict__ x,
                                                   float* __restrict__ out) {
    const int tid = threadIdx.x;
    const int w = tid >> 6, l = tid & 63, cl = l & 15, g = l >> 4;
    const int row0 = blockIdx.x * 64;

    const int ar = row0 + (w << 4) + cl;
    bf16x8 a[8];
#pragma unroll
    for (int ks = 0; ks < 8; ++ks)
        a[ks] = *reinterpret_cast<const bf16x8*>(Y + (size_t)ar * 768 + ks * 32 + g * 8);

#pragma unroll
    for (int ct = 0; ct < 16; ++ct) {
        f32x4 acc = {0.f, 0.f, 0.f, 0.f};
        const unsigned short* Wr = WoH + (size_t)(ct * 16 + cl) * 256 + g * 8;
#pragma unroll
        for (int ks = 0; ks < 8; ++ks) {
            bf16x8 bf = *reinterpret_cast<const bf16x8*>(Wr + ks * 32);
            acc = __builtin_amdgcn_mfma_f32_16x16x32_bf16(a[ks], bf, acc, 0, 0, 0);
        }
#pragma unroll
        for (int r = 0; r < 4; ++r) {
            size_t row = row0 + (w << 4) + (g << 2) + r;
            size_t o = row * E_ + ct * 16 + cl;
            out[o] = acc[r] + x[o];
        }
    }
}

extern "C" void kernel_launch(void* const* d_in, const int* in_sizes, int n_in,
                              void* d_out, int out_size, void* d_ws, size_t ws_size,
                              hipStream_t stream) {
    const float* x  = (const float*)d_in[0];
    const float* Wq = (const float*)d_in[1];
    const float* Wk = (const float*)d_in[2];
    const float* Wv = (const float*)d_in[3];
    const float* Wo = (const float*)d_in[4];

    float* out = (float*)d_out;
    float* xw  = out + (size_t)NPTS * E_;   // second output [B,V]

    // workspace layout
    char* ws = (char*)d_ws;
    float*          sqw   = (float*)ws;                          // 128 KiB
    unsigned short* candw = (unsigned short*)(ws + 131072);      // 1.5 MiB (2 MiB slot)
    int*            idxw  = (int*)(ws + 2228224);                // 768 KiB (1 MiB slot)
    unsigned short* Wh    = (unsigned short*)(ws + 3276800);     // 512 KiB (4 matrices)
    unsigned short* Xh    = (unsigned short*)(ws + 3801088);     // 16 MiB
    unsigned short* Y     = (unsigned short*)(ws + 20578304);    // 48 MiB bf16 [32768][768]

    hipMemsetAsync(xw, 0, (size_t)NPTS * sizeof(float), stream);

    sq_kernel<<<NPTS / 64, 256, 0, stream>>>(x, sqw);
    cvt_kernel<<<NPTS * E_ / 2048, 256, 0, stream>>>(x, Xh);
    cvtw_kernel<<<dim3(32, 4), 256, 0, stream>>>(Wq, Wk, Wv, Wo, Wh);
    knn4_kernel<<<dim3(V_ / 64, B_), 256, 0, stream>>>(Xh, sqw, candw);
    refine_kernel<<<NPTS / 4, 256, 0, stream>>>(x, candw, idxw);
    proj_mfma<<<dim3(NPTS / 64, 3), 256, 0, stream>>>(Xh, Wh, Y);
    attn_kernel<<<NPTS, 256, 0, stream>>>(Y, idxw, xw);
    out_mfma<<<NPTS / 64, 256, 0, stream>>>(Y, Wh + 3 * 65536, x, out);
}

// Round 5
// 527.754 us; speedup vs baseline: 5.0180x; 1.0451x over previous
//
#include <hip/hip_runtime.h>
#include <cfloat>
#include <math.h>

#define B_   8
#define V_   4096
#define E_   256
#define K_   6
#define H_   8
#define HD_  32
#define NPTS (B_*V_)

typedef __bf16 bf16x8 __attribute__((ext_vector_type(8)));
typedef float  f32x4  __attribute__((ext_vector_type(4)));

__device__ __forceinline__ float bf2f(unsigned short u) {
    return __uint_as_float(((unsigned int)u) << 16);
}
__device__ __forceinline__ unsigned short f2bf(float f) {
    unsigned int u = __float_as_uint(f);
    return (unsigned short)((u + 0x7fffu + ((u >> 16) & 1u)) >> 16);
}

// ---------------- k0: fused fp32->bf16 (RNE) + squared norms ----------------
// 256 thr x 8 elems = 2048 elems = 8 rows/block; 32 threads per row.
__global__ __launch_bounds__(256) void cvtsq_kernel(const float* __restrict__ x,
                                                    unsigned short* __restrict__ xh,
                                                    float* __restrict__ sq) {
    size_t i = ((size_t)blockIdx.x * 256 + threadIdx.x) * 8;
    float4 a = *reinterpret_cast<const float4*>(x + i);
    float4 b = *reinterpret_cast<const float4*>(x + i + 4);
    ushort out[8] = { f2bf(a.x), f2bf(a.y), f2bf(a.z), f2bf(a.w),
                      f2bf(b.x), f2bf(b.y), f2bf(b.z), f2bf(b.w) };
    *reinterpret_cast<uint4*>(xh + i) = *reinterpret_cast<uint4*>(out);
    float s = a.x*a.x + a.y*a.y + a.z*a.z + a.w*a.w
            + b.x*b.x + b.y*b.y + b.z*b.z + b.w*b.w;
    s += __shfl_xor(s, 1);
    s += __shfl_xor(s, 2);
    s += __shfl_xor(s, 4);
    s += __shfl_xor(s, 8);
    s += __shfl_xor(s, 16);
    if ((threadIdx.x & 31) == 0)
        sq[blockIdx.x * 8 + (threadIdx.x >> 5)] = s;
}

// ---------------- k0c: weights fp32 -> bf16; grid.y selects matrix ----------------
__global__ __launch_bounds__(256) void cvtw_kernel(const float* __restrict__ Wq,
                                                   const float* __restrict__ Wk,
                                                   const float* __restrict__ Wv,
                                                   const float* __restrict__ Wo,
                                                   unsigned short* __restrict__ Wh) {
    const float* src = (blockIdx.y == 0) ? Wq : (blockIdx.y == 1) ? Wk
                     : (blockIdx.y == 2) ? Wv : Wo;
    unsigned short* dst = Wh + (size_t)blockIdx.y * 65536;
    size_t i = ((size_t)blockIdx.x * 256 + threadIdx.x) * 8;
    float4 a = *reinterpret_cast<const float4*>(src + i);
    float4 b = *reinterpret_cast<const float4*>(src + i + 4);
    ushort out[8] = { f2bf(a.x), f2bf(a.y), f2bf(a.z), f2bf(a.w),
                      f2bf(b.x), f2bf(b.y), f2bf(b.z), f2bf(b.w) };
    *reinterpret_cast<uint4*>(dst + i) = *reinterpret_cast<uint4*>(out);
}

// ---------------- k1: MFMA Gram + packed-key top-6 (24 cands/row/half) ----------------
// Block: 64 rows x 2048 cols (blockIdx.y = column half). 4 waves, 16 rows/wave.
// Candidate key = (monotone(d) & 0xFFFFF000) | col_low12 ; branchless 6-slot
// min/max bubble. Staging: global_load_lds, source-side XOR swizzle (involution).
__global__ __launch_bounds__(256, 4) void knn5_kernel(const unsigned short* __restrict__ xh,
                                                      const float* __restrict__ sq,
                                                      unsigned int* __restrict__ cand) {
    __shared__ __align__(16) char smem[32768];   // 2 x 16KB tile buffers / merge reuse

    const int b    = blockIdx.z;
    const int row0 = blockIdx.x * 64;
    const int colbase = blockIdx.y * 2048;
    const int tid  = threadIdx.x;
    const int w    = tid >> 6;
    const int l    = tid & 63;
    const int cl   = l & 15;
    const int g    = l >> 4;
    const float* sqb = sq + (size_t)b * V_;
    const unsigned short* Xb = xh + ((size_t)b << 12) * E_;

    // A fragments: wave w owns rows row0 + w*16 .. +15 ; full K=256 in regs
    const int ar = row0 + (w << 4) + cl;
    bf16x8 a[8];
#pragma unroll
    for (int ks = 0; ks < 8; ++ks)
        a[ks] = *reinterpret_cast<const bf16x8*>(Xb + ((size_t)ar << 8) + ks * 32 + g * 8);

    unsigned int bk[4][6];
#pragma unroll
    for (int r = 0; r < 4; ++r)
#pragma unroll
        for (int s = 0; s < 6; ++s) bk[r][s] = 0xFFFFFFFFu;

    // prologue: stage tile 0 (32 rows x 256 K bf16 = 16KB) into buf0
#pragma unroll
    for (int it = 0; it < 4; ++it) {
        int li = it * 256 + tid, row = li >> 5, sl = li & 31;
        const unsigned short* gp =
            Xb + ((size_t)(colbase + row) << 8) + ((sl ^ (row & 7)) << 3);
        __builtin_amdgcn_global_load_lds(
            (const __attribute__((address_space(1))) void*)gp,
            (__attribute__((address_space(3))) void*)(smem + li * 16), 16, 0, 0);
    }
    __syncthreads();

    for (int t = 0; t < 64; ++t) {
        const int c0  = colbase + t * 32;
        const int cur = (t & 1) * 16384;
        if (t < 63) {
            char* nb = smem + (cur ^ 16384);
            const int c0n = c0 + 32;
#pragma unroll
            for (int it = 0; it < 4; ++it) {
                int li = it * 256 + tid, row = li >> 5, sl = li & 31;
                const unsigned short* gp =
                    Xb + ((size_t)(c0n + row) << 8) + ((sl ^ (row & 7)) << 3);
                __builtin_amdgcn_global_load_lds(
                    (const __attribute__((address_space(1))) void*)gp,
                    (__attribute__((address_space(3))) void*)(nb + li * 16), 16, 0, 0);
            }
        }
        float sqv[2];
#pragma unroll
        for (int ct = 0; ct < 2; ++ct) sqv[ct] = sqb[c0 + (ct << 4) + cl];

#pragma unroll
        for (int ct = 0; ct < 2; ++ct) {
            const int brow = (ct << 4) + cl;
            const char* bbase = smem + cur + brow * 512;
            const int swz  = (brow & 7) << 4;
            const int kb16 = g << 4;
            f32x4 acc = {0.f, 0.f, 0.f, 0.f};
#pragma unroll
            for (int ks = 0; ks < 8; ++ks) {
                bf16x8 bf = *reinterpret_cast<const bf16x8*>(
                    bbase + ((ks * 64 + kb16) ^ swz));
                acc = __builtin_amdgcn_mfma_f32_16x16x32_bf16(a[ks], bf, acc, 0, 0, 0);
            }
            const unsigned int c = (unsigned int)(c0 + (ct << 4) + cl) & 4095u;
#pragma unroll
            for (int r = 0; r < 4; ++r) {
                float d = fmaf(-2.f, acc[r], sqv[ct]);
                unsigned int u = __float_as_uint(d);
                unsigned int m = u ^ ((unsigned int)((int)u >> 31) | 0x80000000u);
                unsigned int key = (m & 0xFFFFF000u) | c;
#pragma unroll
                for (int s = 0; s < 6; ++s) {
                    unsigned int lo = min(bk[r][s], key);
                    key = max(bk[r][s], key);
                    bk[r][s] = lo;
                }
            }
        }
        __syncthreads();   // prefetch landed + all reads of cur done
    }

    // ---- dump per-lane keys to LDS (stride 97 -> conflict-free scans) ----
    unsigned int* Kd = reinterpret_cast<unsigned int*>(smem);   // [64][97]
#pragma unroll
    for (int r = 0; r < 4; ++r) {
        int rl = (w << 4) + (g << 2) + r;    // C-row = (l>>4)*4 + reg
        int base = rl * 97 + cl * 6;
#pragma unroll
        for (int s = 0; s < 6; ++s) Kd[base + s] = bk[r][s];
    }
    __syncthreads();

    // ---- 4 threads/row, each keeps top-6 of its 24 -> 24 keys/row/half ----
    {
        const int row = tid >> 2, part = tid & 3;
        const unsigned int* kr = Kd + row * 97 + part * 24;
        unsigned int tk[6];
#pragma unroll
        for (int s = 0; s < 6; ++s) tk[s] = 0xFFFFFFFFu;
        for (int j = 0; j < 24; ++j) {
            unsigned int key = kr[j];
#pragma unroll
            for (int s = 0; s < 6; ++s) {
                unsigned int lo = min(tk[s], key);
                key = max(tk[s], key);
                tk[s] = lo;
            }
        }
        unsigned int* op = cand + (((size_t)b << 12) + row0 + row) * 48
                         + blockIdx.y * 24 + part * 6;
#pragma unroll
        for (int s = 0; s < 6; ++s) op[s] = tk[s];
    }
}

// ---------------- k1b: fp64 exact re-rank of 48 candidates -> top-6 ----------------
__global__ __launch_bounds__(256) void refine_kernel(const float* __restrict__ x,
                                                     const unsigned int* __restrict__ cand,
                                                     int* __restrict__ idxout) {
    int wv = threadIdx.x >> 6;
    int lane = threadIdx.x & 63;
    int p = blockIdx.x * 4 + wv;
    int b = p >> 12;
    int vi = p & 4095;
    const float* Xb = x + (size_t)b * V_ * E_;

    double xi[4];
#pragma unroll
    for (int t = 0; t < 4; ++t) xi[t] = (double)Xb[(size_t)vi * E_ + lane + t * 64];

    double bdist[6]; int bidx[6];
#pragma unroll
    for (int s = 0; s < 6; ++s) { bdist[s] = DBL_MAX; bidx[s] = 0x7fffffff; }

    for (int c = 0; c < 48; ++c) {
        int j = (int)(cand[(size_t)p * 48 + c] & 4095u);
        double s = 0.0;
#pragma unroll
        for (int t = 0; t < 4; ++t) {
            double d = xi[t] - (double)Xb[(size_t)j * E_ + lane + t * 64];
            s += d * d;
        }
#pragma unroll
        for (int off = 32; off; off >>= 1) s += __shfl_xor(s, off);
        if (s < bdist[5] || (s == bdist[5] && j < bidx[5])) {
            bdist[5] = s; bidx[5] = j;
#pragma unroll
            for (int t = 5; t > 0; --t) {
                if (bdist[t] < bdist[t - 1] || (bdist[t] == bdist[t - 1] && bidx[t] < bidx[t - 1])) {
                    double td = bdist[t]; bdist[t] = bdist[t - 1]; bdist[t - 1] = td;
                    int    ti = bidx[t];  bidx[t]  = bidx[t - 1];  bidx[t - 1]  = ti;
                } else break;
            }
        }
    }
    if (lane == 0) {
        int* op = idxout + (size_t)p * K_;
#pragma unroll
        for (int s = 0; s < 6; ++s) op[s] = bidx[s];
    }
}

// ---------------- k2: QKV projection, bf16 MFMA, Y[32768][768] bf16 ----------------
__global__ __launch_bounds__(256, 2) void proj_mfma(const unsigned short* __restrict__ xh,
                                                    const unsigned short* __restrict__ Wh,
                                                    unsigned short* __restrict__ Y) {
    const int tid = threadIdx.x;
    const int w = tid >> 6, l = tid & 63, cl = l & 15, g = l >> 4;
    const int row0 = blockIdx.x * 64;
    const int wsel = blockIdx.y;                    // 0=Q,1=K,2=V
    const unsigned short* W = Wh + (size_t)wsel * 65536;

    const int ar = row0 + (w << 4) + cl;
    bf16x8 a[8];
#pragma unroll
    for (int ks = 0; ks < 8; ++ks)
        a[ks] = *reinterpret_cast<const bf16x8*>(xh + ((size_t)ar << 8) + ks * 32 + g * 8);

#pragma unroll
    for (int ct = 0; ct < 16; ++ct) {
        f32x4 acc = {0.f, 0.f, 0.f, 0.f};
        const unsigned short* Wr = W + (size_t)(ct * 16 + cl) * 256 + g * 8;
#pragma unroll
        for (int ks = 0; ks < 8; ++ks) {
            bf16x8 bf = *reinterpret_cast<const bf16x8*>(Wr + ks * 32);
            acc = __builtin_amdgcn_mfma_f32_16x16x32_bf16(a[ks], bf, acc, 0, 0, 0);
        }
#pragma unroll
        for (int r = 0; r < 4; ++r) {
            size_t row = row0 + (w << 4) + (g << 2) + r;
            Y[row * 768 + wsel * 256 + ct * 16 + cl] = f2bf(acc[r]);
        }
    }
}

// ---------------- k3: per-point attention (bf16 Y) ----------------
__global__ __launch_bounds__(256) void attn_kernel(unsigned short* __restrict__ Y,
                                                   const int* __restrict__ idx,
                                                   float* __restrict__ xw) {
    const int p = blockIdx.x;
    const int b = p >> 12;
    const int tid = threadIdx.x;
    const int d = tid & 31;
    __shared__ float aw[K_];
    __shared__ int   nbs[K_];
    if (tid < K_) { aw[tid] = 0.f; nbs[tid] = idx[(size_t)p * K_ + tid]; }
    __syncthreads();
    int nb[K_];
#pragma unroll
    for (int k = 0; k < K_; ++k) nb[k] = nbs[k];

    unsigned short* Yp = Y + (size_t)p * 768;
    float q = bf2f(Yp[tid]);
    float vself = bf2f(Yp[512 + tid]);
    const size_t bbase = (size_t)(b << 12) * 768;

    float sc[K_];
#pragma unroll
    for (int k = 0; k < K_; ++k) {
        const unsigned short* Kr = Y + bbase + (size_t)nb[k] * 768 + 256;
        float s = q * bf2f(Kr[tid]);
        s += __shfl_xor(s, 16);
        s += __shfl_xor(s, 8);
        s += __shfl_xor(s, 4);
        s += __shfl_xor(s, 2);
        s += __shfl_xor(s, 1);
        sc[k] = s * 0.17677669529663687f;   // 1/sqrt(32)
    }
    float m = sc[0];
#pragma unroll
    for (int k = 1; k < K_; ++k) m = fmaxf(m, sc[k]);
    float e[K_], sum = 0.f;
#pragma unroll
    for (int k = 0; k < K_; ++k) { e[k] = __expf(sc[k] - m); sum += e[k]; }
    float inv = 1.f / sum;

    float o = 0.f;
#pragma unroll
    for (int k = 0; k < K_; ++k) {
        const unsigned short* Vr = Y + bbase + (size_t)nb[k] * 768 + 512;
        o += (e[k] * inv) * (bf2f(Vr[tid]) - vself);
    }
    if (d == 0) {
#pragma unroll
        for (int k = 0; k < K_; ++k) atomicAdd(&aw[k], e[k] * inv);
    }
    __syncthreads();
    Yp[tid] = f2bf(o);          // own Q row only read by this block -> safe
    if (tid < K_) atomicAdd(&xw[(b << 12) + nb[tid]], aw[tid] * 0.125f);
}

// ---------------- k4: out = P @ Wo^T + x (bf16 MFMA, fp32 out) ----------------
__global__ __launch_bounds__(256, 2) void out_mfma(const unsigned short* __restrict__ Y,
                                                   const unsigned short* __restrict__ WoH,
                                                   const float* __restrict__ x,
                                                   float* __restrict__ out) {
    const int tid = threadIdx.x;
    const int w = tid >> 6, l = tid & 63, cl = l & 15, g = l >> 4;
    const int row0 = blockIdx.x * 64;

    const int ar = row0 + (w << 4) + cl;
    bf16x8 a[8];
#pragma unroll
    for (int ks = 0; ks < 8; ++ks)
        a[ks] = *reinterpret_cast<const bf16x8*>(Y + (size_t)ar * 768 + ks * 32 + g * 8);

#pragma unroll
    for (int ct = 0; ct < 16; ++ct) {
        f32x4 acc = {0.f, 0.f, 0.f, 0.f};
        const unsigned short* Wr = WoH + (size_t)(ct * 16 + cl) * 256 + g * 8;
#pragma unroll
        for (int ks = 0; ks < 8; ++ks) {
            bf16x8 bf = *reinterpret_cast<const bf16x8*>(Wr + ks * 32);
            acc = __builtin_amdgcn_mfma_f32_16x16x32_bf16(a[ks], bf, acc, 0, 0, 0);
        }
#pragma unroll
        for (int r = 0; r < 4; ++r) {
            size_t row = row0 + (w << 4) + (g << 2) + r;
            size_t o = row * E_ + ct * 16 + cl;
            out[o] = acc[r] + x[o];
        }
    }
}

extern "C" void kernel_launch(void* const* d_in, const int* in_sizes, int n_in,
                              void* d_out, int out_size, void* d_ws, size_t ws_size,
                              hipStream_t stream) {
    const float* x  = (const float*)d_in[0];
    const float* Wq = (const float*)d_in[1];
    const float* Wk = (const float*)d_in[2];
    const float* Wv = (const float*)d_in[3];
    const float* Wo = (const float*)d_in[4];

    float* out = (float*)d_out;
    float* xw  = out + (size_t)NPTS * E_;   // second output [B,V]

    // workspace layout
    char* ws = (char*)d_ws;
    float*          sqw   = (float*)ws;                          // 128 KiB
    unsigned int*   candw = (unsigned int*)(ws + 131072);        // 6 MiB (48 uint/pt)
    int*            idxw  = (int*)(ws + 6422528);                // 768 KiB (1 MiB slot)
    unsigned short* Wh    = (unsigned short*)(ws + 7471104);     // 512 KiB (4 matrices)
    unsigned short* Xh    = (unsigned short*)(ws + 7995392);     // 16 MiB
    unsigned short* Y     = (unsigned short*)(ws + 24772608);    // 48 MiB bf16 [32768][768]

    hipMemsetAsync(xw, 0, (size_t)NPTS * sizeof(float), stream);

    cvtsq_kernel<<<NPTS * E_ / 2048, 256, 0, stream>>>(x, Xh, sqw);
    cvtw_kernel<<<dim3(32, 4), 256, 0, stream>>>(Wq, Wk, Wv, Wo, Wh);
    knn5_kernel<<<dim3(V_ / 64, 2, B_), 256, 0, stream>>>(Xh, sqw, candw);
    refine_kernel<<<NPTS / 4, 256, 0, stream>>>(x, candw, idxw);
    proj_mfma<<<dim3(NPTS / 64, 3), 256, 0, stream>>>(Xh, Wh, Y);
    attn_kernel<<<NPTS, 256, 0, stream>>>(Y, idxw, xw);
    out_mfma<<<NPTS / 64, 256, 0, stream>>>(Y, Wh + 3 * 65536, x, out);
}

// Round 6
// 390.585 us; speedup vs baseline: 6.7803x; 1.3512x over previous
//
#include <hip/hip_runtime.h>
#include <cfloat>
#include <math.h>

#define B_   8
#define V_   4096
#define E_   256
#define K_   6
#define H_   8
#define HD_  32
#define NPTS (B_*V_)

typedef __bf16 bf16x8 __attribute__((ext_vector_type(8)));
typedef float  f32x4  __attribute__((ext_vector_type(4)));

__device__ __forceinline__ float bf2f(unsigned short u) {
    return __uint_as_float(((unsigned int)u) << 16);
}
__device__ __forceinline__ unsigned short f2bf(float f) {
    unsigned int u = __float_as_uint(f);
    return (unsigned short)((u + 0x7fffu + ((u >> 16) & 1u)) >> 16);
}

// ---------------- k0: fused fp32->bf16 (RNE) + squared norms ----------------
__global__ __launch_bounds__(256) void cvtsq_kernel(const float* __restrict__ x,
                                                    unsigned short* __restrict__ xh,
                                                    float* __restrict__ sq) {
    size_t i = ((size_t)blockIdx.x * 256 + threadIdx.x) * 8;
    float4 a = *reinterpret_cast<const float4*>(x + i);
    float4 b = *reinterpret_cast<const float4*>(x + i + 4);
    ushort out[8] = { f2bf(a.x), f2bf(a.y), f2bf(a.z), f2bf(a.w),
                      f2bf(b.x), f2bf(b.y), f2bf(b.z), f2bf(b.w) };
    *reinterpret_cast<uint4*>(xh + i) = *reinterpret_cast<uint4*>(out);
    float s = a.x*a.x + a.y*a.y + a.z*a.z + a.w*a.w
            + b.x*b.x + b.y*b.y + b.z*b.z + b.w*b.w;
    s += __shfl_xor(s, 1);
    s += __shfl_xor(s, 2);
    s += __shfl_xor(s, 4);
    s += __shfl_xor(s, 8);
    s += __shfl_xor(s, 16);
    if ((threadIdx.x & 31) == 0)
        sq[blockIdx.x * 8 + (threadIdx.x >> 5)] = s;
}

// ---------------- k0c: weights fp32 -> bf16; grid.y selects matrix ----------------
__global__ __launch_bounds__(256) void cvtw_kernel(const float* __restrict__ Wq,
                                                   const float* __restrict__ Wk,
                                                   const float* __restrict__ Wv,
                                                   const float* __restrict__ Wo,
                                                   unsigned short* __restrict__ Wh) {
    const float* src = (blockIdx.y == 0) ? Wq : (blockIdx.y == 1) ? Wk
                     : (blockIdx.y == 2) ? Wv : Wo;
    unsigned short* dst = Wh + (size_t)blockIdx.y * 65536;
    size_t i = ((size_t)blockIdx.x * 256 + threadIdx.x) * 8;
    float4 a = *reinterpret_cast<const float4*>(src + i);
    float4 b = *reinterpret_cast<const float4*>(src + i + 4);
    ushort out[8] = { f2bf(a.x), f2bf(a.y), f2bf(a.z), f2bf(a.w),
                      f2bf(b.x), f2bf(b.y), f2bf(b.z), f2bf(b.w) };
    *reinterpret_cast<uint4*>(dst + i) = *reinterpret_cast<uint4*>(out);
}

// ---------------- k1: MFMA Gram + packed-key top-6 (24 cands/row/half) ----------------
__global__ __launch_bounds__(256, 4) void knn5_kernel(const unsigned short* __restrict__ xh,
                                                      const float* __restrict__ sq,
                                                      unsigned int* __restrict__ cand) {
    __shared__ __align__(16) char smem[32768];   // 2 x 16KB tile buffers / merge reuse

    const int b    = blockIdx.z;
    const int row0 = blockIdx.x * 64;
    const int colbase = blockIdx.y * 2048;
    const int tid  = threadIdx.x;
    const int w    = tid >> 6;
    const int l    = tid & 63;
    const int cl   = l & 15;
    const int g    = l >> 4;
    const float* sqb = sq + (size_t)b * V_;
    const unsigned short* Xb = xh + ((size_t)b << 12) * E_;

    const int ar = row0 + (w << 4) + cl;
    bf16x8 a[8];
#pragma unroll
    for (int ks = 0; ks < 8; ++ks)
        a[ks] = *reinterpret_cast<const bf16x8*>(Xb + ((size_t)ar << 8) + ks * 32 + g * 8);

    unsigned int bk[4][6];
#pragma unroll
    for (int r = 0; r < 4; ++r)
#pragma unroll
        for (int s = 0; s < 6; ++s) bk[r][s] = 0xFFFFFFFFu;

#pragma unroll
    for (int it = 0; it < 4; ++it) {
        int li = it * 256 + tid, row = li >> 5, sl = li & 31;
        const unsigned short* gp =
            Xb + ((size_t)(colbase + row) << 8) + ((sl ^ (row & 7)) << 3);
        __builtin_amdgcn_global_load_lds(
            (const __attribute__((address_space(1))) void*)gp,
            (__attribute__((address_space(3))) void*)(smem + li * 16), 16, 0, 0);
    }
    __syncthreads();

    for (int t = 0; t < 64; ++t) {
        const int c0  = colbase + t * 32;
        const int cur = (t & 1) * 16384;
        if (t < 63) {
            char* nb = smem + (cur ^ 16384);
            const int c0n = c0 + 32;
#pragma unroll
            for (int it = 0; it < 4; ++it) {
                int li = it * 256 + tid, row = li >> 5, sl = li & 31;
                const unsigned short* gp =
                    Xb + ((size_t)(c0n + row) << 8) + ((sl ^ (row & 7)) << 3);
                __builtin_amdgcn_global_load_lds(
                    (const __attribute__((address_space(1))) void*)gp,
                    (__attribute__((address_space(3))) void*)(nb + li * 16), 16, 0, 0);
            }
        }
        float sqv[2];
#pragma unroll
        for (int ct = 0; ct < 2; ++ct) sqv[ct] = sqb[c0 + (ct << 4) + cl];

#pragma unroll
        for (int ct = 0; ct < 2; ++ct) {
            const int brow = (ct << 4) + cl;
            const char* bbase = smem + cur + brow * 512;
            const int swz  = (brow & 7) << 4;
            const int kb16 = g << 4;
            f32x4 acc = {0.f, 0.f, 0.f, 0.f};
#pragma unroll
            for (int ks = 0; ks < 8; ++ks) {
                bf16x8 bf = *reinterpret_cast<const bf16x8*>(
                    bbase + ((ks * 64 + kb16) ^ swz));
                acc = __builtin_amdgcn_mfma_f32_16x16x32_bf16(a[ks], bf, acc, 0, 0, 0);
            }
            const unsigned int c = (unsigned int)(c0 + (ct << 4) + cl) & 4095u;
#pragma unroll
            for (int r = 0; r < 4; ++r) {
                float d = fmaf(-2.f, acc[r], sqv[ct]);
                unsigned int u = __float_as_uint(d);
                unsigned int m = u ^ ((unsigned int)((int)u >> 31) | 0x80000000u);
                unsigned int key = (m & 0xFFFFF000u) | c;
#pragma unroll
                for (int s = 0; s < 6; ++s) {
                    unsigned int lo = min(bk[r][s], key);
                    key = max(bk[r][s], key);
                    bk[r][s] = lo;
                }
            }
        }
        __syncthreads();
    }

    unsigned int* Kd = reinterpret_cast<unsigned int*>(smem);   // [64][97]
#pragma unroll
    for (int r = 0; r < 4; ++r) {
        int rl = (w << 4) + (g << 2) + r;
        int base = rl * 97 + cl * 6;
#pragma unroll
        for (int s = 0; s < 6; ++s) Kd[base + s] = bk[r][s];
    }
    __syncthreads();

    {
        const int row = tid >> 2, part = tid & 3;
        const unsigned int* kr = Kd + row * 97 + part * 24;
        unsigned int tk[6];
#pragma unroll
        for (int s = 0; s < 6; ++s) tk[s] = 0xFFFFFFFFu;
        for (int j = 0; j < 24; ++j) {
            unsigned int key = kr[j];
#pragma unroll
            for (int s = 0; s < 6; ++s) {
                unsigned int lo = min(tk[s], key);
                key = max(tk[s], key);
                tk[s] = lo;
            }
        }
        unsigned int* op = cand + (((size_t)b << 12) + row0 + row) * 48
                         + blockIdx.y * 24 + part * 6;
#pragma unroll
        for (int s = 0; s < 6; ++s) op[s] = tk[s];
    }
}

// ---------------- k1s: global key-top-16 of 48 -> ushort indices ----------------
// keys are (quantized-d<<12)|idx : lexicographic (d, idx) order == top_k tie-break.
__global__ __launch_bounds__(256) void sel_kernel(const unsigned int* __restrict__ cand,
                                                  unsigned short* __restrict__ c16) {
    int p = blockIdx.x * 256 + threadIdx.x;
    const unsigned int* cp = cand + (size_t)p * 48;
    unsigned int tk[16];
#pragma unroll
    for (int s = 0; s < 16; ++s) tk[s] = 0xFFFFFFFFu;
    for (int j = 0; j < 48; ++j) {
        unsigned int key = cp[j];
#pragma unroll
        for (int s = 0; s < 16; ++s) {
            unsigned int lo = min(tk[s], key);
            key = max(tk[s], key);
            tk[s] = lo;
        }
    }
    unsigned short* op = c16 + (size_t)p * 16;
#pragma unroll
    for (int s = 0; s < 16; ++s) op[s] = (unsigned short)(tk[s] & 4095u);
}

// ---------------- k1b: fp64 exact re-rank of 16 candidates -> top-6 ----------------
// split-wave: each 32-lane half computes one candidate (8 elems/lane, 5 xor levels)
__global__ __launch_bounds__(256) void refine_kernel(const float* __restrict__ x,
                                                     const unsigned short* __restrict__ c16,
                                                     int* __restrict__ idxout) {
    int wv = threadIdx.x >> 6;
    int lane = threadIdx.x & 63;
    int p = blockIdx.x * 4 + wv;
    int b = p >> 12;
    int vi = p & 4095;
    const float* Xb = x + ((size_t)b << 12) * E_;
    const int half = lane >> 5;
    const int hl = lane & 31;

    double xi[8];
#pragma unroll
    for (int t = 0; t < 8; ++t) xi[t] = (double)Xb[(size_t)vi * E_ + hl + t * 32];

    double bdist[6]; int bidx[6];
#pragma unroll
    for (int s = 0; s < 6; ++s) { bdist[s] = DBL_MAX; bidx[s] = 0x7fffffff; }

    const unsigned short* cp = c16 + (size_t)p * 16;
    for (int c = 0; c < 16; c += 2) {
        int jme = cp[c + half];
        const float* Xj = Xb + (size_t)jme * E_;
        double s = 0.0;
#pragma unroll
        for (int t = 0; t < 8; ++t) {
            double d = xi[t] - (double)Xj[hl + t * 32];
            s = fma(d, d, s);
        }
#pragma unroll
        for (int off = 16; off; off >>= 1) s += __shfl_xor(s, off);  // within half
        double sv[2];
        sv[0] = __shfl(s, 0);
        sv[1] = __shfl(s, 32);
        int jv[2] = { (int)cp[c], (int)cp[c + 1] };
#pragma unroll
        for (int q = 0; q < 2; ++q) {
            double sq_ = sv[q]; int j = jv[q];
            if (sq_ < bdist[5] || (sq_ == bdist[5] && j < bidx[5])) {
                bdist[5] = sq_; bidx[5] = j;
#pragma unroll
                for (int t = 5; t > 0; --t) {
                    if (bdist[t] < bdist[t - 1] ||
                        (bdist[t] == bdist[t - 1] && bidx[t] < bidx[t - 1])) {
                        double td = bdist[t]; bdist[t] = bdist[t - 1]; bdist[t - 1] = td;
                        int    ti = bidx[t];  bidx[t]  = bidx[t - 1];  bidx[t - 1]  = ti;
                    } else break;
                }
            }
        }
    }
    if (lane == 0) {
        int* op = idxout + (size_t)p * K_;
#pragma unroll
        for (int s = 0; s < 6; ++s) op[s] = bidx[s];
    }
}

// ---------------- k2: QKV projection, bf16 MFMA, Y[32768][768] bf16 ----------------
__global__ __launch_bounds__(256, 2) void proj_mfma(const unsigned short* __restrict__ xh,
                                                    const unsigned short* __restrict__ Wh,
                                                    unsigned short* __restrict__ Y) {
    const int tid = threadIdx.x;
    const int w = tid >> 6, l = tid & 63, cl = l & 15, g = l >> 4;
    const int row0 = blockIdx.x * 64;
    const int wsel = blockIdx.y;                    // 0=Q,1=K,2=V
    const unsigned short* W = Wh + (size_t)wsel * 65536;

    const int ar = row0 + (w << 4) + cl;
    bf16x8 a[8];
#pragma unroll
    for (int ks = 0; ks < 8; ++ks)
        a[ks] = *reinterpret_cast<const bf16x8*>(xh + ((size_t)ar << 8) + ks * 32 + g * 8);

#pragma unroll
    for (int ct = 0; ct < 16; ++ct) {
        f32x4 acc = {0.f, 0.f, 0.f, 0.f};
        const unsigned short* Wr = W + (size_t)(ct * 16 + cl) * 256 + g * 8;
#pragma unroll
        for (int ks = 0; ks < 8; ++ks) {
            bf16x8 bf = *reinterpret_cast<const bf16x8*>(Wr + ks * 32);
            acc = __builtin_amdgcn_mfma_f32_16x16x32_bf16(a[ks], bf, acc, 0, 0, 0);
        }
#pragma unroll
        for (int r = 0; r < 4; ++r) {
            size_t row = row0 + (w << 4) + (g << 2) + r;
            Y[row * 768 + wsel * 256 + ct * 16 + cl] = f2bf(acc[r]);
        }
    }
}

// ---------------- k3: per-point attention (bf16 Y) ----------------
__global__ __launch_bounds__(256) void attn_kernel(unsigned short* __restrict__ Y,
                                                   const int* __restrict__ idx,
                                                   float* __restrict__ xw) {
    const int p = blockIdx.x;
    const int b = p >> 12;
    const int tid = threadIdx.x;
    const int d = tid & 31;
    __shared__ float aw[K_];
    __shared__ int   nbs[K_];
    if (tid < K_) { aw[tid] = 0.f; nbs[tid] = idx[(size_t)p * K_ + tid]; }
    __syncthreads();
    int nb[K_];
#pragma unroll
    for (int k = 0; k < K_; ++k) nb[k] = nbs[k];

    unsigned short* Yp = Y + (size_t)p * 768;
    float q = bf2f(Yp[tid]);
    float vself = bf2f(Yp[512 + tid]);
    const size_t bbase = (size_t)(b << 12) * 768;

    float sc[K_];
#pragma unroll
    for (int k = 0; k < K_; ++k) {
        const unsigned short* Kr = Y + bbase + (size_t)nb[k] * 768 + 256;
        float s = q * bf2f(Kr[tid]);
        s += __shfl_xor(s, 16);
        s += __shfl_xor(s, 8);
        s += __shfl_xor(s, 4);
        s += __shfl_xor(s, 2);
        s += __shfl_xor(s, 1);
        sc[k] = s * 0.17677669529663687f;   // 1/sqrt(32)
    }
    float m = sc[0];
#pragma unroll
    for (int k = 1; k < K_; ++k) m = fmaxf(m, sc[k]);
    float e[K_], sum = 0.f;
#pragma unroll
    for (int k = 0; k < K_; ++k) { e[k] = __expf(sc[k] - m); sum += e[k]; }
    float inv = 1.f / sum;

    float o = 0.f;
#pragma unroll
    for (int k = 0; k < K_; ++k) {
        const unsigned short* Vr = Y + bbase + (size_t)nb[k] * 768 + 512;
        o += (e[k] * inv) * (bf2f(Vr[tid]) - vself);
    }
    if (d == 0) {
#pragma unroll
        for (int k = 0; k < K_; ++k) atomicAdd(&aw[k], e[k] * inv);
    }
    __syncthreads();
    Yp[tid] = f2bf(o);
    if (tid < K_) atomicAdd(&xw[(b << 12) + nb[tid]], aw[tid] * 0.125f);
}

// ---------------- k4: out = P @ Wo^T + x (bf16 MFMA, fp32 out) ----------------
__global__ __launch_bounds__(256, 2) void out_mfma(const unsigned short* __restrict__ Y,
                                                   const unsigned short* __restrict__ WoH,
                                                   const float* __restrict__ x,
                                                   float* __restrict__ out) {
    const int tid = threadIdx.x;
    const int w = tid >> 6, l = tid & 63, cl = l & 15, g = l >> 4;
    const int row0 = blockIdx.x * 64;

    const int ar = row0 + (w << 4) + cl;
    bf16x8 a[8];
#pragma unroll
    for (int ks = 0; ks < 8; ++ks)
        a[ks] = *reinterpret_cast<const bf16x8*>(Y + (size_t)ar * 768 + ks * 32 + g * 8);

#pragma unroll
    for (int ct = 0; ct < 16; ++ct) {
        f32x4 acc = {0.f, 0.f, 0.f, 0.f};
        const unsigned short* Wr = WoH + (size_t)(ct * 16 + cl) * 256 + g * 8;
#pragma unroll
        for (int ks = 0; ks < 8; ++ks) {
            bf16x8 bf = *reinterpret_cast<const bf16x8*>(Wr + ks * 32);
            acc = __builtin_amdgcn_mfma_f32_16x16x32_bf16(a[ks], bf, acc, 0, 0, 0);
        }
#pragma unroll
        for (int r = 0; r < 4; ++r) {
            size_t row = row0 + (w << 4) + (g << 2) + r;
            size_t o = row * E_ + ct * 16 + cl;
            out[o] = acc[r] + x[o];
        }
    }
}

extern "C" void kernel_launch(void* const* d_in, const int* in_sizes, int n_in,
                              void* d_out, int out_size, void* d_ws, size_t ws_size,
                              hipStream_t stream) {
    const float* x  = (const float*)d_in[0];
    const float* Wq = (const float*)d_in[1];
    const float* Wk = (const float*)d_in[2];
    const float* Wv = (const float*)d_in[3];
    const float* Wo = (const float*)d_in[4];

    float* out = (float*)d_out;
    float* xw  = out + (size_t)NPTS * E_;   // second output [B,V]

    // workspace layout
    char* ws = (char*)d_ws;
    float*          sqw   = (float*)ws;                          // 128 KiB
    unsigned int*   candw = (unsigned int*)(ws + 131072);        // 6 MiB (48 uint/pt)
    int*            idxw  = (int*)(ws + 6422528);                // 768 KiB (1 MiB slot)
    unsigned short* Wh    = (unsigned short*)(ws + 7471104);     // 512 KiB (4 matrices)
    unsigned short* c16w  = (unsigned short*)(ws + 7995392);     // 1 MiB
    unsigned short* Xh    = (unsigned short*)(ws + 9043968);     // 16 MiB
    unsigned short* Y     = (unsigned short*)(ws + 25821184);    // 48 MiB bf16 [32768][768]

    hipMemsetAsync(xw, 0, (size_t)NPTS * sizeof(float), stream);

    cvtsq_kernel<<<NPTS * E_ / 2048, 256, 0, stream>>>(x, Xh, sqw);
    cvtw_kernel<<<dim3(32, 4), 256, 0, stream>>>(Wq, Wk, Wv, Wo, Wh);
    knn5_kernel<<<dim3(V_ / 64, 2, B_), 256, 0, stream>>>(Xh, sqw, candw);
    sel_kernel<<<NPTS / 256, 256, 0, stream>>>(candw, c16w);
    refine_kernel<<<NPTS / 4, 256, 0, stream>>>(x, c16w, idxw);
    proj_mfma<<<dim3(NPTS / 64, 3), 256, 0, stream>>>(Xh, Wh, Y);
    attn_kernel<<<NPTS, 256, 0, stream>>>(Y, idxw, xw);
    out_mfma<<<NPTS / 64, 256, 0, stream>>>(Y, Wh + 3 * 65536, x, out);
}

// Round 7
// 377.219 us; speedup vs baseline: 7.0205x; 1.0354x over previous
//
#include <hip/hip_runtime.h>
#include <cfloat>
#include <math.h>

#define B_   8
#define V_   4096
#define E_   256
#define K_   6
#define H_   8
#define HD_  32
#define NPTS (B_*V_)

typedef __bf16 bf16x8 __attribute__((ext_vector_type(8)));
typedef float  f32x4  __attribute__((ext_vector_type(4)));

__device__ __forceinline__ float bf2f(unsigned short u) {
    return __uint_as_float(((unsigned int)u) << 16);
}
__device__ __forceinline__ unsigned short f2bf(float f) {
    unsigned int u = __float_as_uint(f);
    return (unsigned short)((u + 0x7fffu + ((u >> 16) & 1u)) >> 16);
}
__device__ __forceinline__ unsigned int med3u(unsigned int a, unsigned int b,
                                              unsigned int c) {
    unsigned int d;
    asm("v_med3_u32 %0, %1, %2, %3" : "=v"(d) : "v"(a), "v"(b), "v"(c));
    return d;
}

// ---------------- k0: fused fp32->bf16 (RNE) + squared norms ----------------
__global__ __launch_bounds__(256) void cvtsq_kernel(const float* __restrict__ x,
                                                    unsigned short* __restrict__ xh,
                                                    float* __restrict__ sq) {
    size_t i = ((size_t)blockIdx.x * 256 + threadIdx.x) * 8;
    float4 a = *reinterpret_cast<const float4*>(x + i);
    float4 b = *reinterpret_cast<const float4*>(x + i + 4);
    ushort out[8] = { f2bf(a.x), f2bf(a.y), f2bf(a.z), f2bf(a.w),
                      f2bf(b.x), f2bf(b.y), f2bf(b.z), f2bf(b.w) };
    *reinterpret_cast<uint4*>(xh + i) = *reinterpret_cast<uint4*>(out);
    float s = a.x*a.x + a.y*a.y + a.z*a.z + a.w*a.w
            + b.x*b.x + b.y*b.y + b.z*b.z + b.w*b.w;
    s += __shfl_xor(s, 1);
    s += __shfl_xor(s, 2);
    s += __shfl_xor(s, 4);
    s += __shfl_xor(s, 8);
    s += __shfl_xor(s, 16);
    if ((threadIdx.x & 31) == 0)
        sq[blockIdx.x * 8 + (threadIdx.x >> 5)] = s;
}

// ---------------- k0c: weights fp32 -> bf16; grid.y selects matrix ----------------
__global__ __launch_bounds__(256) void cvtw_kernel(const float* __restrict__ Wq,
                                                   const float* __restrict__ Wk,
                                                   const float* __restrict__ Wv,
                                                   const float* __restrict__ Wo,
                                                   unsigned short* __restrict__ Wh) {
    const float* src = (blockIdx.y == 0) ? Wq : (blockIdx.y == 1) ? Wk
                     : (blockIdx.y == 2) ? Wv : Wo;
    unsigned short* dst = Wh + (size_t)blockIdx.y * 65536;
    size_t i = ((size_t)blockIdx.x * 256 + threadIdx.x) * 8;
    float4 a = *reinterpret_cast<const float4*>(src + i);
    float4 b = *reinterpret_cast<const float4*>(src + i + 4);
    ushort out[8] = { f2bf(a.x), f2bf(a.y), f2bf(a.z), f2bf(a.w),
                      f2bf(b.x), f2bf(b.y), f2bf(b.z), f2bf(b.w) };
    *reinterpret_cast<uint4*>(dst + i) = *reinterpret_cast<uint4*>(out);
}

// ---------------- k1: MFMA Gram + biased-key med3 top-6 (24 cands/row/half) ----
// Rank by d_b = (sq[r]+8) + sq[c] - 2*dot  > 0  -> positive-float bits monotone.
// key = (bits(d_b) & 0xFFFFF000) | col ; 6-slot sorted list via v_med3_u32.
__global__ __launch_bounds__(256, 4) void knn6_kernel(const unsigned short* __restrict__ xh,
                                                      const float* __restrict__ sq,
                                                      unsigned int* __restrict__ cand) {
    __shared__ __align__(16) char smem[40960];   // 2x16KB tiles + 8KB sq half

    const int b    = blockIdx.z;
    const int row0 = blockIdx.x * 64;
    const int colbase = blockIdx.y * 2048;
    const int tid  = threadIdx.x;
    const int w    = tid >> 6;
    const int l    = tid & 63;
    const int cl   = l & 15;
    const int g    = l >> 4;
    const float* sqb = sq + (size_t)b * V_;
    const unsigned short* Xb = xh + ((size_t)b << 12) * E_;

    // A fragments: wave w owns rows row0 + w*16 .. +15 ; full K=256 in regs
    const int ar = row0 + (w << 4) + cl;
    bf16x8 a[8];
#pragma unroll
    for (int ks = 0; ks < 8; ++ks)
        a[ks] = *reinterpret_cast<const bf16x8*>(Xb + ((size_t)ar << 8) + ks * 32 + g * 8);

    // sq of my 4 C-rows, +8 bias (keeps d_b > 0 incl. self)
    float srq8[4];
#pragma unroll
    for (int r = 0; r < 4; ++r)
        srq8[r] = sqb[row0 + (w << 4) + (g << 2) + r] + 8.f;

    unsigned int bk[4][6];
#pragma unroll
    for (int r = 0; r < 4; ++r)
#pragma unroll
        for (int s = 0; s < 6; ++s) bk[r][s] = 0xFFFFFFFFu;

    // stage sq half (2048 floats) into LDS at 32768
#pragma unroll
    for (int it = 0; it < 2; ++it) {
        int li = it * 256 + tid;
        __builtin_amdgcn_global_load_lds(
            (const __attribute__((address_space(1))) void*)(sqb + colbase + li * 4),
            (__attribute__((address_space(3))) void*)(smem + 32768 + li * 16), 16, 0, 0);
    }
    // stage tile 0 (source-side XOR swizzle, linear LDS dest)
#pragma unroll
    for (int it = 0; it < 4; ++it) {
        int li = it * 256 + tid, row = li >> 5, sl = li & 31;
        const unsigned short* gp =
            Xb + ((size_t)(colbase + row) << 8) + ((sl ^ (row & 7)) << 3);
        __builtin_amdgcn_global_load_lds(
            (const __attribute__((address_space(1))) void*)gp,
            (__attribute__((address_space(3))) void*)(smem + li * 16), 16, 0, 0);
    }
    __syncthreads();
    const float* sqs = reinterpret_cast<const float*>(smem + 32768);

    for (int t = 0; t < 64; ++t) {
        const int cur = (t & 1) * 16384;
        if (t < 63) {
            char* nbuf = smem + (cur ^ 16384);
            const int c0n = colbase + (t + 1) * 32;
#pragma unroll
            for (int it = 0; it < 4; ++it) {
                int li = it * 256 + tid, row = li >> 5, sl = li & 31;
                const unsigned short* gp =
                    Xb + ((size_t)(c0n + row) << 8) + ((sl ^ (row & 7)) << 3);
                __builtin_amdgcn_global_load_lds(
                    (const __attribute__((address_space(1))) void*)gp,
                    (__attribute__((address_space(3))) void*)(nbuf + li * 16), 16, 0, 0);
            }
        }
#pragma unroll
        for (int ct = 0; ct < 2; ++ct) {
            const int cc = (t << 5) + (ct << 4) + cl;       // col within half
            const float sqc = sqs[cc];
            const int brow = (ct << 4) + cl;
            const char* bbase = smem + cur + brow * 512;
            const int swz  = (brow & 7) << 4;
            const int kb16 = g << 4;
            f32x4 acc = {0.f, 0.f, 0.f, 0.f};
#pragma unroll
            for (int ks = 0; ks < 8; ++ks) {
                bf16x8 bf = *reinterpret_cast<const bf16x8*>(
                    bbase + ((ks * 64 + kb16) ^ swz));
                acc = __builtin_amdgcn_mfma_f32_16x16x32_bf16(a[ks], bf, acc, 0, 0, 0);
            }
            const unsigned int c = (unsigned int)(colbase + cc) & 4095u;
#pragma unroll
            for (int r = 0; r < 4; ++r) {
                float d = fmaf(-2.f, acc[r], sqc) + srq8[r];
                unsigned int key = (__float_as_uint(d) & 0xFFFFF000u) | c;
                bk[r][5] = med3u(bk[r][4], bk[r][5], key);
                bk[r][4] = med3u(bk[r][3], bk[r][4], key);
                bk[r][3] = med3u(bk[r][2], bk[r][3], key);
                bk[r][2] = med3u(bk[r][1], bk[r][2], key);
                bk[r][1] = med3u(bk[r][0], bk[r][1], key);
                bk[r][0] = min(bk[r][0], key);
            }
        }
        __syncthreads();   // prefetch landed + all reads of cur done
    }

    // ---- dump per-lane keys to LDS (stride 97 -> conflict-free scans) ----
    unsigned int* Kd = reinterpret_cast<unsigned int*>(smem);   // [64][97]
#pragma unroll
    for (int r = 0; r < 4; ++r) {
        int rl = (w << 4) + (g << 2) + r;
        int base = rl * 97 + cl * 6;
#pragma unroll
        for (int s = 0; s < 6; ++s) Kd[base + s] = bk[r][s];
    }
    __syncthreads();

    // ---- 4 threads/row, each keeps top-6 of its 24 -> 24 keys/row/half ----
    {
        const int row = tid >> 2, part = tid & 3;
        const unsigned int* kr = Kd + row * 97 + part * 24;
        unsigned int tk[6];
#pragma unroll
        for (int s = 0; s < 6; ++s) tk[s] = 0xFFFFFFFFu;
        for (int j = 0; j < 24; ++j) {
            unsigned int key = kr[j];
            tk[5] = med3u(tk[4], tk[5], key);
            tk[4] = med3u(tk[3], tk[4], key);
            tk[3] = med3u(tk[2], tk[3], key);
            tk[2] = med3u(tk[1], tk[2], key);
            tk[1] = med3u(tk[0], tk[1], key);
            tk[0] = min(tk[0], key);
        }
        unsigned int* op = cand + (((size_t)b << 12) + row0 + row) * 48
                         + blockIdx.y * 24 + part * 6;
#pragma unroll
        for (int s = 0; s < 6; ++s) op[s] = tk[s];
    }
}

// ---------------- k1s: global key-top-16 of 48 -> ushort indices ----------------
__global__ __launch_bounds__(256) void sel_kernel(const unsigned int* __restrict__ cand,
                                                  unsigned short* __restrict__ c16) {
    int p = blockIdx.x * 256 + threadIdx.x;
    const unsigned int* cp = cand + (size_t)p * 48;
    unsigned int tk[16];
#pragma unroll
    for (int s = 0; s < 16; ++s) tk[s] = 0xFFFFFFFFu;
    for (int j = 0; j < 48; ++j) {
        unsigned int key = cp[j];
#pragma unroll
        for (int s = 15; s > 0; --s) tk[s] = med3u(tk[s - 1], tk[s], key);
        tk[0] = min(tk[0], key);
    }
    unsigned short* op = c16 + (size_t)p * 16;
#pragma unroll
    for (int s = 0; s < 16; ++s) op[s] = (unsigned short)(tk[s] & 4095u);
}

// ---------------- k1b: fp64 exact re-rank of 16 candidates -> top-6 ----------------
__global__ __launch_bounds__(256) void refine_kernel(const float* __restrict__ x,
                                                     const unsigned short* __restrict__ c16,
                                                     int* __restrict__ idxout) {
    int wv = threadIdx.x >> 6;
    int lane = threadIdx.x & 63;
    int p = blockIdx.x * 4 + wv;
    int b = p >> 12;
    int vi = p & 4095;
    const float* Xb = x + ((size_t)b << 12) * E_;
    const int half = lane >> 5;
    const int hl = lane & 31;

    double xi[8];
#pragma unroll
    for (int t = 0; t < 8; ++t) xi[t] = (double)Xb[(size_t)vi * E_ + hl + t * 32];

    double bdist[6]; int bidx[6];
#pragma unroll
    for (int s = 0; s < 6; ++s) { bdist[s] = DBL_MAX; bidx[s] = 0x7fffffff; }

    const unsigned short* cp = c16 + (size_t)p * 16;
    for (int c = 0; c < 16; c += 2) {
        int jme = cp[c + half];
        const float* Xj = Xb + (size_t)jme * E_;
        double s = 0.0;
#pragma unroll
        for (int t = 0; t < 8; ++t) {
            double d = xi[t] - (double)Xj[hl + t * 32];
            s = fma(d, d, s);
        }
#pragma unroll
        for (int off = 16; off; off >>= 1) s += __shfl_xor(s, off);  // within half
        double sv[2];
        sv[0] = __shfl(s, 0);
        sv[1] = __shfl(s, 32);
        int jv[2] = { (int)cp[c], (int)cp[c + 1] };
#pragma unroll
        for (int q = 0; q < 2; ++q) {
            double sq_ = sv[q]; int j = jv[q];
            if (sq_ < bdist[5] || (sq_ == bdist[5] && j < bidx[5])) {
                bdist[5] = sq_; bidx[5] = j;
#pragma unroll
                for (int t = 5; t > 0; --t) {
                    if (bdist[t] < bdist[t - 1] ||
                        (bdist[t] == bdist[t - 1] && bidx[t] < bidx[t - 1])) {
                        double td = bdist[t]; bdist[t] = bdist[t - 1]; bdist[t - 1] = td;
                        int    ti = bidx[t];  bidx[t]  = bidx[t - 1];  bidx[t - 1]  = ti;
                    } else break;
                }
            }
        }
    }
    if (lane == 0) {
        int* op = idxout + (size_t)p * K_;
#pragma unroll
        for (int s = 0; s < 6; ++s) op[s] = bidx[s];
    }
}

// ---------------- k2: QKV projection, bf16 MFMA, Y[32768][768] bf16 ----------------
__global__ __launch_bounds__(256, 2) void proj_mfma(const unsigned short* __restrict__ xh,
                                                    const unsigned short* __restrict__ Wh,
                                                    unsigned short* __restrict__ Y) {
    const int tid = threadIdx.x;
    const int w = tid >> 6, l = tid & 63, cl = l & 15, g = l >> 4;
    const int row0 = blockIdx.x * 64;
    const int wsel = blockIdx.y;                    // 0=Q,1=K,2=V
    const unsigned short* W = Wh + (size_t)wsel * 65536;

    const int ar = row0 + (w << 4) + cl;
    bf16x8 a[8];
#pragma unroll
    for (int ks = 0; ks < 8; ++ks)
        a[ks] = *reinterpret_cast<const bf16x8*>(xh + ((size_t)ar << 8) + ks * 32 + g * 8);

#pragma unroll
    for (int ct = 0; ct < 16; ++ct) {
        f32x4 acc = {0.f, 0.f, 0.f, 0.f};
        const unsigned short* Wr = W + (size_t)(ct * 16 + cl) * 256 + g * 8;
#pragma unroll
        for (int ks = 0; ks < 8; ++ks) {
            bf16x8 bf = *reinterpret_cast<const bf16x8*>(Wr + ks * 32);
            acc = __builtin_amdgcn_mfma_f32_16x16x32_bf16(a[ks], bf, acc, 0, 0, 0);
        }
#pragma unroll
        for (int r = 0; r < 4; ++r) {
            size_t row = row0 + (w << 4) + (g << 2) + r;
            Y[row * 768 + wsel * 256 + ct * 16 + cl] = f2bf(acc[r]);
        }
    }
}

// ---------------- k3: per-point attention (bf16 Y) ----------------
__global__ __launch_bounds__(256) void attn_kernel(unsigned short* __restrict__ Y,
                                                   const int* __restrict__ idx,
                                                   float* __restrict__ xw) {
    const int p = blockIdx.x;
    const int b = p >> 12;
    const int tid = threadIdx.x;
    const int d = tid & 31;
    __shared__ float aw[K_];
    __shared__ int   nbs[K_];
    if (tid < K_) { aw[tid] = 0.f; nbs[tid] = idx[(size_t)p * K_ + tid]; }
    __syncthreads();
    int nb[K_];
#pragma unroll
    for (int k = 0; k < K_; ++k) nb[k] = nbs[k];

    unsigned short* Yp = Y + (size_t)p * 768;
    float q = bf2f(Yp[tid]);
    float vself = bf2f(Yp[512 + tid]);
    const size_t bbase = (size_t)(b << 12) * 768;

    float sc[K_];
#pragma unroll
    for (int k = 0; k < K_; ++k) {
        const unsigned short* Kr = Y + bbase + (size_t)nb[k] * 768 + 256;
        float s = q * bf2f(Kr[tid]);
        s += __shfl_xor(s, 16);
        s += __shfl_xor(s, 8);
        s += __shfl_xor(s, 4);
        s += __shfl_xor(s, 2);
        s += __shfl_xor(s, 1);
        sc[k] = s * 0.17677669529663687f;   // 1/sqrt(32)
    }
    float m = sc[0];
#pragma unroll
    for (int k = 1; k < K_; ++k) m = fmaxf(m, sc[k]);
    float e[K_], sum = 0.f;
#pragma unroll
    for (int k = 0; k < K_; ++k) { e[k] = __expf(sc[k] - m); sum += e[k]; }
    float inv = 1.f / sum;

    float o = 0.f;
#pragma unroll
    for (int k = 0; k < K_; ++k) {
        const unsigned short* Vr = Y + bbase + (size_t)nb[k] * 768 + 512;
        o += (e[k] * inv) * (bf2f(Vr[tid]) - vself);
    }
    if (d == 0) {
#pragma unroll
        for (int k = 0; k < K_; ++k) atomicAdd(&aw[k], e[k] * inv);
    }
    __syncthreads();
    Yp[tid] = f2bf(o);
    if (tid < K_) atomicAdd(&xw[(b << 12) + nb[tid]], aw[tid] * 0.125f);
}

// ---------------- k4: out = P @ Wo^T + x (bf16 MFMA, fp32 out) ----------------
__global__ __launch_bounds__(256, 2) void out_mfma(const unsigned short* __restrict__ Y,
                                                   const unsigned short* __restrict__ WoH,
                                                   const float* __restrict__ x,
                                                   float* __restrict__ out) {
    const int tid = threadIdx.x;
    const int w = tid >> 6, l = tid & 63, cl = l & 15, g = l >> 4;
    const int row0 = blockIdx.x * 64;

    const int ar = row0 + (w << 4) + cl;
    bf16x8 a[8];
#pragma unroll
    for (int ks = 0; ks < 8; ++ks)
        a[ks] = *reinterpret_cast<const bf16x8*>(Y + (size_t)ar * 768 + ks * 32 + g * 8);

#pragma unroll
    for (int ct = 0; ct < 16; ++ct) {
        f32x4 acc = {0.f, 0.f, 0.f, 0.f};
        const unsigned short* Wr = WoH + (size_t)(ct * 16 + cl) * 256 + g * 8;
#pragma unroll
        for (int ks = 0; ks < 8; ++ks) {
            bf16x8 bf = *reinterpret_cast<const bf16x8*>(Wr + ks * 32);
            acc = __builtin_amdgcn_mfma_f32_16x16x32_bf16(a[ks], bf, acc, 0, 0, 0);
        }
#pragma unroll
        for (int r = 0; r < 4; ++r) {
            size_t row = row0 + (w << 4) + (g << 2) + r;
            size_t o = row * E_ + ct * 16 + cl;
            out[o] = acc[r] + x[o];
        }
    }
}

extern "C" void kernel_launch(void* const* d_in, const int* in_sizes, int n_in,
                              void* d_out, int out_size, void* d_ws, size_t ws_size,
                              hipStream_t stream) {
    const float* x  = (const float*)d_in[0];
    const float* Wq = (const float*)d_in[1];
    const float* Wk = (const float*)d_in[2];
    const float* Wv = (const float*)d_in[3];
    const float* Wo = (const float*)d_in[4];

    float* out = (float*)d_out;
    float* xw  = out + (size_t)NPTS * E_;   // second output [B,V]

    // workspace layout
    char* ws = (char*)d_ws;
    float*          sqw   = (float*)ws;                          // 128 KiB
    unsigned int*   candw = (unsigned int*)(ws + 131072);        // 6 MiB (48 uint/pt)
    int*            idxw  = (int*)(ws + 6422528);                // 768 KiB (1 MiB slot)
    unsigned short* Wh    = (unsigned short*)(ws + 7471104);     // 512 KiB (4 matrices)
    unsigned short* c16w  = (unsigned short*)(ws + 7995392);     // 1 MiB
    unsigned short* Xh    = (unsigned short*)(ws + 9043968);     // 16 MiB
    unsigned short* Y     = (unsigned short*)(ws + 25821184);    // 48 MiB bf16 [32768][768]

    hipMemsetAsync(xw, 0, (size_t)NPTS * sizeof(float), stream);

    cvtsq_kernel<<<NPTS * E_ / 2048, 256, 0, stream>>>(x, Xh, sqw);
    cvtw_kernel<<<dim3(32, 4), 256, 0, stream>>>(Wq, Wk, Wv, Wo, Wh);
    knn6_kernel<<<dim3(V_ / 64, 2, B_), 256, 0, stream>>>(Xh, sqw, candw);
    sel_kernel<<<NPTS / 256, 256, 0, stream>>>(candw, c16w);
    refine_kernel<<<NPTS / 4, 256, 0, stream>>>(x, c16w, idxw);
    proj_mfma<<<dim3(NPTS / 64, 3), 256, 0, stream>>>(Xh, Wh, Y);
    attn_kernel<<<NPTS, 256, 0, stream>>>(Y, idxw, xw);
    out_mfma<<<NPTS / 64, 256, 0, stream>>>(Y, Wh + 3 * 65536, x, out);
}

// Round 8
// 361.072 us; speedup vs baseline: 7.3345x; 1.0447x over previous
//
#include <hip/hip_runtime.h>
#include <cfloat>
#include <math.h>

#define B_   8
#define V_   4096
#define E_   256
#define K_   6
#define H_   8
#define HD_  32
#define NPTS (B_*V_)

typedef __bf16 bf16x8 __attribute__((ext_vector_type(8)));
typedef float  f32x4  __attribute__((ext_vector_type(4)));

__device__ __forceinline__ float bf2f(unsigned short u) {
    return __uint_as_float(((unsigned int)u) << 16);
}
__device__ __forceinline__ unsigned short f2bf(float f) {
    unsigned int u = __float_as_uint(f);
    return (unsigned short)((u + 0x7fffu + ((u >> 16) & 1u)) >> 16);
}
__device__ __forceinline__ unsigned int med3u(unsigned int a, unsigned int b,
                                              unsigned int c) {
    unsigned int d;
    asm("v_med3_u32 %0, %1, %2, %3" : "=v"(d) : "v"(a), "v"(b), "v"(c));
    return d;
}

// ------ k0: fused fp32->bf16 of x (+norms) and of the 4 weight matrices ------
// blocks [0,4096): x rows (8 elems/thread, 32 thr/row, shfl-reduced sq)
// blocks [4096,4224): weights, 32 blocks per matrix
__global__ __launch_bounds__(256) void cvtsq_kernel(const float* __restrict__ x,
                                                    const float* __restrict__ Wq,
                                                    const float* __restrict__ Wk,
                                                    const float* __restrict__ Wv,
                                                    const float* __restrict__ Wo,
                                                    unsigned short* __restrict__ xh,
                                                    unsigned short* __restrict__ Wh,
                                                    float* __restrict__ sq) {
    const int bx = blockIdx.x;
    if (bx < 4096) {
        size_t i = ((size_t)bx * 256 + threadIdx.x) * 8;
        float4 a = *reinterpret_cast<const float4*>(x + i);
        float4 b = *reinterpret_cast<const float4*>(x + i + 4);
        ushort o[8] = { f2bf(a.x), f2bf(a.y), f2bf(a.z), f2bf(a.w),
                        f2bf(b.x), f2bf(b.y), f2bf(b.z), f2bf(b.w) };
        *reinterpret_cast<uint4*>(xh + i) = *reinterpret_cast<uint4*>(o);
        float s = a.x*a.x + a.y*a.y + a.z*a.z + a.w*a.w
                + b.x*b.x + b.y*b.y + b.z*b.z + b.w*b.w;
        s += __shfl_xor(s, 1);
        s += __shfl_xor(s, 2);
        s += __shfl_xor(s, 4);
        s += __shfl_xor(s, 8);
        s += __shfl_xor(s, 16);
        if ((threadIdx.x & 31) == 0)
            sq[bx * 8 + (threadIdx.x >> 5)] = s;
    } else {
        const int wb = bx - 4096;               // 0..127
        const int m = wb >> 5;
        const float* src = (m == 0) ? Wq : (m == 1) ? Wk : (m == 2) ? Wv : Wo;
        unsigned short* dst = Wh + (size_t)m * 65536;
        size_t i = ((size_t)(wb & 31) * 256 + threadIdx.x) * 8;
        float4 a = *reinterpret_cast<const float4*>(src + i);
        float4 b = *reinterpret_cast<const float4*>(src + i + 4);
        ushort o[8] = { f2bf(a.x), f2bf(a.y), f2bf(a.z), f2bf(a.w),
                        f2bf(b.x), f2bf(b.y), f2bf(b.z), f2bf(b.w) };
        *reinterpret_cast<uint4*>(dst + i) = *reinterpret_cast<uint4*>(o);
    }
}

// ---------------- k1: MFMA Gram + biased-key med3 top-6 (24 cands/row/half) ----
// Rank by d = (sq[c]+600) - 2*dot  (>0 always since sq[c]-2dot >= -sq[r] > -600)
// key = (bits(d) & 0xFFFFF000) | col ; wave-guarded med3 bubble.
__global__ __launch_bounds__(256, 4) void knn7_kernel(const unsigned short* __restrict__ xh,
                                                      const float* __restrict__ sq,
                                                      unsigned int* __restrict__ cand) {
    __shared__ __align__(16) char smem[40960];   // 2x16KB tiles + 8KB sq half

    const int b    = blockIdx.z;
    const int row0 = blockIdx.x * 64;
    const int colbase = blockIdx.y * 2048;
    const int tid  = threadIdx.x;
    const int w    = tid >> 6;
    const int l    = tid & 63;
    const int cl   = l & 15;
    const int g    = l >> 4;
    const float* sqb = sq + (size_t)b * V_;
    const unsigned short* Xb = xh + ((size_t)b << 12) * E_;

    const int ar = row0 + (w << 4) + cl;
    bf16x8 a[8];
#pragma unroll
    for (int ks = 0; ks < 8; ++ks)
        a[ks] = *reinterpret_cast<const bf16x8*>(Xb + ((size_t)ar << 8) + ks * 32 + g * 8);

    unsigned int bk[4][6];
#pragma unroll
    for (int r = 0; r < 4; ++r)
#pragma unroll
        for (int s = 0; s < 6; ++s) bk[r][s] = 0xFFFFFFFFu;

    // stage sq half (2048 floats) into LDS at 32768
#pragma unroll
    for (int it = 0; it < 2; ++it) {
        int li = it * 256 + tid;
        __builtin_amdgcn_global_load_lds(
            (const __attribute__((address_space(1))) void*)(sqb + colbase + li * 4),
            (__attribute__((address_space(3))) void*)(smem + 32768 + li * 16), 16, 0, 0);
    }
    // stage tile 0 (source-side XOR swizzle, linear LDS dest)
#pragma unroll
    for (int it = 0; it < 4; ++it) {
        int li = it * 256 + tid, row = li >> 5, sl = li & 31;
        const unsigned short* gp =
            Xb + ((size_t)(colbase + row) << 8) + ((sl ^ (row & 7)) << 3);
        __builtin_amdgcn_global_load_lds(
            (const __attribute__((address_space(1))) void*)gp,
            (__attribute__((address_space(3))) void*)(smem + li * 16), 16, 0, 0);
    }
    __syncthreads();
    const float* sqs = reinterpret_cast<const float*>(smem + 32768);

    for (int t = 0; t < 64; ++t) {
        const int cur = (t & 1) * 16384;
        if (t < 63) {
            char* nbuf = smem + (cur ^ 16384);
            const int c0n = colbase + (t + 1) * 32;
#pragma unroll
            for (int it = 0; it < 4; ++it) {
                int li = it * 256 + tid, row = li >> 5, sl = li & 31;
                const unsigned short* gp =
                    Xb + ((size_t)(c0n + row) << 8) + ((sl ^ (row & 7)) << 3);
                __builtin_amdgcn_global_load_lds(
                    (const __attribute__((address_space(1))) void*)gp,
                    (__attribute__((address_space(3))) void*)(nbuf + li * 16), 16, 0, 0);
            }
        }
#pragma unroll
        for (int ct = 0; ct < 2; ++ct) {
            const int cc = (t << 5) + (ct << 4) + cl;       // col within half
            const float sqc600 = sqs[cc] + 600.f;
            const int brow = (ct << 4) + cl;
            const char* bbase = smem + cur + brow * 512;
            const int swz  = (brow & 7) << 4;
            const int kb16 = g << 4;
            f32x4 acc = {0.f, 0.f, 0.f, 0.f};
#pragma unroll
            for (int ks = 0; ks < 8; ++ks) {
                bf16x8 bf = *reinterpret_cast<const bf16x8*>(
                    bbase + ((ks * 64 + kb16) ^ swz));
                acc = __builtin_amdgcn_mfma_f32_16x16x32_bf16(a[ks], bf, acc, 0, 0, 0);
            }
            const unsigned int c = (unsigned int)(colbase + cc) & 4095u;
#pragma unroll
            for (int r = 0; r < 4; ++r) {
                float d = fmaf(-2.f, acc[r], sqc600);
                unsigned int key = (__float_as_uint(d) & 0xFFFFF000u) | c;
                if (__any(key < bk[r][5])) {
                    bk[r][5] = med3u(bk[r][4], bk[r][5], key);
                    bk[r][4] = med3u(bk[r][3], bk[r][4], key);
                    bk[r][3] = med3u(bk[r][2], bk[r][3], key);
                    bk[r][2] = med3u(bk[r][1], bk[r][2], key);
                    bk[r][1] = med3u(bk[r][0], bk[r][1], key);
                    bk[r][0] = min(bk[r][0], key);
                }
            }
        }
        __syncthreads();   // prefetch landed + all reads of cur done
    }

    // ---- dump per-lane keys to LDS (stride 97 -> conflict-free scans) ----
    unsigned int* Kd = reinterpret_cast<unsigned int*>(smem);   // [64][97]
#pragma unroll
    for (int r = 0; r < 4; ++r) {
        int rl = (w << 4) + (g << 2) + r;
        int base = rl * 97 + cl * 6;
#pragma unroll
        for (int s = 0; s < 6; ++s) Kd[base + s] = bk[r][s];
    }
    __syncthreads();

    // ---- 4 threads/row, each keeps top-6 of its 24 -> 24 keys/row/half ----
    {
        const int row = tid >> 2, part = tid & 3;
        const unsigned int* kr = Kd + row * 97 + part * 24;
        unsigned int tk[6];
#pragma unroll
        for (int s = 0; s < 6; ++s) tk[s] = 0xFFFFFFFFu;
        for (int j = 0; j < 24; ++j) {
            unsigned int key = kr[j];
            tk[5] = med3u(tk[4], tk[5], key);
            tk[4] = med3u(tk[3], tk[4], key);
            tk[3] = med3u(tk[2], tk[3], key);
            tk[2] = med3u(tk[1], tk[2], key);
            tk[1] = med3u(tk[0], tk[1], key);
            tk[0] = min(tk[0], key);
        }
        unsigned int* op = cand + (((size_t)b << 12) + row0 + row) * 48
                         + blockIdx.y * 24 + part * 6;
#pragma unroll
        for (int s = 0; s < 6; ++s) op[s] = tk[s];
    }
}

// ---------------- k1s: key-top-16 of 48; resolve boundary or flag ----------------
// Output depends only on the top-6 SET (softmax-sum + scatter-add are
// permutation-invariant), so when the quantized rank-6/7 gap exceeds the
// total error margin the approx set is exact -> write idx, skip refine.
__global__ __launch_bounds__(256) void sel_kernel(const unsigned int* __restrict__ cand,
                                                  unsigned short* __restrict__ c16,
                                                  int* __restrict__ idxout,
                                                  unsigned char* __restrict__ flag) {
    int p = blockIdx.x * 256 + threadIdx.x;
    const unsigned int* cp = cand + (size_t)p * 48;
    unsigned int tk[16];
#pragma unroll
    for (int s = 0; s < 16; ++s) tk[s] = 0xFFFFFFFFu;
    for (int j = 0; j < 48; ++j) {
        unsigned int key = cp[j];
#pragma unroll
        for (int s = 15; s > 0; --s) tk[s] = med3u(tk[s - 1], tk[s], key);
        tk[0] = min(tk[0], key);
    }
    unsigned short* op = c16 + (size_t)p * 16;
#pragma unroll
    for (int s = 0; s < 16; ++s) op[s] = (unsigned short)(tk[s] & 4095u);
    int* ip = idxout + (size_t)p * K_;
#pragma unroll
    for (int s = 0; s < 6; ++s) ip[s] = (int)(tk[s] & 4095u);
    float d6 = __uint_as_float(tk[5] & 0xFFFFF000u);
    float d7 = __uint_as_float(tk[6] & 0xFFFFF000u);
    flag[p] = (d7 - d6 < 1.25f) ? 1 : 0;
}

// ------- k1b: fp64 exact re-rank of 16 candidates (flagged points only) -------
__global__ __launch_bounds__(256) void refine_kernel(const float* __restrict__ x,
                                                     const unsigned short* __restrict__ c16,
                                                     const unsigned char* __restrict__ flag,
                                                     int* __restrict__ idxout) {
    int wv = threadIdx.x >> 6;
    int lane = threadIdx.x & 63;
    int p = blockIdx.x * 4 + wv;
    if (!flag[p]) return;
    int b = p >> 12;
    int vi = p & 4095;
    const float* Xb = x + ((size_t)b << 12) * E_;
    const int half = lane >> 5;
    const int hl = lane & 31;

    double xi[8];
#pragma unroll
    for (int t = 0; t < 8; ++t) xi[t] = (double)Xb[(size_t)vi * E_ + hl + t * 32];

    double bdist[6]; int bidx[6];
#pragma unroll
    for (int s = 0; s < 6; ++s) { bdist[s] = DBL_MAX; bidx[s] = 0x7fffffff; }

    const unsigned short* cp = c16 + (size_t)p * 16;
    for (int c = 0; c < 16; c += 2) {
        int jme = cp[c + half];
        const float* Xj = Xb + (size_t)jme * E_;
        double s = 0.0;
#pragma unroll
        for (int t = 0; t < 8; ++t) {
            double d = xi[t] - (double)Xj[hl + t * 32];
            s = fma(d, d, s);
        }
#pragma unroll
        for (int off = 16; off; off >>= 1) s += __shfl_xor(s, off);  // within half
        double sv[2];
        sv[0] = __shfl(s, 0);
        sv[1] = __shfl(s, 32);
        int jv[2] = { (int)cp[c], (int)cp[c + 1] };
#pragma unroll
        for (int q = 0; q < 2; ++q) {
            double sq_ = sv[q]; int j = jv[q];
            if (sq_ < bdist[5] || (sq_ == bdist[5] && j < bidx[5])) {
                bdist[5] = sq_; bidx[5] = j;
#pragma unroll
                for (int t = 5; t > 0; --t) {
                    if (bdist[t] < bdist[t - 1] ||
                        (bdist[t] == bdist[t - 1] && bidx[t] < bidx[t - 1])) {
                        double td = bdist[t]; bdist[t] = bdist[t - 1]; bdist[t - 1] = td;
                        int    ti = bidx[t];  bidx[t]  = bidx[t - 1];  bidx[t - 1]  = ti;
                    } else break;
                }
            }
        }
    }
    if (lane == 0) {
        int* op = idxout + (size_t)p * K_;
#pragma unroll
        for (int s = 0; s < 6; ++s) op[s] = bidx[s];
    }
}

// ---------------- k2: QKV projection, bf16 MFMA, Y[32768][768] bf16 ----------------
__global__ __launch_bounds__(256, 2) void proj_mfma(const unsigned short* __restrict__ xh,
                                                    const unsigned short* __restrict__ Wh,
                                                    unsigned short* __restrict__ Y) {
    const int tid = threadIdx.x;
    const int w = tid >> 6, l = tid & 63, cl = l & 15, g = l >> 4;
    const int row0 = blockIdx.x * 64;
    const int wsel = blockIdx.y;                    // 0=Q,1=K,2=V
    const unsigned short* W = Wh + (size_t)wsel * 65536;

    const int ar = row0 + (w << 4) + cl;
    bf16x8 a[8];
#pragma unroll
    for (int ks = 0; ks < 8; ++ks)
        a[ks] = *reinterpret_cast<const bf16x8*>(xh + ((size_t)ar << 8) + ks * 32 + g * 8);

#pragma unroll
    for (int ct = 0; ct < 16; ++ct) {
        f32x4 acc = {0.f, 0.f, 0.f, 0.f};
        const unsigned short* Wr = W + (size_t)(ct * 16 + cl) * 256 + g * 8;
#pragma unroll
        for (int ks = 0; ks < 8; ++ks) {
            bf16x8 bf = *reinterpret_cast<const bf16x8*>(Wr + ks * 32);
            acc = __builtin_amdgcn_mfma_f32_16x16x32_bf16(a[ks], bf, acc, 0, 0, 0);
        }
#pragma unroll
        for (int r = 0; r < 4; ++r) {
            size_t row = row0 + (w << 4) + (g << 2) + r;
            Y[row * 768 + wsel * 256 + ct * 16 + cl] = f2bf(acc[r]);
        }
    }
}

// ---------------- k3: per-point attention (bf16 Y) ----------------
__global__ __launch_bounds__(256) void attn_kernel(unsigned short* __restrict__ Y,
                                                   const int* __restrict__ idx,
                                                   float* __restrict__ xw) {
    const int p = blockIdx.x;
    const int b = p >> 12;
    const int tid = threadIdx.x;
    const int d = tid & 31;
    __shared__ float aw[K_];
    __shared__ int   nbs[K_];
    if (tid < K_) { aw[tid] = 0.f; nbs[tid] = idx[(size_t)p * K_ + tid]; }
    __syncthreads();
    int nb[K_];
#pragma unroll
    for (int k = 0; k < K_; ++k) nb[k] = nbs[k];

    unsigned short* Yp = Y + (size_t)p * 768;
    float q = bf2f(Yp[tid]);
    float vself = bf2f(Yp[512 + tid]);
    const size_t bbase = (size_t)(b << 12) * 768;

    float sc[K_];
#pragma unroll
    for (int k = 0; k < K_; ++k) {
        const unsigned short* Kr = Y + bbase + (size_t)nb[k] * 768 + 256;
        float s = q * bf2f(Kr[tid]);
        s += __shfl_xor(s, 16);
        s += __shfl_xor(s, 8);
        s += __shfl_xor(s, 4);
        s += __shfl_xor(s, 2);
        s += __shfl_xor(s, 1);
        sc[k] = s * 0.17677669529663687f;   // 1/sqrt(32)
    }
    float m = sc[0];
#pragma unroll
    for (int k = 1; k < K_; ++k) m = fmaxf(m, sc[k]);
    float e[K_], sum = 0.f;
#pragma unroll
    for (int k = 0; k < K_; ++k) { e[k] = __expf(sc[k] - m); sum += e[k]; }
    float inv = 1.f / sum;

    float o = 0.f;
#pragma unroll
    for (int k = 0; k < K_; ++k) {
        const unsigned short* Vr = Y + bbase + (size_t)nb[k] * 768 + 512;
        o += (e[k] * inv) * (bf2f(Vr[tid]) - vself);
    }
    if (d == 0) {
#pragma unroll
        for (int k = 0; k < K_; ++k) atomicAdd(&aw[k], e[k] * inv);
    }
    __syncthreads();
    Yp[tid] = f2bf(o);
    if (tid < K_) atomicAdd(&xw[(b << 12) + nb[tid]], aw[tid] * 0.125f);
}

// ---------------- k4: out = P @ Wo^T + x (bf16 MFMA, fp32 out) ----------------
__global__ __launch_bounds__(256, 2) void out_mfma(const unsigned short* __restrict__ Y,
                                                   const unsigned short* __restrict__ WoH,
                                                   const float* __restrict__ x,
                                                   float* __restrict__ out) {
    const int tid = threadIdx.x;
    const int w = tid >> 6, l = tid & 63, cl = l & 15, g = l >> 4;
    const int row0 = blockIdx.x * 64;

    const int ar = row0 + (w << 4) + cl;
    bf16x8 a[8];
#pragma unroll
    for (int ks = 0; ks < 8; ++ks)
        a[ks] = *reinterpret_cast<const bf16x8*>(Y + (size_t)ar * 768 + ks * 32 + g * 8);

#pragma unroll
    for (int ct = 0; ct < 16; ++ct) {
        f32x4 acc = {0.f, 0.f, 0.f, 0.f};
        const unsigned short* Wr = WoH + (size_t)(ct * 16 + cl) * 256 + g * 8;
#pragma unroll
        for (int ks = 0; ks < 8; ++ks) {
            bf16x8 bf = *reinterpret_cast<const bf16x8*>(Wr + ks * 32);
            acc = __builtin_amdgcn_mfma_f32_16x16x32_bf16(a[ks], bf, acc, 0, 0, 0);
        }
#pragma unroll
        for (int r = 0; r < 4; ++r) {
            size_t row = row0 + (w << 4) + (g << 2) + r;
            size_t o = row * E_ + ct * 16 + cl;
            out[o] = acc[r] + x[o];
        }
    }
}

extern "C" void kernel_launch(void* const* d_in, const int* in_sizes, int n_in,
                              void* d_out, int out_size, void* d_ws, size_t ws_size,
                              hipStream_t stream) {
    const float* x  = (const float*)d_in[0];
    const float* Wq = (const float*)d_in[1];
    const float* Wk = (const float*)d_in[2];
    const float* Wv = (const float*)d_in[3];
    const float* Wo = (const float*)d_in[4];

    float* out = (float*)d_out;
    float* xw  = out + (size_t)NPTS * E_;   // second output [B,V]

    // workspace layout
    char* ws = (char*)d_ws;
    float*          sqw   = (float*)ws;                          // 128 KiB
    unsigned int*   candw = (unsigned int*)(ws + 131072);        // 6 MiB (48 uint/pt)
    int*            idxw  = (int*)(ws + 6422528);                // 768 KiB
    unsigned char*  flagw = (unsigned char*)(ws + 7208960);      // 32 KiB
    unsigned short* Wh    = (unsigned short*)(ws + 7471104);     // 512 KiB (4 matrices)
    unsigned short* c16w  = (unsigned short*)(ws + 7995392);     // 1 MiB
    unsigned short* Xh    = (unsigned short*)(ws + 9043968);     // 16 MiB
    unsigned short* Y     = (unsigned short*)(ws + 25821184);    // 48 MiB bf16 [32768][768]

    hipMemsetAsync(xw, 0, (size_t)NPTS * sizeof(float), stream);

    cvtsq_kernel<<<4096 + 128, 256, 0, stream>>>(x, Wq, Wk, Wv, Wo, Xh, Wh, sqw);
    knn7_kernel<<<dim3(V_ / 64, 2, B_), 256, 0, stream>>>(Xh, sqw, candw);
    sel_kernel<<<NPTS / 256, 256, 0, stream>>>(candw, c16w, idxw, flagw);
    refine_kernel<<<NPTS / 4, 256, 0, stream>>>(x, c16w, flagw, idxw);
    proj_mfma<<<dim3(NPTS / 64, 3), 256, 0, stream>>>(Xh, Wh, Y);
    attn_kernel<<<NPTS, 256, 0, stream>>>(Y, idxw, xw);
    out_mfma<<<NPTS / 64, 256, 0, stream>>>(Y, Wh + 3 * 65536, x, out);
}

// Round 9
// 336.837 us; speedup vs baseline: 7.8622x; 1.0720x over previous
//
#include <hip/hip_runtime.h>
#include <cfloat>
#include <math.h>

#define B_   8
#define V_   4096
#define E_   256
#define K_   6
#define H_   8
#define HD_  32
#define NPTS (B_*V_)

typedef __bf16 bf16x8 __attribute__((ext_vector_type(8)));
typedef float  f32x4  __attribute__((ext_vector_type(4)));

__device__ __forceinline__ float bf2f(unsigned short u) {
    return __uint_as_float(((unsigned int)u) << 16);
}
__device__ __forceinline__ unsigned short f2bf(float f) {
    unsigned int u = __float_as_uint(f);
    return (unsigned short)((u + 0x7fffu + ((u >> 16) & 1u)) >> 16);
}
__device__ __forceinline__ unsigned int med3u(unsigned int a, unsigned int b,
                                              unsigned int c) {
    unsigned int d;
    asm("v_med3_u32 %0, %1, %2, %3" : "=v"(d) : "v"(a), "v"(b), "v"(c));
    return d;
}

// ------ k0: fused fp32->bf16 of x (+norms) and of the 4 weight matrices ------
__global__ __launch_bounds__(256) void cvtsq_kernel(const float* __restrict__ x,
                                                    const float* __restrict__ Wq,
                                                    const float* __restrict__ Wk,
                                                    const float* __restrict__ Wv,
                                                    const float* __restrict__ Wo,
                                                    unsigned short* __restrict__ xh,
                                                    unsigned short* __restrict__ Wh,
                                                    float* __restrict__ sq) {
    const int bx = blockIdx.x;
    if (bx < 4096) {
        size_t i = ((size_t)bx * 256 + threadIdx.x) * 8;
        float4 a = *reinterpret_cast<const float4*>(x + i);
        float4 b = *reinterpret_cast<const float4*>(x + i + 4);
        ushort o[8] = { f2bf(a.x), f2bf(a.y), f2bf(a.z), f2bf(a.w),
                        f2bf(b.x), f2bf(b.y), f2bf(b.z), f2bf(b.w) };
        *reinterpret_cast<uint4*>(xh + i) = *reinterpret_cast<uint4*>(o);
        float s = a.x*a.x + a.y*a.y + a.z*a.z + a.w*a.w
                + b.x*b.x + b.y*b.y + b.z*b.z + b.w*b.w;
        s += __shfl_xor(s, 1);
        s += __shfl_xor(s, 2);
        s += __shfl_xor(s, 4);
        s += __shfl_xor(s, 8);
        s += __shfl_xor(s, 16);
        if ((threadIdx.x & 31) == 0)
            sq[bx * 8 + (threadIdx.x >> 5)] = s;
    } else {
        const int wb = bx - 4096;               // 0..127
        const int m = wb >> 5;
        const float* src = (m == 0) ? Wq : (m == 1) ? Wk : (m == 2) ? Wv : Wo;
        unsigned short* dst = Wh + (size_t)m * 65536;
        size_t i = ((size_t)(wb & 31) * 256 + threadIdx.x) * 8;
        float4 a = *reinterpret_cast<const float4*>(src + i);
        float4 b = *reinterpret_cast<const float4*>(src + i + 4);
        ushort o[8] = { f2bf(a.x), f2bf(a.y), f2bf(a.z), f2bf(a.w),
                        f2bf(b.x), f2bf(b.y), f2bf(b.z), f2bf(b.w) };
        *reinterpret_cast<uint4*>(dst + i) = *reinterpret_cast<uint4*>(o);
    }
}

// ---------------- k1: MFMA Gram + integer-key med3 top-6 (24 cands/row/half) ----
// d_b = (sq[c]+600) - 2*dot  in (240,1680) ; key = u32(d_b*512)<<12 | col
// (monotone, step 1/512). Unguarded 6-slot v_med3_u32 bubble (R8 lesson:
// wave-any guard never skips -> pure overhead).
__global__ __launch_bounds__(256, 4) void knn8_kernel(const unsigned short* __restrict__ xh,
                                                      const float* __restrict__ sq,
                                                      unsigned int* __restrict__ cand) {
    __shared__ __align__(16) char smem[40960];   // 2x16KB tiles + 8KB sq half

    const int b    = blockIdx.z;
    const int row0 = blockIdx.x * 64;
    const int colbase = blockIdx.y * 2048;
    const int tid  = threadIdx.x;
    const int w    = tid >> 6;
    const int l    = tid & 63;
    const int cl   = l & 15;
    const int g    = l >> 4;
    const float* sqb = sq + (size_t)b * V_;
    const unsigned short* Xb = xh + ((size_t)b << 12) * E_;

    const int ar = row0 + (w << 4) + cl;
    bf16x8 a[8];
#pragma unroll
    for (int ks = 0; ks < 8; ++ks)
        a[ks] = *reinterpret_cast<const bf16x8*>(Xb + ((size_t)ar << 8) + ks * 32 + g * 8);

    unsigned int bk[4][6];
#pragma unroll
    for (int r = 0; r < 4; ++r)
#pragma unroll
        for (int s = 0; s < 6; ++s) bk[r][s] = 0xFFFFFFFFu;

    // stage sq half (2048 floats) into LDS at 32768
#pragma unroll
    for (int it = 0; it < 2; ++it) {
        int li = it * 256 + tid;
        __builtin_amdgcn_global_load_lds(
            (const __attribute__((address_space(1))) void*)(sqb + colbase + li * 4),
            (__attribute__((address_space(3))) void*)(smem + 32768 + li * 16), 16, 0, 0);
    }
    // stage tile 0 (source-side XOR swizzle, linear LDS dest)
#pragma unroll
    for (int it = 0; it < 4; ++it) {
        int li = it * 256 + tid, row = li >> 5, sl = li & 31;
        const unsigned short* gp =
            Xb + ((size_t)(colbase + row) << 8) + ((sl ^ (row & 7)) << 3);
        __builtin_amdgcn_global_load_lds(
            (const __attribute__((address_space(1))) void*)gp,
            (__attribute__((address_space(3))) void*)(smem + li * 16), 16, 0, 0);
    }
    __syncthreads();
    const float* sqs = reinterpret_cast<const float*>(smem + 32768);

    for (int t = 0; t < 64; ++t) {
        const int cur = (t & 1) * 16384;
        if (t < 63) {
            char* nbuf = smem + (cur ^ 16384);
            const int c0n = colbase + (t + 1) * 32;
#pragma unroll
            for (int it = 0; it < 4; ++it) {
                int li = it * 256 + tid, row = li >> 5, sl = li & 31;
                const unsigned short* gp =
                    Xb + ((size_t)(c0n + row) << 8) + ((sl ^ (row & 7)) << 3);
                __builtin_amdgcn_global_load_lds(
                    (const __attribute__((address_space(1))) void*)gp,
                    (__attribute__((address_space(3))) void*)(nbuf + li * 16), 16, 0, 0);
            }
        }
#pragma unroll
        for (int ct = 0; ct < 2; ++ct) {
            const int cc = (t << 5) + (ct << 4) + cl;       // col within half
            const float sqc512 = (sqs[cc] + 600.f) * 512.f;
            const int brow = (ct << 4) + cl;
            const char* bbase = smem + cur + brow * 512;
            const int swz  = (brow & 7) << 4;
            const int kb16 = g << 4;
            f32x4 acc = {0.f, 0.f, 0.f, 0.f};
#pragma unroll
            for (int ks = 0; ks < 8; ++ks) {
                bf16x8 bf = *reinterpret_cast<const bf16x8*>(
                    bbase + ((ks * 64 + kb16) ^ swz));
                acc = __builtin_amdgcn_mfma_f32_16x16x32_bf16(a[ks], bf, acc, 0, 0, 0);
            }
            const unsigned int c = (unsigned int)(colbase + cc) & 4095u;
#pragma unroll
            for (int r = 0; r < 4; ++r) {
                float d = fmaf(-1024.f, acc[r], sqc512);      // (d_b)*512
                unsigned int key = ((unsigned int)d << 12) | c;
                bk[r][5] = med3u(bk[r][4], bk[r][5], key);
                bk[r][4] = med3u(bk[r][3], bk[r][4], key);
                bk[r][3] = med3u(bk[r][2], bk[r][3], key);
                bk[r][2] = med3u(bk[r][1], bk[r][2], key);
                bk[r][1] = med3u(bk[r][0], bk[r][1], key);
                bk[r][0] = min(bk[r][0], key);
            }
        }
        __syncthreads();   // prefetch landed + all reads of cur done
    }

    // ---- dump per-lane keys to LDS (stride 97 -> conflict-free scans) ----
    unsigned int* Kd = reinterpret_cast<unsigned int*>(smem);   // [64][97]
#pragma unroll
    for (int r = 0; r < 4; ++r) {
        int rl = (w << 4) + (g << 2) + r;
        int base = rl * 97 + cl * 6;
#pragma unroll
        for (int s = 0; s < 6; ++s) Kd[base + s] = bk[r][s];
    }
    __syncthreads();

    // ---- 4 threads/row, each keeps top-6 of its 24 -> 24 keys/row/half ----
    {
        const int row = tid >> 2, part = tid & 3;
        const unsigned int* kr = Kd + row * 97 + part * 24;
        unsigned int tk[6];
#pragma unroll
        for (int s = 0; s < 6; ++s) tk[s] = 0xFFFFFFFFu;
        for (int j = 0; j < 24; ++j) {
            unsigned int key = kr[j];
            tk[5] = med3u(tk[4], tk[5], key);
            tk[4] = med3u(tk[3], tk[4], key);
            tk[3] = med3u(tk[2], tk[3], key);
            tk[2] = med3u(tk[1], tk[2], key);
            tk[1] = med3u(tk[0], tk[1], key);
            tk[0] = min(tk[0], key);
        }
        unsigned int* op = cand + (((size_t)b << 12) + row0 + row) * 48
                         + blockIdx.y * 24 + part * 6;
#pragma unroll
        for (int s = 0; s < 6; ++s) op[s] = tk[s];
    }
}

// ---------------- k1s: key-top-16 of 48; resolve boundary or flag ----------------
// Integer keys: step 1/512 -> flag margin dominated by bf16-Gram noise only.
__global__ __launch_bounds__(256) void sel_kernel(const unsigned int* __restrict__ cand,
                                                  unsigned short* __restrict__ c16,
                                                  int* __restrict__ idxout,
                                                  unsigned char* __restrict__ flag) {
    int p = blockIdx.x * 256 + threadIdx.x;
    const unsigned int* cp = cand + (size_t)p * 48;
    unsigned int tk[16];
#pragma unroll
    for (int s = 0; s < 16; ++s) tk[s] = 0xFFFFFFFFu;
    for (int j = 0; j < 48; ++j) {
        unsigned int key = cp[j];
#pragma unroll
        for (int s = 15; s > 0; --s) tk[s] = med3u(tk[s - 1], tk[s], key);
        tk[0] = min(tk[0], key);
    }
    unsigned short* op = c16 + (size_t)p * 16;
#pragma unroll
    for (int s = 0; s < 16; ++s) op[s] = (unsigned short)(tk[s] & 4095u);
    int* ip = idxout + (size_t)p * K_;
#pragma unroll
    for (int s = 0; s < 6; ++s) ip[s] = (int)(tk[s] & 4095u);
    float d6 = (float)(tk[5] >> 12) * 0.001953125f;
    float d7 = (float)(tk[6] >> 12) * 0.001953125f;
    flag[p] = (d7 - d6 < 0.4f) ? 1 : 0;
}

// ------- k1b: fp64 exact re-rank of 16 candidates (flagged points only) -------
// XCD-swizzled block->point map: each XCD's blocks stay within one batch
// (x rows 4MB/batch ~ one XCD L2).
__global__ __launch_bounds__(256) void refine_kernel(const float* __restrict__ x,
                                                     const unsigned short* __restrict__ c16,
                                                     const unsigned char* __restrict__ flag,
                                                     int* __restrict__ idxout) {
    int wv = threadIdx.x >> 6;
    int lane = threadIdx.x & 63;
    const int bid = blockIdx.x;
    const int nbk = ((bid & 7) << 10) | (bid >> 3);   // bijective, 1024 blocks/batch
    int p = nbk * 4 + wv;
    if (!flag[p]) return;
    int b = p >> 12;
    int vi = p & 4095;
    const float* Xb = x + ((size_t)b << 12) * E_;
    const int half = lane >> 5;
    const int hl = lane & 31;

    double xi[8];
#pragma unroll
    for (int t = 0; t < 8; ++t) xi[t] = (double)Xb[(size_t)vi * E_ + hl + t * 32];

    double bdist[6]; int bidx[6];
#pragma unroll
    for (int s = 0; s < 6; ++s) { bdist[s] = DBL_MAX; bidx[s] = 0x7fffffff; }

    const unsigned short* cp = c16 + (size_t)p * 16;
    for (int c = 0; c < 16; c += 2) {
        int jme = cp[c + half];
        const float* Xj = Xb + (size_t)jme * E_;
        double s = 0.0;
#pragma unroll
        for (int t = 0; t < 8; ++t) {
            double d = xi[t] - (double)Xj[hl + t * 32];
            s = fma(d, d, s);
        }
#pragma unroll
        for (int off = 16; off; off >>= 1) s += __shfl_xor(s, off);  // within half
        double sv[2];
        sv[0] = __shfl(s, 0);
        sv[1] = __shfl(s, 32);
        int jv[2] = { (int)cp[c], (int)cp[c + 1] };
#pragma unroll
        for (int q = 0; q < 2; ++q) {
            double sq_ = sv[q]; int j = jv[q];
            if (sq_ < bdist[5] || (sq_ == bdist[5] && j < bidx[5])) {
                bdist[5] = sq_; bidx[5] = j;
#pragma unroll
                for (int t = 5; t > 0; --t) {
                    if (bdist[t] < bdist[t - 1] ||
                        (bdist[t] == bdist[t - 1] && bidx[t] < bidx[t - 1])) {
                        double td = bdist[t]; bdist[t] = bdist[t - 1]; bdist[t - 1] = td;
                        int    ti = bidx[t];  bidx[t]  = bidx[t - 1];  bidx[t - 1]  = ti;
                    } else break;
                }
            }
        }
    }
    if (lane == 0) {
        int* op = idxout + (size_t)p * K_;
#pragma unroll
        for (int s = 0; s < 6; ++s) op[s] = bidx[s];
    }
}

// ---------------- k2: QKV projection, bf16 MFMA, Y[32768][768] bf16 ----------------
__global__ __launch_bounds__(256, 2) void proj_mfma(const unsigned short* __restrict__ xh,
                                                    const unsigned short* __restrict__ Wh,
                                                    unsigned short* __restrict__ Y) {
    const int tid = threadIdx.x;
    const int w = tid >> 6, l = tid & 63, cl = l & 15, g = l >> 4;
    const int row0 = blockIdx.x * 64;
    const int wsel = blockIdx.y;                    // 0=Q,1=K,2=V
    const unsigned short* W = Wh + (size_t)wsel * 65536;

    const int ar = row0 + (w << 4) + cl;
    bf16x8 a[8];
#pragma unroll
    for (int ks = 0; ks < 8; ++ks)
        a[ks] = *reinterpret_cast<const bf16x8*>(xh + ((size_t)ar << 8) + ks * 32 + g * 8);

#pragma unroll
    for (int ct = 0; ct < 16; ++ct) {
        f32x4 acc = {0.f, 0.f, 0.f, 0.f};
        const unsigned short* Wr = W + (size_t)(ct * 16 + cl) * 256 + g * 8;
#pragma unroll
        for (int ks = 0; ks < 8; ++ks) {
            bf16x8 bf = *reinterpret_cast<const bf16x8*>(Wr + ks * 32);
            acc = __builtin_amdgcn_mfma_f32_16x16x32_bf16(a[ks], bf, acc, 0, 0, 0);
        }
#pragma unroll
        for (int r = 0; r < 4; ++r) {
            size_t row = row0 + (w << 4) + (g << 2) + r;
            Y[row * 768 + wsel * 256 + ct * 16 + cl] = f2bf(acc[r]);
        }
    }
}

// ---------------- k3: per-point attention (bf16 Y), XCD-batch swizzle ----------------
__global__ __launch_bounds__(256) void attn_kernel(unsigned short* __restrict__ Y,
                                                   const int* __restrict__ idx,
                                                   float* __restrict__ xw) {
    const int bid = blockIdx.x;
    const int p = ((bid & 7) << 12) | (bid >> 3);   // bijective; batch = bid&7
    const int b = p >> 12;
    const int tid = threadIdx.x;
    const int d = tid & 31;
    __shared__ float aw[K_];
    __shared__ int   nbs[K_];
    if (tid < K_) { aw[tid] = 0.f; nbs[tid] = idx[(size_t)p * K_ + tid]; }
    __syncthreads();
    int nb[K_];
#pragma unroll
    for (int k = 0; k < K_; ++k) nb[k] = nbs[k];

    unsigned short* Yp = Y + (size_t)p * 768;
    float q = bf2f(Yp[tid]);
    float vself = bf2f(Yp[512 + tid]);
    const size_t bbase = (size_t)(b << 12) * 768;

    float sc[K_];
#pragma unroll
    for (int k = 0; k < K_; ++k) {
        const unsigned short* Kr = Y + bbase + (size_t)nb[k] * 768 + 256;
        float s = q * bf2f(Kr[tid]);
        s += __shfl_xor(s, 16);
        s += __shfl_xor(s, 8);
        s += __shfl_xor(s, 4);
        s += __shfl_xor(s, 2);
        s += __shfl_xor(s, 1);
        sc[k] = s * 0.17677669529663687f;   // 1/sqrt(32)
    }
    float m = sc[0];
#pragma unroll
    for (int k = 1; k < K_; ++k) m = fmaxf(m, sc[k]);
    float e[K_], sum = 0.f;
#pragma unroll
    for (int k = 0; k < K_; ++k) { e[k] = __expf(sc[k] - m); sum += e[k]; }
    float inv = 1.f / sum;

    float o = 0.f;
#pragma unroll
    for (int k = 0; k < K_; ++k) {
        const unsigned short* Vr = Y + bbase + (size_t)nb[k] * 768 + 512;
        o += (e[k] * inv) * (bf2f(Vr[tid]) - vself);
    }
    if (d == 0) {
#pragma unroll
        for (int k = 0; k < K_; ++k) atomicAdd(&aw[k], e[k] * inv);
    }
    __syncthreads();
    Yp[tid] = f2bf(o);
    if (tid < K_) atomicAdd(&xw[(b << 12) + nb[tid]], aw[tid] * 0.125f);
}

// ---------------- k4: out = P @ Wo^T + x (bf16 MFMA, fp32 out) ----------------
__global__ __launch_bounds__(256, 2) void out_mfma(const unsigned short* __restrict__ Y,
                                                   const unsigned short* __restrict__ WoH,
                                                   const float* __restrict__ x,
                                                   float* __restrict__ out) {
    const int tid = threadIdx.x;
    const int w = tid >> 6, l = tid & 63, cl = l & 15, g = l >> 4;
    const int row0 = blockIdx.x * 64;

    const int ar = row0 + (w << 4) + cl;
    bf16x8 a[8];
#pragma unroll
    for (int ks = 0; ks < 8; ++ks)
        a[ks] = *reinterpret_cast<const bf16x8*>(Y + (size_t)ar * 768 + ks * 32 + g * 8);

#pragma unroll
    for (int ct = 0; ct < 16; ++ct) {
        f32x4 acc = {0.f, 0.f, 0.f, 0.f};
        const unsigned short* Wr = WoH + (size_t)(ct * 16 + cl) * 256 + g * 8;
#pragma unroll
        for (int ks = 0; ks < 8; ++ks) {
            bf16x8 bf = *reinterpret_cast<const bf16x8*>(Wr + ks * 32);
            acc = __builtin_amdgcn_mfma_f32_16x16x32_bf16(a[ks], bf, acc, 0, 0, 0);
        }
#pragma unroll
        for (int r = 0; r < 4; ++r) {
            size_t row = row0 + (w << 4) + (g << 2) + r;
            size_t o = row * E_ + ct * 16 + cl;
            out[o] = acc[r] + x[o];
        }
    }
}

extern "C" void kernel_launch(void* const* d_in, const int* in_sizes, int n_in,
                              void* d_out, int out_size, void* d_ws, size_t ws_size,
                              hipStream_t stream) {
    const float* x  = (const float*)d_in[0];
    const float* Wq = (const float*)d_in[1];
    const float* Wk = (const float*)d_in[2];
    const float* Wv = (const float*)d_in[3];
    const float* Wo = (const float*)d_in[4];

    float* out = (float*)d_out;
    float* xw  = out + (size_t)NPTS * E_;   // second output [B,V]

    // workspace layout
    char* ws = (char*)d_ws;
    float*          sqw   = (float*)ws;                          // 128 KiB
    unsigned int*   candw = (unsigned int*)(ws + 131072);        // 6 MiB (48 uint/pt)
    int*            idxw  = (int*)(ws + 6422528);                // 768 KiB
    unsigned char*  flagw = (unsigned char*)(ws + 7208960);      // 32 KiB
    unsigned short* Wh    = (unsigned short*)(ws + 7471104);     // 512 KiB (4 matrices)
    unsigned short* c16w  = (unsigned short*)(ws + 7995392);     // 1 MiB
    unsigned short* Xh    = (unsigned short*)(ws + 9043968);     // 16 MiB
    unsigned short* Y     = (unsigned short*)(ws + 25821184);    // 48 MiB bf16 [32768][768]

    hipMemsetAsync(xw, 0, (size_t)NPTS * sizeof(float), stream);

    cvtsq_kernel<<<4096 + 128, 256, 0, stream>>>(x, Wq, Wk, Wv, Wo, Xh, Wh, sqw);
    knn8_kernel<<<dim3(V_ / 64, 2, B_), 256, 0, stream>>>(Xh, sqw, candw);
    sel_kernel<<<NPTS / 256, 256, 0, stream>>>(candw, c16w, idxw, flagw);
    refine_kernel<<<NPTS / 4, 256, 0, stream>>>(x, c16w, flagw, idxw);
    proj_mfma<<<dim3(NPTS / 64, 3), 256, 0, stream>>>(Xh, Wh, Y);
    attn_kernel<<<NPTS, 256, 0, stream>>>(Y, idxw, xw);
    out_mfma<<<NPTS / 64, 256, 0, stream>>>(Y, Wh + 3 * 65536, x, out);
}

// Round 10
// 334.505 us; speedup vs baseline: 7.9170x; 1.0070x over previous
//
#include <hip/hip_runtime.h>
#include <cfloat>
#include <math.h>

#define B_   8
#define V_   4096
#define E_   256
#define K_   6
#define H_   8
#define HD_  32
#define NPTS (B_*V_)

typedef __bf16 bf16x8 __attribute__((ext_vector_type(8)));
typedef float  f32x4  __attribute__((ext_vector_type(4)));
typedef float  f32x16 __attribute__((ext_vector_type(16)));

__device__ __forceinline__ float bf2f(unsigned short u) {
    return __uint_as_float(((unsigned int)u) << 16);
}
__device__ __forceinline__ unsigned short f2bf(float f) {
    unsigned int u = __float_as_uint(f);
    return (unsigned short)((u + 0x7fffu + ((u >> 16) & 1u)) >> 16);
}
__device__ __forceinline__ unsigned int med3u(unsigned int a, unsigned int b,
                                              unsigned int c) {
    unsigned int d;
    asm("v_med3_u32 %0, %1, %2, %3" : "=v"(d) : "v"(a), "v"(b), "v"(c));
    return d;
}

// ------ k0: fused fp32->bf16 of x (+norms) and of the 4 weight matrices ------
__global__ __launch_bounds__(256) void cvtsq_kernel(const float* __restrict__ x,
                                                    const float* __restrict__ Wq,
                                                    const float* __restrict__ Wk,
                                                    const float* __restrict__ Wv,
                                                    const float* __restrict__ Wo,
                                                    unsigned short* __restrict__ xh,
                                                    unsigned short* __restrict__ Wh,
                                                    float* __restrict__ sq) {
    const int bx = blockIdx.x;
    if (bx < 4096) {
        size_t i = ((size_t)bx * 256 + threadIdx.x) * 8;
        float4 a = *reinterpret_cast<const float4*>(x + i);
        float4 b = *reinterpret_cast<const float4*>(x + i + 4);
        ushort o[8] = { f2bf(a.x), f2bf(a.y), f2bf(a.z), f2bf(a.w),
                        f2bf(b.x), f2bf(b.y), f2bf(b.z), f2bf(b.w) };
        *reinterpret_cast<uint4*>(xh + i) = *reinterpret_cast<uint4*>(o);
        float s = a.x*a.x + a.y*a.y + a.z*a.z + a.w*a.w
                + b.x*b.x + b.y*b.y + b.z*b.z + b.w*b.w;
        s += __shfl_xor(s, 1);
        s += __shfl_xor(s, 2);
        s += __shfl_xor(s, 4);
        s += __shfl_xor(s, 8);
        s += __shfl_xor(s, 16);
        if ((threadIdx.x & 31) == 0)
            sq[bx * 8 + (threadIdx.x >> 5)] = s;
    } else {
        const int wb = bx - 4096;               // 0..127
        const int m = wb >> 5;
        const float* src = (m == 0) ? Wq : (m == 1) ? Wk : (m == 2) ? Wv : Wo;
        unsigned short* dst = Wh + (size_t)m * 65536;
        size_t i = ((size_t)(wb & 31) * 256 + threadIdx.x) * 8;
        float4 a = *reinterpret_cast<const float4*>(src + i);
        float4 b = *reinterpret_cast<const float4*>(src + i + 4);
        ushort o[8] = { f2bf(a.x), f2bf(a.y), f2bf(a.z), f2bf(a.w),
                        f2bf(b.x), f2bf(b.y), f2bf(b.z), f2bf(b.w) };
        *reinterpret_cast<uint4*>(dst + i) = *reinterpret_cast<uint4*>(o);
    }
}

// ------ k0b: permute (sq+600)*512 into MFMA reg order ------
// sqp[((b*4+stripe)*32 + t)*32 + h*16 + reg] = (sq[b][stripe*1024 + t*32 +
//   (reg&3)+8*(reg>>2)+4*h] + 600)*512
__global__ __launch_bounds__(256) void sqp_kernel(const float* __restrict__ sq,
                                                  float* __restrict__ sqp) {
    int i = blockIdx.x * 256 + threadIdx.x;     // 32768 entries
    int reg = i & 15, h = (i >> 4) & 1, t = (i >> 5) & 31;
    int stripe = (i >> 10) & 3, b = i >> 12;
    int col = stripe * 1024 + t * 32 + (reg & 3) + 8 * (reg >> 2) + 4 * h;
    sqp[i] = (sq[b * 4096 + col] + 600.f) * 512.f;
}

// ---- k1: 32x32x16 MFMA Gram (swapped operands) + per-lane row top-6 ----
// Block: 128 rows x 1024 cols (stripe = blockIdx.y). 4 waves, 32 rows/wave.
// A-operand = candidate-col tile (LDS, read ONCE per wave per tile);
// B-operand = wave's 32 rows (registers). D: col(lane&31)=output row,
// reg=candidate -> each lane owns ONE row's top-6 -> no merge phase.
__global__ __launch_bounds__(256, 4) void knn9_kernel(const unsigned short* __restrict__ xh,
                                                      const float* __restrict__ sqp,
                                                      unsigned int* __restrict__ cand) {
    __shared__ __align__(16) char smem[36864];   // 2x16KB tiles + 4KB sqp stripe

    const int b      = blockIdx.z;
    const int row0   = blockIdx.x * 128;
    const int stripe = blockIdx.y;
    const int colbase = stripe * 1024;
    const int tid = threadIdx.x;
    const int w   = tid >> 6;
    const int l   = tid & 63;
    const int ln  = l & 31;       // output row within wave AND A-candidate col
    const int h   = l >> 5;       // k-subgroup / candidate M-split
    const unsigned short* Xb = xh + ((size_t)b << 12) * E_;

    // B fragments: my output row, full K=256 in 16 x bf16x8 (64 VGPRs)
    const int myrow = row0 + (w << 5) + ln;
    bf16x8 brow[16];
#pragma unroll
    for (int kg = 0; kg < 16; ++kg)
        brow[kg] = *reinterpret_cast<const bf16x8*>(
            Xb + ((size_t)myrow << 8) + kg * 16 + h * 8);

    unsigned int bk[6];
#pragma unroll
    for (int s = 0; s < 6; ++s) bk[s] = 0xFFFFFFFFu;

    // stage sqp stripe (1024 floats, 4KB) at smem+32768
    __builtin_amdgcn_global_load_lds(
        (const __attribute__((address_space(1))) void*)
            (sqp + ((size_t)(b * 4 + stripe) << 10) + tid * 4),
        (__attribute__((address_space(3))) void*)(smem + 32768 + tid * 16), 16, 0, 0);
    // stage tile 0 (32 cols x 256 k, source-side XOR swizzle, linear dest)
#pragma unroll
    for (int it = 0; it < 4; ++it) {
        int li = it * 256 + tid, col = li >> 5, sl = li & 31;
        const unsigned short* gp =
            Xb + ((size_t)(colbase + col) << 8) + ((sl ^ (col & 7)) << 3);
        __builtin_amdgcn_global_load_lds(
            (const __attribute__((address_space(1))) void*)gp,
            (__attribute__((address_space(3))) void*)(smem + li * 16), 16, 0, 0);
    }
    __syncthreads();

    for (int t = 0; t < 32; ++t) {
        const int cur = (t & 1) * 16384;
        if (t < 31) {
            char* nbuf = smem + (cur ^ 16384);
            const int c0n = colbase + (t + 1) * 32;
#pragma unroll
            for (int it = 0; it < 4; ++it) {
                int li = it * 256 + tid, col = li >> 5, sl = li & 31;
                const unsigned short* gp =
                    Xb + ((size_t)(c0n + col) << 8) + ((sl ^ (col & 7)) << 3);
                __builtin_amdgcn_global_load_lds(
                    (const __attribute__((address_space(1))) void*)gp,
                    (__attribute__((address_space(3))) void*)(nbuf + li * 16), 16, 0, 0);
            }
        }
        // sqp regs for this tile: 16 floats at [t*32 + h*16 .. +16)
        const char* sb = smem + 32768 + t * 128 + h * 64;
        f32x4 sv0 = *reinterpret_cast<const f32x4*>(sb);
        f32x4 sv1 = *reinterpret_cast<const f32x4*>(sb + 16);
        f32x4 sv2 = *reinterpret_cast<const f32x4*>(sb + 32);
        f32x4 sv3 = *reinterpret_cast<const f32x4*>(sb + 48);

        // 16 MFMAs over K=256: A = tile col ln, k-slot (kg*2+h); B = brow
        f32x16 acc = {};
        const char* abase = smem + cur + ln * 512;
        const int swz = (ln & 7);
#pragma unroll
        for (int kg = 0; kg < 16; ++kg) {
            bf16x8 af = *reinterpret_cast<const bf16x8*>(
                abase + ((((kg << 1) + h) ^ swz) << 4));
            acc = __builtin_amdgcn_mfma_f32_32x32x16_bf16(af, brow[kg], acc, 0, 0, 0);
        }

        // selection: reg r -> candidate col = colbase + t*32 + (r&3)+8*(r>>2)+4h
        const unsigned int cb0 = (unsigned int)(colbase + (t << 5) + (h << 2));
#pragma unroll
        for (int r = 0; r < 16; ++r) {
            float sqv = (r < 4) ? sv0[r & 3] : (r < 8) ? sv1[r & 3]
                       : (r < 12) ? sv2[r & 3] : sv3[r & 3];
            float d = fmaf(-1024.f, acc[r], sqv);        // d_b * 512
            unsigned int key = ((unsigned int)d << 12)
                             | (cb0 + (r & 3) + ((r >> 2) << 3));
            bk[5] = med3u(bk[4], bk[5], key);
            bk[4] = med3u(bk[3], bk[4], key);
            bk[3] = med3u(bk[2], bk[3], key);
            bk[2] = med3u(bk[1], bk[2], key);
            bk[1] = med3u(bk[0], bk[1], key);
            bk[0] = min(bk[0], key);
        }
        __syncthreads();   // prefetch landed + all reads of cur done
    }

    // each lane writes its 6 keys (12 per row per stripe, 48 per row total)
    size_t p = ((size_t)b << 12) + myrow;
    unsigned int* op = cand + p * 48 + stripe * 12 + h * 6;
#pragma unroll
    for (int s = 0; s < 6; ++s) op[s] = bk[s];
}

// ---------------- k1s: key-top-16 of 48; resolve boundary or flag ----------------
__global__ __launch_bounds__(256) void sel_kernel(const unsigned int* __restrict__ cand,
                                                  unsigned short* __restrict__ c16,
                                                  int* __restrict__ idxout,
                                                  unsigned char* __restrict__ flag) {
    int p = blockIdx.x * 256 + threadIdx.x;
    const unsigned int* cp = cand + (size_t)p * 48;
    unsigned int tk[16];
#pragma unroll
    for (int s = 0; s < 16; ++s) tk[s] = 0xFFFFFFFFu;
    for (int j = 0; j < 48; ++j) {
        unsigned int key = cp[j];
#pragma unroll
        for (int s = 15; s > 0; --s) tk[s] = med3u(tk[s - 1], tk[s], key);
        tk[0] = min(tk[0], key);
    }
    unsigned short* op = c16 + (size_t)p * 16;
#pragma unroll
    for (int s = 0; s < 16; ++s) op[s] = (unsigned short)(tk[s] & 4095u);
    int* ip = idxout + (size_t)p * K_;
#pragma unroll
    for (int s = 0; s < 6; ++s) ip[s] = (int)(tk[s] & 4095u);
    float d6 = (float)(tk[5] >> 12) * 0.001953125f;
    float d7 = (float)(tk[6] >> 12) * 0.001953125f;
    flag[p] = (d7 - d6 < 0.4f) ? 1 : 0;
}

// ------- k1b: fp64 exact re-rank of 16 candidates (flagged points only) -------
__global__ __launch_bounds__(256) void refine_kernel(const float* __restrict__ x,
                                                     const unsigned short* __restrict__ c16,
                                                     const unsigned char* __restrict__ flag,
                                                     int* __restrict__ idxout) {
    int wv = threadIdx.x >> 6;
    int lane = threadIdx.x & 63;
    const int bid = blockIdx.x;
    const int nbk = ((bid & 7) << 10) | (bid >> 3);   // bijective, 1024 blocks/batch
    int p = nbk * 4 + wv;
    if (!flag[p]) return;
    int b = p >> 12;
    int vi = p & 4095;
    const float* Xb = x + ((size_t)b << 12) * E_;
    const int half = lane >> 5;
    const int hl = lane & 31;

    double xi[8];
#pragma unroll
    for (int t = 0; t < 8; ++t) xi[t] = (double)Xb[(size_t)vi * E_ + hl + t * 32];

    double bdist[6]; int bidx[6];
#pragma unroll
    for (int s = 0; s < 6; ++s) { bdist[s] = DBL_MAX; bidx[s] = 0x7fffffff; }

    const unsigned short* cp = c16 + (size_t)p * 16;
    for (int c = 0; c < 16; c += 2) {
        int jme = cp[c + half];
        const float* Xj = Xb + (size_t)jme * E_;
        double s = 0.0;
#pragma unroll
        for (int t = 0; t < 8; ++t) {
            double d = xi[t] - (double)Xj[hl + t * 32];
            s = fma(d, d, s);
        }
#pragma unroll
        for (int off = 16; off; off >>= 1) s += __shfl_xor(s, off);  // within half
        double sv[2];
        sv[0] = __shfl(s, 0);
        sv[1] = __shfl(s, 32);
        int jv[2] = { (int)cp[c], (int)cp[c + 1] };
#pragma unroll
        for (int q = 0; q < 2; ++q) {
            double sq_ = sv[q]; int j = jv[q];
            if (sq_ < bdist[5] || (sq_ == bdist[5] && j < bidx[5])) {
                bdist[5] = sq_; bidx[5] = j;
#pragma unroll
                for (int t = 5; t > 0; --t) {
                    if (bdist[t] < bdist[t - 1] ||
                        (bdist[t] == bdist[t - 1] && bidx[t] < bidx[t - 1])) {
                        double td = bdist[t]; bdist[t] = bdist[t - 1]; bdist[t - 1] = td;
                        int    ti = bidx[t];  bidx[t]  = bidx[t - 1];  bidx[t - 1]  = ti;
                    } else break;
                }
            }
        }
    }
    if (lane == 0) {
        int* op = idxout + (size_t)p * K_;
#pragma unroll
        for (int s = 0; s < 6; ++s) op[s] = bidx[s];
    }
}

// ---------------- k2: QKV projection, bf16 MFMA, Y[32768][768] bf16 ----------------
__global__ __launch_bounds__(256, 2) void proj_mfma(const unsigned short* __restrict__ xh,
                                                    const unsigned short* __restrict__ Wh,
                                                    unsigned short* __restrict__ Y) {
    const int tid = threadIdx.x;
    const int w = tid >> 6, l = tid & 63, cl = l & 15, g = l >> 4;
    const int row0 = blockIdx.x * 64;
    const int wsel = blockIdx.y;                    // 0=Q,1=K,2=V
    const unsigned short* W = Wh + (size_t)wsel * 65536;

    const int ar = row0 + (w << 4) + cl;
    bf16x8 a[8];
#pragma unroll
    for (int ks = 0; ks < 8; ++ks)
        a[ks] = *reinterpret_cast<const bf16x8*>(xh + ((size_t)ar << 8) + ks * 32 + g * 8);

#pragma unroll
    for (int ct = 0; ct < 16; ++ct) {
        f32x4 acc = {0.f, 0.f, 0.f, 0.f};
        const unsigned short* Wr = W + (size_t)(ct * 16 + cl) * 256 + g * 8;
#pragma unroll
        for (int ks = 0; ks < 8; ++ks) {
            bf16x8 bf = *reinterpret_cast<const bf16x8*>(Wr + ks * 32);
            acc = __builtin_amdgcn_mfma_f32_16x16x32_bf16(a[ks], bf, acc, 0, 0, 0);
        }
#pragma unroll
        for (int r = 0; r < 4; ++r) {
            size_t row = row0 + (w << 4) + (g << 2) + r;
            Y[row * 768 + wsel * 256 + ct * 16 + cl] = f2bf(acc[r]);
        }
    }
}

// ---------------- k3: per-point attention (bf16 Y), XCD-batch swizzle ----------------
__global__ __launch_bounds__(256) void attn_kernel(unsigned short* __restrict__ Y,
                                                   const int* __restrict__ idx,
                                                   float* __restrict__ xw) {
    const int bid = blockIdx.x;
    const int p = ((bid & 7) << 12) | (bid >> 3);   // bijective; batch = bid&7
    const int b = p >> 12;
    const int tid = threadIdx.x;
    const int d = tid & 31;
    __shared__ float aw[K_];
    __shared__ int   nbs[K_];
    if (tid < K_) { aw[tid] = 0.f; nbs[tid] = idx[(size_t)p * K_ + tid]; }
    __syncthreads();
    int nb[K_];
#pragma unroll
    for (int k = 0; k < K_; ++k) nb[k] = nbs[k];

    unsigned short* Yp = Y + (size_t)p * 768;
    float q = bf2f(Yp[tid]);
    float vself = bf2f(Yp[512 + tid]);
    const size_t bbase = (size_t)(b << 12) * 768;

    float sc[K_];
#pragma unroll
    for (int k = 0; k < K_; ++k) {
        const unsigned short* Kr = Y + bbase + (size_t)nb[k] * 768 + 256;
        float s = q * bf2f(Kr[tid]);
        s += __shfl_xor(s, 16);
        s += __shfl_xor(s, 8);
        s += __shfl_xor(s, 4);
        s += __shfl_xor(s, 2);
        s += __shfl_xor(s, 1);
        sc[k] = s * 0.17677669529663687f;   // 1/sqrt(32)
    }
    float m = sc[0];
#pragma unroll
    for (int k = 1; k < K_; ++k) m = fmaxf(m, sc[k]);
    float e[K_], sum = 0.f;
#pragma unroll
    for (int k = 0; k < K_; ++k) { e[k] = __expf(sc[k] - m); sum += e[k]; }
    float inv = 1.f / sum;

    float o = 0.f;
#pragma unroll
    for (int k = 0; k < K_; ++k) {
        const unsigned short* Vr = Y + bbase + (size_t)nb[k] * 768 + 512;
        o += (e[k] * inv) * (bf2f(Vr[tid]) - vself);
    }
    if (d == 0) {
#pragma unroll
        for (int k = 0; k < K_; ++k) atomicAdd(&aw[k], e[k] * inv);
    }
    __syncthreads();
    Yp[tid] = f2bf(o);
    if (tid < K_) atomicAdd(&xw[(b << 12) + nb[tid]], aw[tid] * 0.125f);
}

// ---------------- k4: out = P @ Wo^T + x (bf16 MFMA, fp32 out) ----------------
__global__ __launch_bounds__(256, 2) void out_mfma(const unsigned short* __restrict__ Y,
                                                   const unsigned short* __restrict__ WoH,
                                                   const float* __restrict__ x,
                                                   float* __restrict__ out) {
    const int tid = threadIdx.x;
    const int w = tid >> 6, l = tid & 63, cl = l & 15, g = l >> 4;
    const int row0 = blockIdx.x * 64;

    const int ar = row0 + (w << 4) + cl;
    bf16x8 a[8];
#pragma unroll
    for (int ks = 0; ks < 8; ++ks)
        a[ks] = *reinterpret_cast<const bf16x8*>(Y + (size_t)ar * 768 + ks * 32 + g * 8);

#pragma unroll
    for (int ct = 0; ct < 16; ++ct) {
        f32x4 acc = {0.f, 0.f, 0.f, 0.f};
        const unsigned short* Wr = WoH + (size_t)(ct * 16 + cl) * 256 + g * 8;
#pragma unroll
        for (int ks = 0; ks < 8; ++ks) {
            bf16x8 bf = *reinterpret_cast<const bf16x8*>(Wr + ks * 32);
            acc = __builtin_amdgcn_mfma_f32_16x16x32_bf16(a[ks], bf, acc, 0, 0, 0);
        }
#pragma unroll
        for (int r = 0; r < 4; ++r) {
            size_t row = row0 + (w << 4) + (g << 2) + r;
            size_t o = row * E_ + ct * 16 + cl;
            out[o] = acc[r] + x[o];
        }
    }
}

extern "C" void kernel_launch(void* const* d_in, const int* in_sizes, int n_in,
                              void* d_out, int out_size, void* d_ws, size_t ws_size,
                              hipStream_t stream) {
    const float* x  = (const float*)d_in[0];
    const float* Wq = (const float*)d_in[1];
    const float* Wk = (const float*)d_in[2];
    const float* Wv = (const float*)d_in[3];
    const float* Wo = (const float*)d_in[4];

    float* out = (float*)d_out;
    float* xw  = out + (size_t)NPTS * E_;   // second output [B,V]

    // workspace layout
    char* ws = (char*)d_ws;
    float*          sqw   = (float*)ws;                          // 128 KiB
    float*          sqpw  = (float*)(ws + 131072);               // 128 KiB
    unsigned int*   candw = (unsigned int*)(ws + 262144);        // 6 MiB (48 uint/pt)
    int*            idxw  = (int*)(ws + 6553600);                // 768 KiB
    unsigned char*  flagw = (unsigned char*)(ws + 7340032);      // 32 KiB
    unsigned short* Wh    = (unsigned short*)(ws + 7372800);     // 512 KiB (4 matrices)
    unsigned short* c16w  = (unsigned short*)(ws + 7897088);     // 1 MiB
    unsigned short* Xh    = (unsigned short*)(ws + 8945664);     // 16 MiB
    unsigned short* Y     = (unsigned short*)(ws + 25722880);    // 48 MiB bf16 [32768][768]

    hipMemsetAsync(xw, 0, (size_t)NPTS * sizeof(float), stream);

    cvtsq_kernel<<<4096 + 128, 256, 0, stream>>>(x, Wq, Wk, Wv, Wo, Xh, Wh, sqw);
    sqp_kernel<<<128, 256, 0, stream>>>(sqw, sqpw);
    knn9_kernel<<<dim3(V_ / 128, 4, B_), 256, 0, stream>>>(Xh, sqpw, candw);
    sel_kernel<<<NPTS / 256, 256, 0, stream>>>(candw, c16w, idxw, flagw);
    refine_kernel<<<NPTS / 4, 256, 0, stream>>>(x, c16w, flagw, idxw);
    proj_mfma<<<dim3(NPTS / 64, 3), 256, 0, stream>>>(Xh, Wh, Y);
    attn_kernel<<<NPTS, 256, 0, stream>>>(Y, idxw, xw);
    out_mfma<<<NPTS / 64, 256, 0, stream>>>(Y, Wh + 3 * 65536, x, out);
}

// Round 12
// 274.243 us; speedup vs baseline: 9.6566x; 1.2197x over previous
//
#include <hip/hip_runtime.h>
#include <cfloat>
#include <math.h>

#define B_   8
#define V_   4096
#define E_   256
#define K_   6
#define H_   8
#define HD_  32
#define NPTS (B_*V_)

typedef __bf16 bf16x8 __attribute__((ext_vector_type(8)));
typedef float  f32x4  __attribute__((ext_vector_type(4)));
typedef float  f32x16 __attribute__((ext_vector_type(16)));

__device__ __forceinline__ float bf2f(unsigned short u) {
    return __uint_as_float(((unsigned int)u) << 16);
}
__device__ __forceinline__ unsigned short f2bf(float f) {
    unsigned int u = __float_as_uint(f);
    return (unsigned short)((u + 0x7fffu + ((u >> 16) & 1u)) >> 16);
}
__device__ __forceinline__ unsigned int med3u(unsigned int a, unsigned int b,
                                              unsigned int c) {
    unsigned int d;
    asm("v_med3_u32 %0, %1, %2, %3" : "=v"(d) : "v"(a), "v"(b), "v"(c));
    return d;
}

// ------ k0: fused fp32->bf16 of x (+norms) and of the 4 weight matrices ------
__global__ __launch_bounds__(256) void cvtsq_kernel(const float* __restrict__ x,
                                                    const float* __restrict__ Wq,
                                                    const float* __restrict__ Wk,
                                                    const float* __restrict__ Wv,
                                                    const float* __restrict__ Wo,
                                                    unsigned short* __restrict__ xh,
                                                    unsigned short* __restrict__ Wh,
                                                    float* __restrict__ sq) {
    const int bx = blockIdx.x;
    if (bx < 4096) {
        size_t i = ((size_t)bx * 256 + threadIdx.x) * 8;
        float4 a = *reinterpret_cast<const float4*>(x + i);
        float4 b = *reinterpret_cast<const float4*>(x + i + 4);
        ushort o[8] = { f2bf(a.x), f2bf(a.y), f2bf(a.z), f2bf(a.w),
                        f2bf(b.x), f2bf(b.y), f2bf(b.z), f2bf(b.w) };
        *reinterpret_cast<uint4*>(xh + i) = *reinterpret_cast<uint4*>(o);
        float s = a.x*a.x + a.y*a.y + a.z*a.z + a.w*a.w
                + b.x*b.x + b.y*b.y + b.z*b.z + b.w*b.w;
        s += __shfl_xor(s, 1);
        s += __shfl_xor(s, 2);
        s += __shfl_xor(s, 4);
        s += __shfl_xor(s, 8);
        s += __shfl_xor(s, 16);
        if ((threadIdx.x & 31) == 0)
            sq[bx * 8 + (threadIdx.x >> 5)] = s;
    } else {
        const int wb = bx - 4096;               // 0..127
        const int m = wb >> 5;
        const float* src = (m == 0) ? Wq : (m == 1) ? Wk : (m == 2) ? Wv : Wo;
        unsigned short* dst = Wh + (size_t)m * 65536;
        size_t i = ((size_t)(wb & 31) * 256 + threadIdx.x) * 8;
        float4 a = *reinterpret_cast<const float4*>(src + i);
        float4 b = *reinterpret_cast<const float4*>(src + i + 4);
        ushort o[8] = { f2bf(a.x), f2bf(a.y), f2bf(a.z), f2bf(a.w),
                        f2bf(b.x), f2bf(b.y), f2bf(b.z), f2bf(b.w) };
        *reinterpret_cast<uint4*>(dst + i) = *reinterpret_cast<uint4*>(o);
    }
}

// ------ k0c: permute (sq+600)*512 into MFMA reg order ------
__global__ __launch_bounds__(256) void sqp_kernel(const float* __restrict__ sq,
                                                  float* __restrict__ sqp) {
    int i = blockIdx.x * 256 + threadIdx.x;     // 32768 entries
    int reg = i & 15, h = (i >> 4) & 1, t = (i >> 5) & 31;
    int stripe = (i >> 10) & 3, b = i >> 12;
    int col = stripe * 1024 + t * 32 + (reg & 3) + 8 * (reg >> 2) + 4 * h;
    sqp[i] = (sq[b * 4096 + col] + 600.f) * 512.f;
}

// ---- k1: 32x32x16 MFMA Gram (swapped operands) + per-lane row top-6 ----
__global__ __launch_bounds__(256, 4) void knn9_kernel(const unsigned short* __restrict__ xh,
                                                      const float* __restrict__ sqp,
                                                      unsigned int* __restrict__ cand) {
    __shared__ __align__(16) char smem[36864];   // 2x16KB tiles + 4KB sqp stripe

    const int b      = blockIdx.z;
    const int row0   = blockIdx.x * 128;
    const int stripe = blockIdx.y;
    const int colbase = stripe * 1024;
    const int tid = threadIdx.x;
    const int w   = tid >> 6;
    const int l   = tid & 63;
    const int ln  = l & 31;
    const int h   = l >> 5;
    const unsigned short* Xb = xh + ((size_t)b << 12) * E_;

    const int myrow = row0 + (w << 5) + ln;
    bf16x8 brow[16];
#pragma unroll
    for (int kg = 0; kg < 16; ++kg)
        brow[kg] = *reinterpret_cast<const bf16x8*>(
            Xb + ((size_t)myrow << 8) + kg * 16 + h * 8);

    unsigned int bk[6];
#pragma unroll
    for (int s = 0; s < 6; ++s) bk[s] = 0xFFFFFFFFu;

    __builtin_amdgcn_global_load_lds(
        (const __attribute__((address_space(1))) void*)
            (sqp + ((size_t)(b * 4 + stripe) << 10) + tid * 4),
        (__attribute__((address_space(3))) void*)(smem + 32768 + tid * 16), 16, 0, 0);
#pragma unroll
    for (int it = 0; it < 4; ++it) {
        int li = it * 256 + tid, col = li >> 5, sl = li & 31;
        const unsigned short* gp =
            Xb + ((size_t)(colbase + col) << 8) + ((sl ^ (col & 7)) << 3);
        __builtin_amdgcn_global_load_lds(
            (const __attribute__((address_space(1))) void*)gp,
            (__attribute__((address_space(3))) void*)(smem + li * 16), 16, 0, 0);
    }
    __syncthreads();

    for (int t = 0; t < 32; ++t) {
        const int cur = (t & 1) * 16384;
        if (t < 31) {
            char* nbuf = smem + (cur ^ 16384);
            const int c0n = colbase + (t + 1) * 32;
#pragma unroll
            for (int it = 0; it < 4; ++it) {
                int li = it * 256 + tid, col = li >> 5, sl = li & 31;
                const unsigned short* gp =
                    Xb + ((size_t)(c0n + col) << 8) + ((sl ^ (col & 7)) << 3);
                __builtin_amdgcn_global_load_lds(
                    (const __attribute__((address_space(1))) void*)gp,
                    (__attribute__((address_space(3))) void*)(nbuf + li * 16), 16, 0, 0);
            }
        }
        const char* sb = smem + 32768 + t * 128 + h * 64;
        f32x4 sv0 = *reinterpret_cast<const f32x4*>(sb);
        f32x4 sv1 = *reinterpret_cast<const f32x4*>(sb + 16);
        f32x4 sv2 = *reinterpret_cast<const f32x4*>(sb + 32);
        f32x4 sv3 = *reinterpret_cast<const f32x4*>(sb + 48);

        f32x16 acc = {};
        const char* abase = smem + cur + ln * 512;
        const int swz = (ln & 7);
#pragma unroll
        for (int kg = 0; kg < 16; ++kg) {
            bf16x8 af = *reinterpret_cast<const bf16x8*>(
                abase + ((((kg << 1) + h) ^ swz) << 4));
            acc = __builtin_amdgcn_mfma_f32_32x32x16_bf16(af, brow[kg], acc, 0, 0, 0);
        }

        const unsigned int cb0 = (unsigned int)(colbase + (t << 5) + (h << 2));
#pragma unroll
        for (int r = 0; r < 16; ++r) {
            float sqv = (r < 4) ? sv0[r & 3] : (r < 8) ? sv1[r & 3]
                       : (r < 12) ? sv2[r & 3] : sv3[r & 3];
            float d = fmaf(-1024.f, acc[r], sqv);        // d_b * 512
            unsigned int key = ((unsigned int)d << 12)
                             | (cb0 + (r & 3) + ((r >> 2) << 3));
            bk[5] = med3u(bk[4], bk[5], key);
            bk[4] = med3u(bk[3], bk[4], key);
            bk[3] = med3u(bk[2], bk[3], key);
            bk[2] = med3u(bk[1], bk[2], key);
            bk[1] = med3u(bk[0], bk[1], key);
            bk[0] = min(bk[0], key);
        }
        __syncthreads();
    }

    size_t p = ((size_t)b << 12) + myrow;
    unsigned int* op = cand + p * 48 + stripe * 12 + h * 6;
#pragma unroll
    for (int s = 0; s < 6; ++s) op[s] = bk[s];
}

// ---------------- k1s: key-top-16 of 48; resolve boundary or flag ----------------
__global__ __launch_bounds__(256) void sel_kernel(const unsigned int* __restrict__ cand,
                                                  unsigned short* __restrict__ c16,
                                                  int* __restrict__ idxout,
                                                  unsigned char* __restrict__ flag) {
    int p = blockIdx.x * 256 + threadIdx.x;
    const unsigned int* cp = cand + (size_t)p * 48;
    unsigned int tk[16];
#pragma unroll
    for (int s = 0; s < 16; ++s) tk[s] = 0xFFFFFFFFu;
    for (int j = 0; j < 48; ++j) {
        unsigned int key = cp[j];
#pragma unroll
        for (int s = 15; s > 0; --s) tk[s] = med3u(tk[s - 1], tk[s], key);
        tk[0] = min(tk[0], key);
    }
    unsigned short* op = c16 + (size_t)p * 16;
#pragma unroll
    for (int s = 0; s < 16; ++s) op[s] = (unsigned short)(tk[s] & 4095u);
    int* ip = idxout + (size_t)p * K_;
#pragma unroll
    for (int s = 0; s < 6; ++s) ip[s] = (int)(tk[s] & 4095u);
    float d6 = (float)(tk[5] >> 12) * 0.001953125f;
    float d7 = (float)(tk[6] >> 12) * 0.001953125f;
    flag[p] = (d7 - d6 < 0.4f) ? 1 : 0;
}

// ------- k1b: fp64 exact re-rank of 16 candidates (flagged points only) -------
__global__ __launch_bounds__(256) void refine_kernel(const float* __restrict__ x,
                                                     const unsigned short* __restrict__ c16,
                                                     const unsigned char* __restrict__ flag,
                                                     int* __restrict__ idxout) {
    int wv = threadIdx.x >> 6;
    int lane = threadIdx.x & 63;
    const int bid = blockIdx.x;
    const int nbk = ((bid & 7) << 10) | (bid >> 3);
    int p = nbk * 4 + wv;
    if (!flag[p]) return;
    int b = p >> 12;
    int vi = p & 4095;
    const float* Xb = x + ((size_t)b << 12) * E_;
    const int half = lane >> 5;
    const int hl = lane & 31;

    double xi[8];
#pragma unroll
    for (int t = 0; t < 8; ++t) xi[t] = (double)Xb[(size_t)vi * E_ + hl + t * 32];

    double bdist[6]; int bidx[6];
#pragma unroll
    for (int s = 0; s < 6; ++s) { bdist[s] = DBL_MAX; bidx[s] = 0x7fffffff; }

    const unsigned short* cp = c16 + (size_t)p * 16;
    for (int c = 0; c < 16; c += 2) {
        int jme = cp[c + half];
        const float* Xj = Xb + (size_t)jme * E_;
        double s = 0.0;
#pragma unroll
        for (int t = 0; t < 8; ++t) {
            double d = xi[t] - (double)Xj[hl + t * 32];
            s = fma(d, d, s);
        }
#pragma unroll
        for (int off = 16; off; off >>= 1) s += __shfl_xor(s, off);
        double sv[2];
        sv[0] = __shfl(s, 0);
        sv[1] = __shfl(s, 32);
        int jv[2] = { (int)cp[c], (int)cp[c + 1] };
#pragma unroll
        for (int q = 0; q < 2; ++q) {
            double sq_ = sv[q]; int j = jv[q];
            if (sq_ < bdist[5] || (sq_ == bdist[5] && j < bidx[5])) {
                bdist[5] = sq_; bidx[5] = j;
#pragma unroll
                for (int t = 5; t > 0; --t) {
                    if (bdist[t] < bdist[t - 1] ||
                        (bdist[t] == bdist[t - 1] && bidx[t] < bidx[t - 1])) {
                        double td = bdist[t]; bdist[t] = bdist[t - 1]; bdist[t - 1] = td;
                        int    ti = bidx[t];  bidx[t]  = bidx[t - 1];  bidx[t - 1]  = ti;
                    } else break;
                }
            }
        }
    }
    if (lane == 0) {
        int* op = idxout + (size_t)p * K_;
#pragma unroll
        for (int s = 0; s < 6; ++s) op[s] = bidx[s];
    }
}

// -------- k2: QKV projection, bf16 MFMA, 128 rows/block (W-tile reused) --------
__global__ __launch_bounds__(256, 2) void proj_mfma(const unsigned short* __restrict__ xh,
                                                    const unsigned short* __restrict__ Wh,
                                                    unsigned short* __restrict__ Y) {
    const int tid = threadIdx.x;
    const int w = tid >> 6, l = tid & 63, cl = l & 15, g = l >> 4;
    const int row0 = blockIdx.x * 128;
    const int wsel = blockIdx.y;                    // 0=Q,1=K,2=V
    const unsigned short* W = Wh + (size_t)wsel * 65536;

    bf16x8 a0[8], a1[8];
    const int ar0 = row0 + (w << 4) + cl;
#pragma unroll
    for (int ks = 0; ks < 8; ++ks) {
        a0[ks] = *reinterpret_cast<const bf16x8*>(xh + ((size_t)ar0 << 8) + ks * 32 + g * 8);
        a1[ks] = *reinterpret_cast<const bf16x8*>(xh + ((size_t)(ar0 + 64) << 8) + ks * 32 + g * 8);
    }

#pragma unroll
    for (int ct = 0; ct < 16; ++ct) {
        f32x4 acc0 = {0.f, 0.f, 0.f, 0.f};
        f32x4 acc1 = {0.f, 0.f, 0.f, 0.f};
        const unsigned short* Wr = W + (size_t)(ct * 16 + cl) * 256 + g * 8;
#pragma unroll
        for (int ks = 0; ks < 8; ++ks) {
            bf16x8 bf = *reinterpret_cast<const bf16x8*>(Wr + ks * 32);
            acc0 = __builtin_amdgcn_mfma_f32_16x16x32_bf16(a0[ks], bf, acc0, 0, 0, 0);
            acc1 = __builtin_amdgcn_mfma_f32_16x16x32_bf16(a1[ks], bf, acc1, 0, 0, 0);
        }
#pragma unroll
        for (int r = 0; r < 4; ++r) {
            size_t row = row0 + (w << 4) + (g << 2) + r;
            Y[row * 768 + wsel * 256 + ct * 16 + cl] = f2bf(acc0[r]);
            Y[(row + 64) * 768 + wsel * 256 + ct * 16 + cl] = f2bf(acc1[r]);
        }
    }
}

// ---- k3: attention, wave-per-point (4 pts/block). Lane l owns elems 4l..4l+3,
// head = l>>3 (8-lane groups). Writes P into the Q slot of Y. ----
__global__ __launch_bounds__(256) void attn_kernel(unsigned short* __restrict__ Y,
                                                   const int* __restrict__ idx,
                                                   float* __restrict__ xw) {
    const int bid = blockIdx.x;                      // 8192
    const int w = threadIdx.x >> 6;
    const int l = threadIdx.x & 63;
    const int p = (((bid & 7) << 12) | ((bid >> 3) << 2)) + w;  // XCD-batch swizzle
    const int b = p >> 12;

    const int* ip = idx + (size_t)p * K_;
    int nb[K_];
#pragma unroll
    for (int k = 0; k < K_; ++k) nb[k] = ip[k];

    unsigned short* Yp = Y + (size_t)p * 768;
    ushort4 q4 = *reinterpret_cast<const ushort4*>(Yp + l * 4);
    ushort4 s4 = *reinterpret_cast<const ushort4*>(Yp + 512 + l * 4);
    float q0 = bf2f(q4.x), q1 = bf2f(q4.y), q2 = bf2f(q4.z), q3 = bf2f(q4.w);
    float v0 = bf2f(s4.x), v1 = bf2f(s4.y), v2 = bf2f(s4.z), v3 = bf2f(s4.w);
    const size_t bbase = (size_t)(b << 12) * 768;

    float sc[K_];
#pragma unroll
    for (int k = 0; k < K_; ++k) {
        ushort4 k4 = *reinterpret_cast<const ushort4*>(
            Y + bbase + (size_t)nb[k] * 768 + 256 + l * 4);
        float s = q0 * bf2f(k4.x) + q1 * bf2f(k4.y)
                + q2 * bf2f(k4.z) + q3 * bf2f(k4.w);
        s += __shfl_xor(s, 1);
        s += __shfl_xor(s, 2);
        s += __shfl_xor(s, 4);
        sc[k] = s * 0.17677669529663687f;   // 1/sqrt(32)
    }
    float m = sc[0];
#pragma unroll
    for (int k = 1; k < K_; ++k) m = fmaxf(m, sc[k]);
    float e[K_], sum = 0.f;
#pragma unroll
    for (int k = 0; k < K_; ++k) { e[k] = __expf(sc[k] - m); sum += e[k]; }
    float inv = 1.f / sum;

    float o0 = 0.f, o1 = 0.f, o2 = 0.f, o3 = 0.f;
    float hs[K_];
#pragma unroll
    for (int k = 0; k < K_; ++k) {
        float a = e[k] * inv;
        ushort4 z4 = *reinterpret_cast<const ushort4*>(
            Y + bbase + (size_t)nb[k] * 768 + 512 + l * 4);
        o0 += a * (bf2f(z4.x) - v0);
        o1 += a * (bf2f(z4.y) - v1);
        o2 += a * (bf2f(z4.z) - v2);
        o3 += a * (bf2f(z4.w) - v3);
        // head-mean for xw: sum a over the 8 head groups (uniform within group)
        float t = a;
        t += __shfl_xor(t, 8);
        t += __shfl_xor(t, 16);
        t += __shfl_xor(t, 32);
        hs[k] = t * 0.125f;
    }
    ushort o4[4] = { f2bf(o0), f2bf(o1), f2bf(o2), f2bf(o3) };
    *reinterpret_cast<ushort4*>(Yp + l * 4) = *reinterpret_cast<ushort4*>(o4);
    if (l < K_) atomicAdd(&xw[(b << 12) + nb[l]], hs[l]);
}

// -------- k4: out = P @ Wo^T + x, 128 rows/block dual-acc --------
__global__ __launch_bounds__(256, 2) void out_mfma(const unsigned short* __restrict__ Y,
                                                   const unsigned short* __restrict__ WoH,
                                                   const float* __restrict__ x,
                                                   float* __restrict__ out) {
    const int tid = threadIdx.x;
    const int w = tid >> 6, l = tid & 63, cl = l & 15, g = l >> 4;
    const int row0 = blockIdx.x * 128;

    bf16x8 a0[8], a1[8];
    const int ar0 = row0 + (w << 4) + cl;
#pragma unroll
    for (int ks = 0; ks < 8; ++ks) {
        a0[ks] = *reinterpret_cast<const bf16x8*>(Y + (size_t)ar0 * 768 + ks * 32 + g * 8);
        a1[ks] = *reinterpret_cast<const bf16x8*>(Y + (size_t)(ar0 + 64) * 768 + ks * 32 + g * 8);
    }

#pragma unroll
    for (int ct = 0; ct < 16; ++ct) {
        f32x4 acc0 = {0.f, 0.f, 0.f, 0.f};
        f32x4 acc1 = {0.f, 0.f, 0.f, 0.f};
        const unsigned short* Wr = WoH + (size_t)(ct * 16 + cl) * 256 + g * 8;
#pragma unroll
        for (int ks = 0; ks < 8; ++ks) {
            bf16x8 bf = *reinterpret_cast<const bf16x8*>(Wr + ks * 32);
            acc0 = __builtin_amdgcn_mfma_f32_16x16x32_bf16(a0[ks], bf, acc0, 0, 0, 0);
            acc1 = __builtin_amdgcn_mfma_f32_16x16x32_bf16(a1[ks], bf, acc1, 0, 0, 0);
        }
#pragma unroll
        for (int r = 0; r < 4; ++r) {
            size_t row = row0 + (w << 4) + (g << 2) + r;
            size_t o = row * E_ + ct * 16 + cl;
            out[o] = acc0[r] + x[o];
            size_t o2 = (row + 64) * E_ + ct * 16 + cl;
            out[o2] = acc1[r] + x[o2];
        }
    }
}

extern "C" void kernel_launch(void* const* d_in, const int* in_sizes, int n_in,
                              void* d_out, int out_size, void* d_ws, size_t ws_size,
                              hipStream_t stream) {
    const float* x  = (const float*)d_in[0];
    const float* Wq = (const float*)d_in[1];
    const float* Wk = (const float*)d_in[2];
    const float* Wv = (const float*)d_in[3];
    const float* Wo = (const float*)d_in[4];

    float* out = (float*)d_out;
    float* xw  = out + (size_t)NPTS * E_;   // second output [B,V]

    // workspace layout
    char* ws = (char*)d_ws;
    float*          sqw   = (float*)ws;                          // 128 KiB
    float*          sqpw  = (float*)(ws + 131072);               // 128 KiB
    unsigned int*   candw = (unsigned int*)(ws + 262144);        // 6 MiB (48 uint/pt)
    int*            idxw  = (int*)(ws + 6553600);                // 768 KiB
    unsigned char*  flagw = (unsigned char*)(ws + 7340032);      // 32 KiB
    unsigned short* Wh    = (unsigned short*)(ws + 7372800);     // 512 KiB (4 matrices)
    unsigned short* c16w  = (unsigned short*)(ws + 7897088);     // 1 MiB
    unsigned short* Xh    = (unsigned short*)(ws + 8945664);     // 16 MiB
    unsigned short* Y     = (unsigned short*)(ws + 25722880);    // 48 MiB bf16 [32768][768]

    hipMemsetAsync(xw, 0, (size_t)NPTS * sizeof(float), stream);

    cvtsq_kernel<<<4096 + 128, 256, 0, stream>>>(x, Wq, Wk, Wv, Wo, Xh, Wh, sqw);
    sqp_kernel<<<128, 256, 0, stream>>>(sqw, sqpw);
    knn9_kernel<<<dim3(V_ / 128, 4, B_), 256, 0, stream>>>(Xh, sqpw, candw);
    sel_kernel<<<NPTS / 256, 256, 0, stream>>>(candw, c16w, idxw, flagw);
    refine_kernel<<<NPTS / 4, 256, 0, stream>>>(x, c16w, flagw, idxw);
    proj_mfma<<<dim3(NPTS / 128, 3), 256, 0, stream>>>(Xh, Wh, Y);
    attn_kernel<<<NPTS / 4, 256, 0, stream>>>(Y, idxw, xw);
    out_mfma<<<NPTS / 128, 256, 0, stream>>>(Y, Wh + 3 * 65536, x, out);
}

// Round 14
// 258.892 us; speedup vs baseline: 10.2292x; 1.0593x over previous
//
#include <hip/hip_runtime.h>
#include <cfloat>
#include <math.h>

#define B_   8
#define V_   4096
#define E_   256
#define K_   6
#define H_   8
#define HD_  32
#define NPTS (B_*V_)

typedef __bf16 bf16x8 __attribute__((ext_vector_type(8)));
typedef float  f32x4  __attribute__((ext_vector_type(4)));
typedef float  f32x16 __attribute__((ext_vector_type(16)));

__device__ __forceinline__ float bf2f(unsigned short u) {
    return __uint_as_float(((unsigned int)u) << 16);
}
__device__ __forceinline__ unsigned short f2bf(float f) {
    unsigned int u = __float_as_uint(f);
    return (unsigned short)((u + 0x7fffu + ((u >> 16) & 1u)) >> 16);
}
__device__ __forceinline__ unsigned int med3u(unsigned int a, unsigned int b,
                                              unsigned int c) {
    unsigned int d;
    asm("v_med3_u32 %0, %1, %2, %3" : "=v"(d) : "v"(a), "v"(b), "v"(c));
    return d;
}
// branchless sorted-top-6 insert (single definition -> no transcription bugs)
__device__ __forceinline__ void push6(unsigned int (&k6)[6], unsigned int key) {
    k6[5] = med3u(k6[4], k6[5], key);
    k6[4] = med3u(k6[3], k6[4], key);
    k6[3] = med3u(k6[2], k6[3], key);
    k6[2] = med3u(k6[1], k6[2], key);
    k6[1] = med3u(k6[0], k6[1], key);
    k6[0] = min(k6[0], key);
}

// ------ k0: fused fp32->bf16 of x (+norms) and of the 4 weight matrices ------
__global__ __launch_bounds__(256) void cvtsq_kernel(const float* __restrict__ x,
                                                    const float* __restrict__ Wq,
                                                    const float* __restrict__ Wk,
                                                    const float* __restrict__ Wv,
                                                    const float* __restrict__ Wo,
                                                    unsigned short* __restrict__ xh,
                                                    unsigned short* __restrict__ Wh,
                                                    float* __restrict__ sq) {
    const int bx = blockIdx.x;
    if (bx < 4096) {
        size_t i = ((size_t)bx * 256 + threadIdx.x) * 8;
        float4 a = *reinterpret_cast<const float4*>(x + i);
        float4 b = *reinterpret_cast<const float4*>(x + i + 4);
        ushort o[8] = { f2bf(a.x), f2bf(a.y), f2bf(a.z), f2bf(a.w),
                        f2bf(b.x), f2bf(b.y), f2bf(b.z), f2bf(b.w) };
        *reinterpret_cast<uint4*>(xh + i) = *reinterpret_cast<uint4*>(o);
        float s = a.x*a.x + a.y*a.y + a.z*a.z + a.w*a.w
                + b.x*b.x + b.y*b.y + b.z*b.z + b.w*b.w;
        s += __shfl_xor(s, 1);
        s += __shfl_xor(s, 2);
        s += __shfl_xor(s, 4);
        s += __shfl_xor(s, 8);
        s += __shfl_xor(s, 16);
        if ((threadIdx.x & 31) == 0)
            sq[bx * 8 + (threadIdx.x >> 5)] = s;
    } else {
        const int wb = bx - 4096;               // 0..127
        const int m = wb >> 5;
        const float* src = (m == 0) ? Wq : (m == 1) ? Wk : (m == 2) ? Wv : Wo;
        unsigned short* dst = Wh + (size_t)m * 65536;
        size_t i = ((size_t)(wb & 31) * 256 + threadIdx.x) * 8;
        float4 a = *reinterpret_cast<const float4*>(src + i);
        float4 b = *reinterpret_cast<const float4*>(src + i + 4);
        ushort o[8] = { f2bf(a.x), f2bf(a.y), f2bf(a.z), f2bf(a.w),
                        f2bf(b.x), f2bf(b.y), f2bf(b.z), f2bf(b.w) };
        *reinterpret_cast<uint4*>(dst + i) = *reinterpret_cast<uint4*>(o);
    }
}

// ------ k0c: permute (sq+600)*512 into MFMA reg order ------
__global__ __launch_bounds__(256) void sqp_kernel(const float* __restrict__ sq,
                                                  float* __restrict__ sqp) {
    int i = blockIdx.x * 256 + threadIdx.x;     // 32768 entries
    int reg = i & 15, h = (i >> 4) & 1, t = (i >> 5) & 31;
    int stripe = (i >> 10) & 3, b = i >> 12;
    int col = stripe * 1024 + t * 32 + (reg & 3) + 8 * (reg >> 2) + 4 * h;
    sqp[i] = (sq[b * 4096 + col] + 600.f) * 512.f;
}

// ---- k1: 32x32x16 MFMA Gram, 64 rows/wave (dual B-set: each LDS A-read
// feeds TWO MFMAs -> per-CU LDS traffic halves vs knn9) ----
__global__ __launch_bounds__(256, 2) void knn10_kernel(const unsigned short* __restrict__ xh,
                                                       const float* __restrict__ sqp,
                                                       unsigned int* __restrict__ cand) {
    __shared__ __align__(16) char smem[36864];   // 2x16KB tiles + 4KB sqp stripe

    const int b      = blockIdx.z;
    const int row0   = blockIdx.x * 256;
    const int stripe = blockIdx.y;
    const int colbase = stripe * 1024;
    const int tid = threadIdx.x;
    const int w   = tid >> 6;
    const int l   = tid & 63;
    const int ln  = l & 31;
    const int h   = l >> 5;
    const unsigned short* Xb = xh + ((size_t)b << 12) * E_;

    // B fragments: rows myrow0 and myrow0+32, full K=256 each (128 VGPRs)
    const int myrow0 = row0 + (w << 6) + ln;
    bf16x8 brow0[16], brow1[16];
#pragma unroll
    for (int kg = 0; kg < 16; ++kg) {
        brow0[kg] = *reinterpret_cast<const bf16x8*>(
            Xb + ((size_t)myrow0 << 8) + kg * 16 + h * 8);
        brow1[kg] = *reinterpret_cast<const bf16x8*>(
            Xb + ((size_t)(myrow0 + 32) << 8) + kg * 16 + h * 8);
    }

    unsigned int bk0[6], bk1[6];
#pragma unroll
    for (int s = 0; s < 6; ++s) { bk0[s] = 0xFFFFFFFFu; bk1[s] = 0xFFFFFFFFu; }

    __builtin_amdgcn_global_load_lds(
        (const __attribute__((address_space(1))) void*)
            (sqp + ((size_t)(b * 4 + stripe) << 10) + tid * 4),
        (__attribute__((address_space(3))) void*)(smem + 32768 + tid * 16), 16, 0, 0);
#pragma unroll
    for (int it = 0; it < 4; ++it) {
        int li = it * 256 + tid, col = li >> 5, sl = li & 31;
        const unsigned short* gp =
            Xb + ((size_t)(colbase + col) << 8) + ((sl ^ (col & 7)) << 3);
        __builtin_amdgcn_global_load_lds(
            (const __attribute__((address_space(1))) void*)gp,
            (__attribute__((address_space(3))) void*)(smem + li * 16), 16, 0, 0);
    }
    __syncthreads();

    for (int t = 0; t < 32; ++t) {
        const int cur = (t & 1) * 16384;
        if (t < 31) {
            char* nbuf = smem + (cur ^ 16384);
            const int c0n = colbase + (t + 1) * 32;
#pragma unroll
            for (int it = 0; it < 4; ++it) {
                int li = it * 256 + tid, col = li >> 5, sl = li & 31;
                const unsigned short* gp =
                    Xb + ((size_t)(c0n + col) << 8) + ((sl ^ (col & 7)) << 3);
                __builtin_amdgcn_global_load_lds(
                    (const __attribute__((address_space(1))) void*)gp,
                    (__attribute__((address_space(3))) void*)(nbuf + li * 16), 16, 0, 0);
            }
        }
        const char* sb = smem + 32768 + t * 128 + h * 64;
        f32x4 sv0 = *reinterpret_cast<const f32x4*>(sb);
        f32x4 sv1 = *reinterpret_cast<const f32x4*>(sb + 16);
        f32x4 sv2 = *reinterpret_cast<const f32x4*>(sb + 32);
        f32x4 sv3 = *reinterpret_cast<const f32x4*>(sb + 48);

        f32x16 acc0 = {}, acc1 = {};
        const char* abase = smem + cur + ln * 512;
        const int swz = (ln & 7);
#pragma unroll
        for (int kg = 0; kg < 16; ++kg) {
            bf16x8 af = *reinterpret_cast<const bf16x8*>(
                abase + ((((kg << 1) + h) ^ swz) << 4));
            acc0 = __builtin_amdgcn_mfma_f32_32x32x16_bf16(af, brow0[kg], acc0, 0, 0, 0);
            acc1 = __builtin_amdgcn_mfma_f32_32x32x16_bf16(af, brow1[kg], acc1, 0, 0, 0);
        }

        const unsigned int cb0 = (unsigned int)(colbase + (t << 5) + (h << 2));
#pragma unroll
        for (int r = 0; r < 16; ++r) {
            float sqv = (r < 4) ? sv0[r & 3] : (r < 8) ? sv1[r & 3]
                       : (r < 12) ? sv2[r & 3] : sv3[r & 3];
            unsigned int cidx = cb0 + (r & 3) + ((r >> 2) << 3);
            float d0 = fmaf(-1024.f, acc0[r], sqv);      // d_b * 512
            push6(bk0, ((unsigned int)d0 << 12) | cidx);
            float d1 = fmaf(-1024.f, acc1[r], sqv);
            push6(bk1, ((unsigned int)d1 << 12) | cidx);
        }
        __syncthreads();
    }

    size_t p0 = ((size_t)b << 12) + myrow0;
    unsigned int* op0 = cand + p0 * 48 + stripe * 12 + h * 6;
    unsigned int* op1 = cand + (p0 + 32) * 48 + stripe * 12 + h * 6;
#pragma unroll
    for (int s = 0; s < 6; ++s) { op0[s] = bk0[s]; op1[s] = bk1[s]; }
}

// ---------------- k1s: key-top-16 of 48; resolve boundary or flag ----------------
__global__ __launch_bounds__(256) void sel_kernel(const unsigned int* __restrict__ cand,
                                                  unsigned short* __restrict__ c16,
                                                  int* __restrict__ idxout,
                                                  unsigned char* __restrict__ flag) {
    int p = blockIdx.x * 256 + threadIdx.x;
    const unsigned int* cp = cand + (size_t)p * 48;
    unsigned int tk[16];
#pragma unroll
    for (int s = 0; s < 16; ++s) tk[s] = 0xFFFFFFFFu;
    for (int j = 0; j < 48; ++j) {
        unsigned int key = cp[j];
#pragma unroll
        for (int s = 15; s > 0; --s) tk[s] = med3u(tk[s - 1], tk[s], key);
        tk[0] = min(tk[0], key);
    }
    unsigned short* op = c16 + (size_t)p * 16;
#pragma unroll
    for (int s = 0; s < 16; ++s) op[s] = (unsigned short)(tk[s] & 4095u);
    int* ip = idxout + (size_t)p * K_;
#pragma unroll
    for (int s = 0; s < 6; ++s) ip[s] = (int)(tk[s] & 4095u);
    float d6 = (float)(tk[5] >> 12) * 0.001953125f;
    float d7 = (float)(tk[6] >> 12) * 0.001953125f;
    flag[p] = (d7 - d6 < 0.4f) ? 1 : 0;
}

// ------- k1b: fp64 exact re-rank of 16 candidates (flagged points only) -------
__global__ __launch_bounds__(256) void refine_kernel(const float* __restrict__ x,
                                                     const unsigned short* __restrict__ c16,
                                                     const unsigned char* __restrict__ flag,
                                                     int* __restrict__ idxout) {
    int wv = threadIdx.x >> 6;
    int lane = threadIdx.x & 63;
    const int bid = blockIdx.x;
    const int nbk = ((bid & 7) << 10) | (bid >> 3);
    int p = nbk * 4 + wv;
    if (!flag[p]) return;
    int b = p >> 12;
    int vi = p & 4095;
    const float* Xb = x + ((size_t)b << 12) * E_;
    const int half = lane >> 5;
    const int hl = lane & 31;

    double xi[8];
#pragma unroll
    for (int t = 0; t < 8; ++t) xi[t] = (double)Xb[(size_t)vi * E_ + hl + t * 32];

    double bdist[6]; int bidx[6];
#pragma unroll
    for (int s = 0; s < 6; ++s) { bdist[s] = DBL_MAX; bidx[s] = 0x7fffffff; }

    const unsigned short* cp = c16 + (size_t)p * 16;
    for (int c = 0; c < 16; c += 2) {
        int jme = cp[c + half];
        const float* Xj = Xb + (size_t)jme * E_;
        double s = 0.0;
#pragma unroll
        for (int t = 0; t < 8; ++t) {
            double d = xi[t] - (double)Xj[hl + t * 32];
            s = fma(d, d, s);
        }
#pragma unroll
        for (int off = 16; off; off >>= 1) s += __shfl_xor(s, off);
        double sv[2];
        sv[0] = __shfl(s, 0);
        sv[1] = __shfl(s, 32);
        int jv[2] = { (int)cp[c], (int)cp[c + 1] };
#pragma unroll
        for (int q = 0; q < 2; ++q) {
            double sq_ = sv[q]; int j = jv[q];
            if (sq_ < bdist[5] || (sq_ == bdist[5] && j < bidx[5])) {
                bdist[5] = sq_; bidx[5] = j;
#pragma unroll
                for (int t = 5; t > 0; --t) {
                    if (bdist[t] < bdist[t - 1] ||
                        (bdist[t] == bdist[t - 1] && bidx[t] < bidx[t - 1])) {
                        double td = bdist[t]; bdist[t] = bdist[t - 1]; bdist[t - 1] = td;
                        int    ti = bidx[t];  bidx[t]  = bidx[t - 1];  bidx[t - 1]  = ti;
                    } else break;
                }
            }
        }
    }
    if (lane == 0) {
        int* op = idxout + (size_t)p * K_;
#pragma unroll
        for (int s = 0; s < 6; ++s) op[s] = bidx[s];
    }
}

// -------- k2: QKV projection, bf16 MFMA, 128 rows/block (W-tile reused) --------
__global__ __launch_bounds__(256, 2) void proj_mfma(const unsigned short* __restrict__ xh,
                                                    const unsigned short* __restrict__ Wh,
                                                    unsigned short* __restrict__ Y) {
    const int tid = threadIdx.x;
    const int w = tid >> 6, l = tid & 63, cl = l & 15, g = l >> 4;
    const int row0 = blockIdx.x * 128;
    const int wsel = blockIdx.y;                    // 0=Q,1=K,2=V
    const unsigned short* W = Wh + (size_t)wsel * 65536;

    bf16x8 a0[8], a1[8];
    const int ar0 = row0 + (w << 4) + cl;
#pragma unroll
    for (int ks = 0; ks < 8; ++ks) {
        a0[ks] = *reinterpret_cast<const bf16x8*>(xh + ((size_t)ar0 << 8) + ks * 32 + g * 8);
        a1[ks] = *reinterpret_cast<const bf16x8*>(xh + ((size_t)(ar0 + 64) << 8) + ks * 32 + g * 8);
    }

#pragma unroll
    for (int ct = 0; ct < 16; ++ct) {
        f32x4 acc0 = {0.f, 0.f, 0.f, 0.f};
        f32x4 acc1 = {0.f, 0.f, 0.f, 0.f};
        const unsigned short* Wr = W + (size_t)(ct * 16 + cl) * 256 + g * 8;
#pragma unroll
        for (int ks = 0; ks < 8; ++ks) {
            bf16x8 bf = *reinterpret_cast<const bf16x8*>(Wr + ks * 32);
            acc0 = __builtin_amdgcn_mfma_f32_16x16x32_bf16(a0[ks], bf, acc0, 0, 0, 0);
            acc1 = __builtin_amdgcn_mfma_f32_16x16x32_bf16(a1[ks], bf, acc1, 0, 0, 0);
        }
#pragma unroll
        for (int r = 0; r < 4; ++r) {
            size_t row = row0 + (w << 4) + (g << 2) + r;
            Y[row * 768 + wsel * 256 + ct * 16 + cl] = f2bf(acc0[r]);
            Y[(row + 64) * 768 + wsel * 256 + ct * 16 + cl] = f2bf(acc1[r]);
        }
    }
}

// ---- k3: attention, wave-per-point (4 pts/block) ----
__global__ __launch_bounds__(256) void attn_kernel(unsigned short* __restrict__ Y,
                                                   const int* __restrict__ idx,
                                                   float* __restrict__ xw) {
    const int bid = blockIdx.x;                      // 8192
    const int w = threadIdx.x >> 6;
    const int l = threadIdx.x & 63;
    const int p = (((bid & 7) << 12) | ((bid >> 3) << 2)) + w;  // XCD-batch swizzle
    const int b = p >> 12;

    const int* ip = idx + (size_t)p * K_;
    int nb[K_];
#pragma unroll
    for (int k = 0; k < K_; ++k) nb[k] = ip[k];

    unsigned short* Yp = Y + (size_t)p * 768;
    ushort4 q4 = *reinterpret_cast<const ushort4*>(Yp + l * 4);
    ushort4 s4 = *reinterpret_cast<const ushort4*>(Yp + 512 + l * 4);
    float q0 = bf2f(q4.x), q1 = bf2f(q4.y), q2 = bf2f(q4.z), q3 = bf2f(q4.w);
    float v0 = bf2f(s4.x), v1 = bf2f(s4.y), v2 = bf2f(s4.z), v3 = bf2f(s4.w);
    const size_t bbase = (size_t)(b << 12) * 768;

    float sc[K_];
#pragma unroll
    for (int k = 0; k < K_; ++k) {
        ushort4 k4 = *reinterpret_cast<const ushort4*>(
            Y + bbase + (size_t)nb[k] * 768 + 256 + l * 4);
        float s = q0 * bf2f(k4.x) + q1 * bf2f(k4.y)
                + q2 * bf2f(k4.z) + q3 * bf2f(k4.w);
        s += __shfl_xor(s, 1);
        s += __shfl_xor(s, 2);
        s += __shfl_xor(s, 4);
        sc[k] = s * 0.17677669529663687f;   // 1/sqrt(32)
    }
    float m = sc[0];
#pragma unroll
    for (int k = 1; k < K_; ++k) m = fmaxf(m, sc[k]);
    float e[K_], sum = 0.f;
#pragma unroll
    for (int k = 0; k < K_; ++k) { e[k] = __expf(sc[k] - m); sum += e[k]; }
    float inv = 1.f / sum;

    float o0 = 0.f, o1 = 0.f, o2 = 0.f, o3 = 0.f;
    float hs[K_];
#pragma unroll
    for (int k = 0; k < K_; ++k) {
        float a = e[k] * inv;
        ushort4 z4 = *reinterpret_cast<const ushort4*>(
            Y + bbase + (size_t)nb[k] * 768 + 512 + l * 4);
        o0 += a * (bf2f(z4.x) - v0);
        o1 += a * (bf2f(z4.y) - v1);
        o2 += a * (bf2f(z4.z) - v2);
        o3 += a * (bf2f(z4.w) - v3);
        float t = a;
        t += __shfl_xor(t, 8);
        t += __shfl_xor(t, 16);
        t += __shfl_xor(t, 32);
        hs[k] = t * 0.125f;
    }
    ushort o4[4] = { f2bf(o0), f2bf(o1), f2bf(o2), f2bf(o3) };
    *reinterpret_cast<ushort4*>(Yp + l * 4) = *reinterpret_cast<ushort4*>(o4);
    if (l < K_) atomicAdd(&xw[(b << 12) + nb[l]], hs[l]);
}

// -------- k4: out = P @ Wo^T + x, 128 rows/block dual-acc --------
__global__ __launch_bounds__(256, 2) void out_mfma(const unsigned short* __restrict__ Y,
                                                   const unsigned short* __restrict__ WoH,
                                                   const float* __restrict__ x,
                                                   float* __restrict__ out) {
    const int tid = threadIdx.x;
    const int w = tid >> 6, l = tid & 63, cl = l & 15, g = l >> 4;
    const int row0 = blockIdx.x * 128;

    bf16x8 a0[8], a1[8];
    const int ar0 = row0 + (w << 4) + cl;
#pragma unroll
    for (int ks = 0; ks < 8; ++ks) {
        a0[ks] = *reinterpret_cast<const bf16x8*>(Y + (size_t)ar0 * 768 + ks * 32 + g * 8);
        a1[ks] = *reinterpret_cast<const bf16x8*>(Y + (size_t)(ar0 + 64) * 768 + ks * 32 + g * 8);
    }

#pragma unroll
    for (int ct = 0; ct < 16; ++ct) {
        f32x4 acc0 = {0.f, 0.f, 0.f, 0.f};
        f32x4 acc1 = {0.f, 0.f, 0.f, 0.f};
        const unsigned short* Wr = WoH + (size_t)(ct * 16 + cl) * 256 + g * 8;
#pragma unroll
        for (int ks = 0; ks < 8; ++ks) {
            bf16x8 bf = *reinterpret_cast<const bf16x8*>(Wr + ks * 32);
            acc0 = __builtin_amdgcn_mfma_f32_16x16x32_bf16(a0[ks], bf, acc0, 0, 0, 0);
            acc1 = __builtin_amdgcn_mfma_f32_16x16x32_bf16(a1[ks], bf, acc1, 0, 0, 0);
        }
#pragma unroll
        for (int r = 0; r < 4; ++r) {
            size_t row = row0 + (w << 4) + (g << 2) + r;
            size_t o = row * E_ + ct * 16 + cl;
            out[o] = acc0[r] + x[o];
            size_t o2 = (row + 64) * E_ + ct * 16 + cl;
            out[o2] = acc1[r] + x[o2];
        }
    }
}

extern "C" void kernel_launch(void* const* d_in, const int* in_sizes, int n_in,
                              void* d_out, int out_size, void* d_ws, size_t ws_size,
                              hipStream_t stream) {
    const float* x  = (const float*)d_in[0];
    const float* Wq = (const float*)d_in[1];
    const float* Wk = (const float*)d_in[2];
    const float* Wv = (const float*)d_in[3];
    const float* Wo = (const float*)d_in[4];

    float* out = (float*)d_out;
    float* xw  = out + (size_t)NPTS * E_;   // second output [B,V]

    // workspace layout
    char* ws = (char*)d_ws;
    float*          sqw   = (float*)ws;                          // 128 KiB
    float*          sqpw  = (float*)(ws + 131072);               // 128 KiB
    unsigned int*   candw = (unsigned int*)(ws + 262144);        // 6 MiB (48 uint/pt)
    int*            idxw  = (int*)(ws + 6553600);                // 768 KiB
    unsigned char*  flagw = (unsigned char*)(ws + 7340032);      // 32 KiB
    unsigned short* Wh    = (unsigned short*)(ws + 7372800);     // 512 KiB (4 matrices)
    unsigned short* c16w  = (unsigned short*)(ws + 7897088);     // 1 MiB
    unsigned short* Xh    = (unsigned short*)(ws + 8945664);     // 16 MiB
    unsigned short* Y     = (unsigned short*)(ws + 25722880);    // 48 MiB bf16 [32768][768]

    hipMemsetAsync(xw, 0, (size_t)NPTS * sizeof(float), stream);

    cvtsq_kernel<<<4096 + 128, 256, 0, stream>>>(x, Wq, Wk, Wv, Wo, Xh, Wh, sqw);
    sqp_kernel<<<128, 256, 0, stream>>>(sqw, sqpw);
    knn10_kernel<<<dim3(V_ / 256, 4, B_), 256, 0, stream>>>(Xh, sqpw, candw);
    sel_kernel<<<NPTS / 256, 256, 0, stream>>>(candw, c16w, idxw, flagw);
    refine_kernel<<<NPTS / 4, 256, 0, stream>>>(x, c16w, flagw, idxw);
    proj_mfma<<<dim3(NPTS / 128, 3), 256, 0, stream>>>(Xh, Wh, Y);
    attn_kernel<<<NPTS / 4, 256, 0, stream>>>(Y, idxw, xw);
    out_mfma<<<NPTS / 128, 256, 0, stream>>>(Y, Wh + 3 * 65536, x, out);
}

// Round 15
// 232.541 us; speedup vs baseline: 11.3884x; 1.1133x over previous
//
#include <hip/hip_runtime.h>
#include <cfloat>
#include <math.h>

#define B_   8
#define V_   4096
#define E_   256
#define K_   6
#define H_   8
#define HD_  32
#define NPTS (B_*V_)

typedef __bf16 bf16x8 __attribute__((ext_vector_type(8)));
typedef float  f32x4  __attribute__((ext_vector_type(4)));
typedef float  f32x16 __attribute__((ext_vector_type(16)));

__device__ __forceinline__ float bf2f(unsigned short u) {
    return __uint_as_float(((unsigned int)u) << 16);
}
__device__ __forceinline__ unsigned short f2bf(float f) {
    unsigned int u = __float_as_uint(f);
    return (unsigned short)((u + 0x7fffu + ((u >> 16) & 1u)) >> 16);
}
__device__ __forceinline__ unsigned int med3u(unsigned int a, unsigned int b,
                                              unsigned int c) {
    unsigned int d;
    asm("v_med3_u32 %0, %1, %2, %3" : "=v"(d) : "v"(a), "v"(b), "v"(c));
    return d;
}
// branchless sorted-top-6 insert (single definition -> no transcription bugs)
__device__ __forceinline__ void push6(unsigned int (&k6)[6], unsigned int key) {
    k6[5] = med3u(k6[4], k6[5], key);
    k6[4] = med3u(k6[3], k6[4], key);
    k6[3] = med3u(k6[2], k6[3], key);
    k6[2] = med3u(k6[1], k6[2], key);
    k6[1] = med3u(k6[0], k6[1], key);
    k6[0] = min(k6[0], key);
}

// ------ k0: fp32->bf16 of x + W matrices; sq -> permuted (sq+600)*512 direct ------
__global__ __launch_bounds__(256) void cvtsq_kernel(const float* __restrict__ x,
                                                    const float* __restrict__ Wq,
                                                    const float* __restrict__ Wk,
                                                    const float* __restrict__ Wv,
                                                    const float* __restrict__ Wo,
                                                    unsigned short* __restrict__ xh,
                                                    unsigned short* __restrict__ Wh,
                                                    float* __restrict__ sqp) {
    const int bx = blockIdx.x;
    if (bx < 4096) {
        size_t i = ((size_t)bx * 256 + threadIdx.x) * 8;
        float4 a = *reinterpret_cast<const float4*>(x + i);
        float4 b = *reinterpret_cast<const float4*>(x + i + 4);
        ushort o[8] = { f2bf(a.x), f2bf(a.y), f2bf(a.z), f2bf(a.w),
                        f2bf(b.x), f2bf(b.y), f2bf(b.z), f2bf(b.w) };
        *reinterpret_cast<uint4*>(xh + i) = *reinterpret_cast<uint4*>(o);
        float s = a.x*a.x + a.y*a.y + a.z*a.z + a.w*a.w
                + b.x*b.x + b.y*b.y + b.z*b.z + b.w*b.w;
        s += __shfl_xor(s, 1);
        s += __shfl_xor(s, 2);
        s += __shfl_xor(s, 4);
        s += __shfl_xor(s, 8);
        s += __shfl_xor(s, 16);
        if ((threadIdx.x & 31) == 0) {
            int p = bx * 8 + (threadIdx.x >> 5);
            int b_ = p >> 12, col = p & 4095;
            int stripe = col >> 10, cc = col & 1023;
            int t = cc >> 5, rem = cc & 31;
            int h = (rem >> 2) & 1;
            int reg = (rem & 3) | ((rem >> 3) << 2);
            int i2 = (b_ << 12) | (stripe << 10) | (t << 5) | (h << 4) | reg;
            sqp[i2] = (s + 600.f) * 512.f;
        }
    } else {
        const int wb = bx - 4096;               // 0..127
        const int m = wb >> 5;
        const float* src = (m == 0) ? Wq : (m == 1) ? Wk : (m == 2) ? Wv : Wo;
        unsigned short* dst = Wh + (size_t)m * 65536;
        size_t i = ((size_t)(wb & 31) * 256 + threadIdx.x) * 8;
        float4 a = *reinterpret_cast<const float4*>(src + i);
        float4 b = *reinterpret_cast<const float4*>(src + i + 4);
        ushort o[8] = { f2bf(a.x), f2bf(a.y), f2bf(a.z), f2bf(a.w),
                        f2bf(b.x), f2bf(b.y), f2bf(b.z), f2bf(b.w) };
        *reinterpret_cast<uint4*>(dst + i) = *reinterpret_cast<uint4*>(o);
    }
}

// ---- k1: 32x32x16 MFMA Gram, 64 rows/wave (dual B-set) ----
__global__ __launch_bounds__(256, 2) void knn10_kernel(const unsigned short* __restrict__ xh,
                                                       const float* __restrict__ sqp,
                                                       unsigned int* __restrict__ cand) {
    __shared__ __align__(16) char smem[36864];   // 2x16KB tiles + 4KB sqp stripe

    const int b      = blockIdx.z;
    const int row0   = blockIdx.x * 256;
    const int stripe = blockIdx.y;
    const int colbase = stripe * 1024;
    const int tid = threadIdx.x;
    const int w   = tid >> 6;
    const int l   = tid & 63;
    const int ln  = l & 31;
    const int h   = l >> 5;
    const unsigned short* Xb = xh + ((size_t)b << 12) * E_;

    const int myrow0 = row0 + (w << 6) + ln;
    bf16x8 brow0[16], brow1[16];
#pragma unroll
    for (int kg = 0; kg < 16; ++kg) {
        brow0[kg] = *reinterpret_cast<const bf16x8*>(
            Xb + ((size_t)myrow0 << 8) + kg * 16 + h * 8);
        brow1[kg] = *reinterpret_cast<const bf16x8*>(
            Xb + ((size_t)(myrow0 + 32) << 8) + kg * 16 + h * 8);
    }

    unsigned int bk0[6], bk1[6];
#pragma unroll
    for (int s = 0; s < 6; ++s) { bk0[s] = 0xFFFFFFFFu; bk1[s] = 0xFFFFFFFFu; }

    __builtin_amdgcn_global_load_lds(
        (const __attribute__((address_space(1))) void*)
            (sqp + ((size_t)(b * 4 + stripe) << 10) + tid * 4),
        (__attribute__((address_space(3))) void*)(smem + 32768 + tid * 16), 16, 0, 0);
#pragma unroll
    for (int it = 0; it < 4; ++it) {
        int li = it * 256 + tid, col = li >> 5, sl = li & 31;
        const unsigned short* gp =
            Xb + ((size_t)(colbase + col) << 8) + ((sl ^ (col & 7)) << 3);
        __builtin_amdgcn_global_load_lds(
            (const __attribute__((address_space(1))) void*)gp,
            (__attribute__((address_space(3))) void*)(smem + li * 16), 16, 0, 0);
    }
    __syncthreads();

    for (int t = 0; t < 32; ++t) {
        const int cur = (t & 1) * 16384;
        if (t < 31) {
            char* nbuf = smem + (cur ^ 16384);
            const int c0n = colbase + (t + 1) * 32;
#pragma unroll
            for (int it = 0; it < 4; ++it) {
                int li = it * 256 + tid, col = li >> 5, sl = li & 31;
                const unsigned short* gp =
                    Xb + ((size_t)(c0n + col) << 8) + ((sl ^ (col & 7)) << 3);
                __builtin_amdgcn_global_load_lds(
                    (const __attribute__((address_space(1))) void*)gp,
                    (__attribute__((address_space(3))) void*)(nbuf + li * 16), 16, 0, 0);
            }
        }
        const char* sb = smem + 32768 + t * 128 + h * 64;
        f32x4 sv0 = *reinterpret_cast<const f32x4*>(sb);
        f32x4 sv1 = *reinterpret_cast<const f32x4*>(sb + 16);
        f32x4 sv2 = *reinterpret_cast<const f32x4*>(sb + 32);
        f32x4 sv3 = *reinterpret_cast<const f32x4*>(sb + 48);

        f32x16 acc0 = {}, acc1 = {};
        const char* abase = smem + cur + ln * 512;
        const int swz = (ln & 7);
#pragma unroll
        for (int kg = 0; kg < 16; ++kg) {
            bf16x8 af = *reinterpret_cast<const bf16x8*>(
                abase + ((((kg << 1) + h) ^ swz) << 4));
            acc0 = __builtin_amdgcn_mfma_f32_32x32x16_bf16(af, brow0[kg], acc0, 0, 0, 0);
            acc1 = __builtin_amdgcn_mfma_f32_32x32x16_bf16(af, brow1[kg], acc1, 0, 0, 0);
        }

        const unsigned int cb0 = (unsigned int)(colbase + (t << 5) + (h << 2));
#pragma unroll
        for (int r = 0; r < 16; ++r) {
            float sqv = (r < 4) ? sv0[r & 3] : (r < 8) ? sv1[r & 3]
                       : (r < 12) ? sv2[r & 3] : sv3[r & 3];
            unsigned int cidx = cb0 + (r & 3) + ((r >> 2) << 3);
            float d0 = fmaf(-1024.f, acc0[r], sqv);      // d_b * 512
            push6(bk0, ((unsigned int)d0 << 12) | cidx);
            float d1 = fmaf(-1024.f, acc1[r], sqv);
            push6(bk1, ((unsigned int)d1 << 12) | cidx);
        }
        __syncthreads();
    }

    size_t p0 = ((size_t)b << 12) + myrow0;
    unsigned int* op0 = cand + p0 * 48 + stripe * 12 + h * 6;
    unsigned int* op1 = cand + (p0 + 32) * 48 + stripe * 12 + h * 6;
#pragma unroll
    for (int s = 0; s < 6; ++s) { op0[s] = bk0[s]; op1[s] = bk1[s]; }
}

// ---------------- k1s: key-top-16 of 48; resolve boundary or flag ----------------
__global__ __launch_bounds__(256) void sel_kernel(const unsigned int* __restrict__ cand,
                                                  unsigned short* __restrict__ c16,
                                                  int* __restrict__ idxout,
                                                  unsigned char* __restrict__ flag) {
    int p = blockIdx.x * 256 + threadIdx.x;
    const unsigned int* cp = cand + (size_t)p * 48;
    unsigned int tk[16];
#pragma unroll
    for (int s = 0; s < 16; ++s) tk[s] = 0xFFFFFFFFu;
    for (int j = 0; j < 48; ++j) {
        unsigned int key = cp[j];
#pragma unroll
        for (int s = 15; s > 0; --s) tk[s] = med3u(tk[s - 1], tk[s], key);
        tk[0] = min(tk[0], key);
    }
    unsigned short* op = c16 + (size_t)p * 16;
#pragma unroll
    for (int s = 0; s < 16; ++s) op[s] = (unsigned short)(tk[s] & 4095u);
    int* ip = idxout + (size_t)p * K_;
#pragma unroll
    for (int s = 0; s < 6; ++s) ip[s] = (int)(tk[s] & 4095u);
    float d6 = (float)(tk[5] >> 12) * 0.001953125f;
    float d7 = (float)(tk[6] >> 12) * 0.001953125f;
    flag[p] = (d7 - d6 < 0.4f) ? 1 : 0;
}

// ------- k1b: fp64 exact re-rank of 16 candidates (flagged points only) -------
__global__ __launch_bounds__(256) void refine_kernel(const float* __restrict__ x,
                                                     const unsigned short* __restrict__ c16,
                                                     const unsigned char* __restrict__ flag,
                                                     int* __restrict__ idxout) {
    int wv = threadIdx.x >> 6;
    int lane = threadIdx.x & 63;
    const int bid = blockIdx.x;
    const int nbk = ((bid & 7) << 10) | (bid >> 3);
    int p = nbk * 4 + wv;
    if (!flag[p]) return;
    int b = p >> 12;
    int vi = p & 4095;
    const float* Xb = x + ((size_t)b << 12) * E_;
    const int half = lane >> 5;
    const int hl = lane & 31;

    double xi[8];
#pragma unroll
    for (int t = 0; t < 8; ++t) xi[t] = (double)Xb[(size_t)vi * E_ + hl + t * 32];

    double bdist[6]; int bidx[6];
#pragma unroll
    for (int s = 0; s < 6; ++s) { bdist[s] = DBL_MAX; bidx[s] = 0x7fffffff; }

    const unsigned short* cp = c16 + (size_t)p * 16;
    for (int c = 0; c < 16; c += 2) {
        int jme = cp[c + half];
        const float* Xj = Xb + (size_t)jme * E_;
        double s = 0.0;
#pragma unroll
        for (int t = 0; t < 8; ++t) {
            double d = xi[t] - (double)Xj[hl + t * 32];
            s = fma(d, d, s);
        }
#pragma unroll
        for (int off = 16; off; off >>= 1) s += __shfl_xor(s, off);
        double sv[2];
        sv[0] = __shfl(s, 0);
        sv[1] = __shfl(s, 32);
        int jv[2] = { (int)cp[c], (int)cp[c + 1] };
#pragma unroll
        for (int q = 0; q < 2; ++q) {
            double sq_ = sv[q]; int j = jv[q];
            if (sq_ < bdist[5] || (sq_ == bdist[5] && j < bidx[5])) {
                bdist[5] = sq_; bidx[5] = j;
#pragma unroll
                for (int t = 5; t > 0; --t) {
                    if (bdist[t] < bdist[t - 1] ||
                        (bdist[t] == bdist[t - 1] && bidx[t] < bidx[t - 1])) {
                        double td = bdist[t]; bdist[t] = bdist[t - 1]; bdist[t - 1] = td;
                        int    ti = bidx[t];  bidx[t]  = bidx[t - 1];  bidx[t - 1]  = ti;
                    } else break;
                }
            }
        }
    }
    if (lane == 0) {
        int* op = idxout + (size_t)p * K_;
#pragma unroll
        for (int s = 0; s < 6; ++s) op[s] = bidx[s];
    }
}

// -------- k2: QKV projection, bf16 MFMA, 128 rows/block (W-tile reused) --------
__global__ __launch_bounds__(256, 2) void proj_mfma(const unsigned short* __restrict__ xh,
                                                    const unsigned short* __restrict__ Wh,
                                                    unsigned short* __restrict__ Y) {
    const int tid = threadIdx.x;
    const int w = tid >> 6, l = tid & 63, cl = l & 15, g = l >> 4;
    const int row0 = blockIdx.x * 128;
    const int wsel = blockIdx.y;                    // 0=Q,1=K,2=V
    const unsigned short* W = Wh + (size_t)wsel * 65536;

    bf16x8 a0[8], a1[8];
    const int ar0 = row0 + (w << 4) + cl;
#pragma unroll
    for (int ks = 0; ks < 8; ++ks) {
        a0[ks] = *reinterpret_cast<const bf16x8*>(xh + ((size_t)ar0 << 8) + ks * 32 + g * 8);
        a1[ks] = *reinterpret_cast<const bf16x8*>(xh + ((size_t)(ar0 + 64) << 8) + ks * 32 + g * 8);
    }

#pragma unroll
    for (int ct = 0; ct < 16; ++ct) {
        f32x4 acc0 = {0.f, 0.f, 0.f, 0.f};
        f32x4 acc1 = {0.f, 0.f, 0.f, 0.f};
        const unsigned short* Wr = W + (size_t)(ct * 16 + cl) * 256 + g * 8;
#pragma unroll
        for (int ks = 0; ks < 8; ++ks) {
            bf16x8 bf = *reinterpret_cast<const bf16x8*>(Wr + ks * 32);
            acc0 = __builtin_amdgcn_mfma_f32_16x16x32_bf16(a0[ks], bf, acc0, 0, 0, 0);
            acc1 = __builtin_amdgcn_mfma_f32_16x16x32_bf16(a1[ks], bf, acc1, 0, 0, 0);
        }
#pragma unroll
        for (int r = 0; r < 4; ++r) {
            size_t row = row0 + (w << 4) + (g << 2) + r;
            Y[row * 768 + wsel * 256 + ct * 16 + cl] = f2bf(acc0[r]);
            Y[(row + 64) * 768 + wsel * 256 + ct * 16 + cl] = f2bf(acc1[r]);
        }
    }
}

// ---- k3: fused attention + Wo GEMM + residual. Block = 16 points:
// 4 waves x 4 points sequential; P rows -> LDS; barrier; 16x256 @ Wo^T MFMA. ----
__global__ __launch_bounds__(256) void attn16_kernel(const unsigned short* __restrict__ Y,
                                                     const int* __restrict__ idx,
                                                     const unsigned short* __restrict__ WoH,
                                                     const float* __restrict__ x,
                                                     float* __restrict__ out,
                                                     float* __restrict__ xw) {
    __shared__ __align__(16) unsigned short P[16][264];   // +8 pad vs bank conflicts
    const int bid = blockIdx.x;                           // 2048
    const int blk = ((bid & 7) << 8) | (bid >> 3);        // XCD swizzle: XCD c -> batch c
    const int w = threadIdx.x >> 6;
    const int l = threadIdx.x & 63;
    const int p0 = blk * 16;
    const int b = p0 >> 12;
    const size_t bbase = (size_t)(b << 12) * 768;

    for (int j = 0; j < 4; ++j) {
        const int p = p0 + w * 4 + j;
        const int* ip = idx + (size_t)p * K_;
        int nb[K_];
#pragma unroll
        for (int k = 0; k < K_; ++k) nb[k] = ip[k];

        const unsigned short* Yp = Y + (size_t)p * 768;
        ushort4 q4 = *reinterpret_cast<const ushort4*>(Yp + l * 4);
        ushort4 s4 = *reinterpret_cast<const ushort4*>(Yp + 512 + l * 4);
        float q0 = bf2f(q4.x), q1 = bf2f(q4.y), q2 = bf2f(q4.z), q3 = bf2f(q4.w);
        float v0 = bf2f(s4.x), v1 = bf2f(s4.y), v2 = bf2f(s4.z), v3 = bf2f(s4.w);

        float sc[K_];
#pragma unroll
        for (int k = 0; k < K_; ++k) {
            ushort4 k4 = *reinterpret_cast<const ushort4*>(
                Y + bbase + (size_t)nb[k] * 768 + 256 + l * 4);
            float s = q0 * bf2f(k4.x) + q1 * bf2f(k4.y)
                    + q2 * bf2f(k4.z) + q3 * bf2f(k4.w);
            s += __shfl_xor(s, 1);
            s += __shfl_xor(s, 2);
            s += __shfl_xor(s, 4);
            sc[k] = s * 0.17677669529663687f;   // 1/sqrt(32)
        }
        float m = sc[0];
#pragma unroll
        for (int k = 1; k < K_; ++k) m = fmaxf(m, sc[k]);
        float e[K_], sum = 0.f;
#pragma unroll
        for (int k = 0; k < K_; ++k) { e[k] = __expf(sc[k] - m); sum += e[k]; }
        float inv = 1.f / sum;

        float o0 = 0.f, o1 = 0.f, o2 = 0.f, o3 = 0.f;
        float hs[K_];
#pragma unroll
        for (int k = 0; k < K_; ++k) {
            float a = e[k] * inv;
            ushort4 z4 = *reinterpret_cast<const ushort4*>(
                Y + bbase + (size_t)nb[k] * 768 + 512 + l * 4);
            o0 += a * (bf2f(z4.x) - v0);
            o1 += a * (bf2f(z4.y) - v1);
            o2 += a * (bf2f(z4.z) - v2);
            o3 += a * (bf2f(z4.w) - v3);
            float t = a;
            t += __shfl_xor(t, 8);
            t += __shfl_xor(t, 16);
            t += __shfl_xor(t, 32);
            hs[k] = t * 0.125f;
        }
        ushort o4[4] = { f2bf(o0), f2bf(o1), f2bf(o2), f2bf(o3) };
        *reinterpret_cast<ushort4*>(&P[w * 4 + j][l * 4]) =
            *reinterpret_cast<ushort4*>(o4);
        if (l < K_) atomicAdd(&xw[(b << 12) + nb[l]], hs[l]);
    }
    __syncthreads();

    // 16x256 P @ Wo^T + x ; wave w computes output cols [w*64, w*64+64)
    const int cl = l & 15, g = l >> 4;
    bf16x8 a[8];
#pragma unroll
    for (int ks = 0; ks < 8; ++ks)
        a[ks] = *reinterpret_cast<const bf16x8*>(&P[cl][ks * 32 + g * 8]);

#pragma unroll
    for (int ct = 0; ct < 4; ++ct) {
        const int col0 = w * 64 + ct * 16;
        f32x4 acc = {0.f, 0.f, 0.f, 0.f};
        const unsigned short* Wr = WoH + (size_t)(col0 + cl) * 256 + g * 8;
#pragma unroll
        for (int ks = 0; ks < 8; ++ks) {
            bf16x8 bf = *reinterpret_cast<const bf16x8*>(Wr + ks * 32);
            acc = __builtin_amdgcn_mfma_f32_16x16x32_bf16(a[ks], bf, acc, 0, 0, 0);
        }
#pragma unroll
        for (int r = 0; r < 4; ++r) {
            size_t o = (size_t)(p0 + (g << 2) + r) * E_ + col0 + cl;
            out[o] = acc[r] + x[o];
        }
    }
}

extern "C" void kernel_launch(void* const* d_in, const int* in_sizes, int n_in,
                              void* d_out, int out_size, void* d_ws, size_t ws_size,
                              hipStream_t stream) {
    const float* x  = (const float*)d_in[0];
    const float* Wq = (const float*)d_in[1];
    const float* Wk = (const float*)d_in[2];
    const float* Wv = (const float*)d_in[3];
    const float* Wo = (const float*)d_in[4];

    float* out = (float*)d_out;
    float* xw  = out + (size_t)NPTS * E_;   // second output [B,V]

    // workspace layout
    char* ws = (char*)d_ws;
    float*          sqpw  = (float*)(ws + 131072);               // 128 KiB (permuted)
    unsigned int*   candw = (unsigned int*)(ws + 262144);        // 6 MiB (48 uint/pt)
    int*            idxw  = (int*)(ws + 6553600);                // 768 KiB
    unsigned char*  flagw = (unsigned char*)(ws + 7340032);      // 32 KiB
    unsigned short* Wh    = (unsigned short*)(ws + 7372800);     // 512 KiB (4 matrices)
    unsigned short* c16w  = (unsigned short*)(ws + 7897088);     // 1 MiB
    unsigned short* Xh    = (unsigned short*)(ws + 8945664);     // 16 MiB
    unsigned short* Y     = (unsigned short*)(ws + 25722880);    // 48 MiB bf16 [32768][768]

    hipMemsetAsync(xw, 0, (size_t)NPTS * sizeof(float), stream);

    cvtsq_kernel<<<4096 + 128, 256, 0, stream>>>(x, Wq, Wk, Wv, Wo, Xh, Wh, sqpw);
    knn10_kernel<<<dim3(V_ / 256, 4, B_), 256, 0, stream>>>(Xh, sqpw, candw);
    sel_kernel<<<NPTS / 256, 256, 0, stream>>>(candw, c16w, idxw, flagw);
    refine_kernel<<<NPTS / 4, 256, 0, stream>>>(x, c16w, flagw, idxw);
    proj_mfma<<<dim3(NPTS / 128, 3), 256, 0, stream>>>(Xh, Wh, Y);
    attn16_kernel<<<NPTS / 16, 256, 0, stream>>>(Y, idxw, Wh + 3 * 65536, x, out, xw);
}